// Round 4
// baseline (1547.888 us; speedup 1.0000x reference)
//
#include <hip/hip_runtime.h>

#define RELUF 1
#define ACCF  2

typedef unsigned short ushort_t;
#define BF16_MAGIC 0x3F803F80u   // fe_g word0 if arrays are packed bf16 (1.0,1.0)

__device__ __forceinline__ float bf2f(unsigned short v) {
    return __uint_as_float(((unsigned int)v) << 16);
}
__device__ __forceinline__ unsigned short f2b(float f) {
    unsigned int u = __float_as_uint(f);
    return (unsigned short)((u + 0x7fffu + ((u >> 16) & 1u)) >> 16);
}

// ---------- dual-dtype batched conversion: 45 arrays -> fp32 workspace ----------
struct ConvPack {
    const void* s[45];
    int off[45];
    int n[45];
};

__global__ void conv_all_kernel(ConvPack p, float* __restrict__ base,
                                const unsigned int* __restrict__ gate) {
    const bool isbf = (gate[0] == BF16_MAGIC);
    const int a = blockIdx.y;
    const void* s = p.s[a];
    float* d = base + p.off[a];
    const int n = p.n[a];
    if (isbf) {
        const ushort_t* sp = (const ushort_t*)s;
        for (int i = blockIdx.x * blockDim.x + threadIdx.x; i < n; i += gridDim.x * blockDim.x)
            d[i] = bf2f(sp[i]);
    } else {
        const float* sp = (const float*)s;
        for (int i = blockIdx.x * blockDim.x + threadIdx.x; i < n; i += gridDim.x * blockDim.x)
            d[i] = sp[i];
    }
}

__global__ void zero_f32_kernel(float* __restrict__ p, int n) {
    int i = blockIdx.x * blockDim.x + threadIdx.x;
    if (i < n) p[i] = 0.f;
}
__global__ void zero_i32_kernel(int* __restrict__ p, int n) {
    int i = blockIdx.x * blockDim.x + threadIdx.x;
    if (i < n) p[i] = 0;
}
__global__ void copy4_kernel(const float4* __restrict__ s, float4* __restrict__ d, int n4) {
    int i = blockIdx.x * blockDim.x + threadIdx.x;
    if (i < n4) d[i] = s[i];
}

// ---------- GEMM: C[M,128] = A[M,K] @ W[K,128] (+bias)(+C)(relu), all fp32 ----------
// 128x128 tile, 256 threads, 8x8 per thread.
__global__ __launch_bounds__(256)
void gemm_kernel(const float* __restrict__ A, int lda,
                 const float* __restrict__ W,
                 float* __restrict__ C, int ldc,
                 int M, int K,
                 const float* __restrict__ bias, int flags)
{
    __shared__ float As[16][128];   // [k][m]
    __shared__ float Bs[16][128];   // [k][n]
    const int tid = threadIdx.x;
    const int m0 = blockIdx.x * 128;
    const int ty = tid >> 4, tx = tid & 15;
    const int ar = tid >> 1;          // 0..127 row in tile
    const int akg = (tid & 1) << 3;   // 0 or 8 (k-offset)
    const int wr = tid >> 4;          // 0..15 k-row for W staging
    const int wc = (tid & 15) << 3;   // 0..120 col for W staging
    const bool arow_ok = (m0 + ar) < M;
    const float* Arow = A + (size_t)(m0 + ar) * lda;

    float acc[8][8];
#pragma unroll
    for (int i = 0; i < 8; i++)
#pragma unroll
        for (int j = 0; j < 8; j++) acc[i][j] = 0.f;

    for (int k0 = 0; k0 < K; k0 += 16) {
        float av[8];
        int kb = k0 + akg;
        if (arow_ok && kb + 8 <= K) {
            float4 p0 = *(const float4*)(Arow + kb);
            float4 p1 = *(const float4*)(Arow + kb + 4);
            av[0] = p0.x; av[1] = p0.y; av[2] = p0.z; av[3] = p0.w;
            av[4] = p1.x; av[5] = p1.y; av[6] = p1.z; av[7] = p1.w;
        } else {
            for (int j = 0; j < 8; j++) {
                int k = kb + j;
                av[j] = (arow_ok && k < K) ? Arow[k] : 0.f;
            }
        }
        float wv[8];
        int kw = k0 + wr;
        if (kw < K) {
            float4 q0 = *(const float4*)(W + (size_t)kw * 128 + wc);
            float4 q1 = *(const float4*)(W + (size_t)kw * 128 + wc + 4);
            wv[0] = q0.x; wv[1] = q0.y; wv[2] = q0.z; wv[3] = q0.w;
            wv[4] = q1.x; wv[5] = q1.y; wv[6] = q1.z; wv[7] = q1.w;
        } else {
            for (int j = 0; j < 8; j++) wv[j] = 0.f;
        }
        __syncthreads();
#pragma unroll
        for (int j = 0; j < 8; j++) As[akg + j][ar] = av[j];
#pragma unroll
        for (int j = 0; j < 8; j++) Bs[wr][wc + j] = wv[j];
        __syncthreads();
#pragma unroll
        for (int kk = 0; kk < 16; kk++) {
            float4 a0 = *(const float4*)&As[kk][ty * 8];
            float4 a1 = *(const float4*)&As[kk][ty * 8 + 4];
            float4 w0 = *(const float4*)&Bs[kk][tx * 4];
            float4 w1 = *(const float4*)&Bs[kk][64 + tx * 4];
            float aa[8] = {a0.x, a0.y, a0.z, a0.w, a1.x, a1.y, a1.z, a1.w};
            float ww[8] = {w0.x, w0.y, w0.z, w0.w, w1.x, w1.y, w1.z, w1.w};
#pragma unroll
            for (int i = 0; i < 8; i++)
#pragma unroll
                for (int j = 0; j < 8; j++) acc[i][j] = fmaf(aa[i], ww[j], acc[i][j]);
        }
    }
#pragma unroll
    for (int i = 0; i < 8; i++) {
        int gm = m0 + ty * 8 + i;
        if (gm >= M) continue;
        float* crow = C + (size_t)gm * ldc;
#pragma unroll
        for (int jh = 0; jh < 2; jh++) {
            int gn = jh * 64 + tx * 4;
            float4 r = make_float4(acc[i][jh * 4 + 0], acc[i][jh * 4 + 1],
                                   acc[i][jh * 4 + 2], acc[i][jh * 4 + 3]);
            if (bias) {
                float4 bb = *(const float4*)(bias + gn);
                r.x += bb.x; r.y += bb.y; r.z += bb.z; r.w += bb.w;
            }
            if (flags & ACCF) {
                float4 c0 = *(const float4*)(crow + gn);
                r.x += c0.x; r.y += c0.y; r.z += c0.z; r.w += c0.w;
            }
            if (flags & RELUF) {
                r.x = fmaxf(r.x, 0.f); r.y = fmaxf(r.y, 0.f);
                r.z = fmaxf(r.z, 0.f); r.w = fmaxf(r.w, 0.f);
            }
            *(float4*)(crow + gn) = r;
        }
    }
}

// ---------- LayerNorm(128) + ReLU in place ----------
__global__ void ln_relu_kernel(float* __restrict__ X, int ld,
                               const float* __restrict__ g,
                               const float* __restrict__ b, int M)
{
    int node = blockIdx.x * 4 + (threadIdx.x >> 6);
    int lane = threadIdx.x & 63;
    if (node >= M) return;
    float* row = X + (size_t)node * ld;
    float2 v = *(float2*)(row + lane * 2);
    float s = v.x + v.y, sq = v.x * v.x + v.y * v.y;
#pragma unroll
    for (int off = 32; off; off >>= 1) { s += __shfl_xor(s, off); sq += __shfl_xor(sq, off); }
    float mean = s * (1.f / 128.f);
    float var = sq * (1.f / 128.f) - mean * mean;
    float inv = rsqrtf(var + 1e-5f);
    float y0 = fmaxf((v.x - mean) * inv * g[lane * 2] + b[lane * 2], 0.f);
    float y1 = fmaxf((v.y - mean) * inv * g[lane * 2 + 1] + b[lane * 2 + 1], 0.f);
    *(float2*)(row + lane * 2) = make_float2(y0, y1);
}

// ---------- router ----------
__global__ void router_kernel(const float* __restrict__ hr, const float* __restrict__ rW,
                              float* __restrict__ gates, int M)
{
    int node = blockIdx.x * 4 + (threadIdx.x >> 6);
    int lane = threadIdx.x & 63;
    if (node >= M) return;
    const float* row = hr + (size_t)node * 256;
    float a0 = 0, a1 = 0, a2 = 0, a3 = 0;
#pragma unroll
    for (int i = 0; i < 4; i++) {
        int k = lane + i * 64;
        float xv = row[k];
        float4 wv = *(const float4*)(rW + k * 4);
        a0 = fmaf(xv, wv.x, a0); a1 = fmaf(xv, wv.y, a1);
        a2 = fmaf(xv, wv.z, a2); a3 = fmaf(xv, wv.w, a3);
    }
#pragma unroll
    for (int off = 32; off; off >>= 1) {
        a0 += __shfl_xor(a0, off); a1 += __shfl_xor(a1, off);
        a2 += __shfl_xor(a2, off); a3 += __shfl_xor(a3, off);
    }
    if (lane == 0) {
        float l[4] = {a0 * (1.f / 1.5f), a1 * (1.f / 1.5f), a2 * (1.f / 1.5f), a3 * (1.f / 1.5f)};
        float mx = fmaxf(fmaxf(l[0], l[1]), fmaxf(l[2], l[3]));
        float e[4], ssum = 0.f;
#pragma unroll
        for (int i = 0; i < 4; i++) { e[i] = expf(l[i] - mx); ssum += e[i]; }
        float p[4];
#pragma unroll
        for (int i = 0; i < 4; i++) p[i] = e[i] / ssum;
        int i0 = 0;
        for (int i = 1; i < 4; i++) if (p[i] > p[i0]) i0 = i;
        int i1 = -1;
        for (int i = 0; i < 4; i++) {
            if (i == i0) continue;
            if (i1 < 0 || p[i] > p[i1]) i1 = i;
        }
        float wsum = fmaxf(p[i0] + p[i1], 1e-9f);
        float gg[4] = {0.f, 0.f, 0.f, 0.f};
        gg[i0] = p[i0] / wsum;
        gg[i1] = p[i1] / wsum;
        *(float4*)(gates + (size_t)node * 4) = make_float4(gg[0], gg[1], gg[2], gg[3]);
    }
}

// ---------- graph structure ----------
__global__ void edge_deg_kernel(const int* __restrict__ dst, int* __restrict__ degi, int E) {
    int e = blockIdx.x * blockDim.x + threadIdx.x;
    if (e < E) atomicAdd(&degi[dst[e]], 1);
}
__global__ void batch_count_kernel(const int* __restrict__ batch, float* __restrict__ bcnt, int N) {
    int n = blockIdx.x * blockDim.x + threadIdx.x;
    if (n < N) atomicAdd(&bcnt[batch[n]], 1.0f);
}
__global__ void scan_kernel(const int* __restrict__ degi, int* __restrict__ rowptr, int n) {
    __shared__ int sh[256];
    __shared__ int sbase;
    int tid = threadIdx.x;
    if (tid == 0) { sbase = 0; rowptr[0] = 0; }
    __syncthreads();
    const int CH = 256 * 8;
    for (int c0 = 0; c0 < n; c0 += CH) {
        int loc[8]; int s = 0;
        int base_i = c0 + tid * 8;
#pragma unroll
        for (int j = 0; j < 8; j++) {
            int idx = base_i + j;
            int v = (idx < n) ? degi[idx] : 0;
            s += v; loc[j] = s;
        }
        sh[tid] = s;
        __syncthreads();
        for (int off = 1; off < 256; off <<= 1) {
            int t = (tid >= off) ? sh[tid - off] : 0;
            __syncthreads();
            sh[tid] += t;
            __syncthreads();
        }
        int prev = (tid > 0) ? sh[tid - 1] : 0;
        int b = sbase;
        int total = sh[255];
#pragma unroll
        for (int j = 0; j < 8; j++) {
            int idx = base_i + j;
            if (idx < n) rowptr[idx + 1] = b + prev + loc[j];
        }
        __syncthreads();
        if (tid == 0) sbase = b + total;
        __syncthreads();
    }
}
__global__ void csr_fill_kernel(const int* __restrict__ src, const int* __restrict__ dst,
                                const int* __restrict__ rowptr, int* __restrict__ cursor,
                                int* __restrict__ csr, int E) {
    int e = blockIdx.x * blockDim.x + threadIdx.x;
    if (e >= E) return;
    int d = dst[e];
    int pos = atomicAdd(&cursor[d], 1);
    csr[rowptr[d] + pos] = src[e];
}
__global__ void dinv_kernel(const int* __restrict__ degi, float* __restrict__ dinv,
                            float* __restrict__ dinvl, int N) {
    int n = blockIdx.x * blockDim.x + threadIdx.x;
    if (n >= N) return;
    float deg = (float)degi[n];
    dinv[n] = (deg > 0.f) ? rsqrtf(fmaxf(deg, 1.f)) : 0.f;
    dinvl[n] = rsqrtf(deg + 1.f);
}

// ---------- gather propagation ----------
__global__ void gather_kernel(const float* __restrict__ X, float* __restrict__ Out,
                              const int* __restrict__ rowptr, const int* __restrict__ csr,
                              const float* __restrict__ dv, int self_loop, float scale,
                              const float* __restrict__ bias, int relu, int M)
{
    int node = blockIdx.x * 4 + (threadIdx.x >> 6);
    int lane = threadIdx.x & 63;
    if (node >= M) return;
    int beg = rowptr[node], end = rowptr[node + 1];
    float dn = dv[node];
    float ax = 0.f, ay = 0.f;
    int e = beg;
    for (; e + 3 < end; e += 4) {
        int s0 = csr[e], s1 = csr[e + 1], s2 = csr[e + 2], s3 = csr[e + 3];
        float c0 = dn * dv[s0], c1 = dn * dv[s1], c2 = dn * dv[s2], c3 = dn * dv[s3];
        float2 x0 = *(const float2*)(X + (size_t)s0 * 128 + lane * 2);
        float2 x1 = *(const float2*)(X + (size_t)s1 * 128 + lane * 2);
        float2 x2 = *(const float2*)(X + (size_t)s2 * 128 + lane * 2);
        float2 x3 = *(const float2*)(X + (size_t)s3 * 128 + lane * 2);
        ax = fmaf(c0, x0.x, fmaf(c1, x1.x, fmaf(c2, x2.x, fmaf(c3, x3.x, ax))));
        ay = fmaf(c0, x0.y, fmaf(c1, x1.y, fmaf(c2, x2.y, fmaf(c3, x3.y, ay))));
    }
    for (; e < end; e++) {
        int s = csr[e];
        float c = dn * dv[s];
        float2 xv = *(const float2*)(X + (size_t)s * 128 + lane * 2);
        ax = fmaf(c, xv.x, ax); ay = fmaf(c, xv.y, ay);
    }
    if (self_loop) {
        float c = dn * dn;
        float2 xv = *(const float2*)(X + (size_t)node * 128 + lane * 2);
        ax = fmaf(c, xv.x, ax); ay = fmaf(c, xv.y, ay);
    }
    ax *= scale; ay *= scale;
    if (bias) { ax += bias[lane * 2]; ay += bias[lane * 2 + 1]; }
    if (relu) { ax = fmaxf(ax, 0.f); ay = fmaxf(ay, 0.f); }
    *(float2*)(Out + (size_t)node * 128 + lane * 2) = make_float2(ax, ay);
}

// ---------- graph-transformer attention (4 heads x 32) ----------
__global__ void gt_attn_kernel(const float* __restrict__ Q, const float* __restrict__ Km,
                               const float* __restrict__ V, const int* __restrict__ rowptr,
                               const int* __restrict__ csr, float* __restrict__ Out, int M)
{
    const float SC = 0.17677669529663689f; // 1/sqrt(32)
    int node = blockIdx.x * 4 + (threadIdx.x >> 6);
    int lane = threadIdx.x & 63;
    if (node >= M) return;
    int beg = rowptr[node], end = rowptr[node + 1];
    float2 q = *(const float2*)(Q + (size_t)node * 128 + lane * 2);
    float m = -1e30f;
    for (int e = beg; e < end; e++) {
        int s = csr[e];
        float2 kv = *(const float2*)(Km + (size_t)s * 128 + lane * 2);
        float p = q.x * kv.x + q.y * kv.y;
        p += __shfl_xor(p, 1); p += __shfl_xor(p, 2); p += __shfl_xor(p, 4); p += __shfl_xor(p, 8);
        m = fmaxf(m, p);
    }
    m *= SC;  // positive scale commutes with max
    float denom = 0.f, ax = 0.f, ay = 0.f;
    for (int e = beg; e < end; e++) {
        int s = csr[e];
        float2 kv = *(const float2*)(Km + (size_t)s * 128 + lane * 2);
        float p = q.x * kv.x + q.y * kv.y;
        p += __shfl_xor(p, 1); p += __shfl_xor(p, 2); p += __shfl_xor(p, 4); p += __shfl_xor(p, 8);
        p = expf(p * SC - m);
        denom += p;
        float2 vv = *(const float2*)(V + (size_t)s * 128 + lane * 2);
        ax = fmaf(p, vv.x, ax); ay = fmaf(p, vv.y, ay);
    }
    float d = fmaxf(denom, 1e-9f);
    *(float2*)(Out + (size_t)node * 128 + lane * 2) = make_float2(ax / d, ay / d);
}

// ---------- post-norm + gated accumulate ----------
__global__ void combine_kernel(const float* __restrict__ X, const float* __restrict__ gates,
                               int eidx, const float* __restrict__ png,
                               const float* __restrict__ pnb,
                               const float* __restrict__ esc,
                               float* __restrict__ Out, int M)
{
    int node = blockIdx.x * 4 + (threadIdx.x >> 6);
    int lane = threadIdx.x & 63;
    if (node >= M) return;
    float2 v = *(const float2*)(X + (size_t)node * 128 + lane * 2);
    float s = v.x + v.y, sq = v.x * v.x + v.y * v.y;
#pragma unroll
    for (int off = 32; off; off >>= 1) { s += __shfl_xor(s, off); sq += __shfl_xor(sq, off); }
    float mean = s * (1.f / 128.f);
    float var = sq * (1.f / 128.f) - mean * mean;
    float inv = rsqrtf(var + 1e-5f);
    float g0 = png[eidx * 128 + lane * 2], g1 = png[eidx * 128 + lane * 2 + 1];
    float b0 = pnb[eidx * 128 + lane * 2], b1 = pnb[eidx * 128 + lane * 2 + 1];
    float sc = esc[eidx];
    float wgt = gates[(size_t)node * 4 + eidx];
    float y0 = ((v.x - mean) * inv * g0 + b0) * sc;
    float y1 = ((v.y - mean) * inv * g1 + b1) * sc;
    float* op = Out + (size_t)node * 128 + lane * 2;
    float2 o = *(float2*)op;
    o.x = fmaf(wgt, y0, o.x); o.y = fmaf(wgt, y1, o.y);
    *(float2*)op = o;
}

// ---------- pool ----------
__global__ void pool_kernel(const float* __restrict__ Out, const int* __restrict__ batch,
                            float* __restrict__ pooled, int N)
{
    int idx = blockIdx.x * blockDim.x + threadIdx.x;
    if (idx >= N * 64) return;
    int node = idx >> 6, l = idx & 63;
    float2 v = *(const float2*)(Out + (size_t)node * 128 + l * 2);
    int b = batch[node];
    atomicAdd(&pooled[(size_t)b * 128 + l * 2], v.x);
    atomicAdd(&pooled[(size_t)b * 128 + l * 2 + 1], v.y);
}

// ---------- classification head; output dtype chosen at runtime ----------
__global__ void head_kernel(const float* __restrict__ pooled, const float* __restrict__ bcnt,
                            const float* __restrict__ h1W, const float* __restrict__ h1b,
                            const float* __restrict__ h1g, const float* __restrict__ h1be,
                            const float* __restrict__ h2W, const float* __restrict__ h2b,
                            const float* __restrict__ h2g, const float* __restrict__ h2be,
                            const float* __restrict__ h3W, const float* __restrict__ h3b,
                            const float* __restrict__ lbias,
                            const unsigned int* __restrict__ gate,
                            void* __restrict__ outp, int B)
{
    __shared__ float p[128], z[128];
    int b = blockIdx.x, t = threadIdx.x;
    float cnt = fmaxf(bcnt[b], 1.f);
    p[t] = pooled[(size_t)b * 128 + t] / cnt;
    __syncthreads();
    float a = h1b[t];
    for (int k = 0; k < 128; k++) a = fmaf(p[k], h1W[k * 128 + t], a);
    z[t] = a;
    __syncthreads();
    float s = 0.f, sq = 0.f;
    for (int k = 0; k < 128; k++) { float x = z[k]; s += x; sq += x * x; }
    float mean = s * (1.f / 128.f), var = sq * (1.f / 128.f) - mean * mean;
    float y = fmaxf((a - mean) * rsqrtf(var + 1e-5f) * h1g[t] + h1be[t], 0.f);
    __syncthreads();
    z[t] = y;
    __syncthreads();
    float a2 = 0.f;
    if (t < 64) {
        a2 = h2b[t];
        for (int k = 0; k < 128; k++) a2 = fmaf(z[k], h2W[k * 64 + t], a2);
    }
    __syncthreads();
    if (t < 64) p[t] = a2;
    __syncthreads();
    if (t < 2) {
        float s2 = 0.f, sq2 = 0.f;
        for (int k = 0; k < 64; k++) { float x = p[k]; s2 += x; sq2 += x * x; }
        float mean2 = s2 * (1.f / 64.f), var2 = sq2 * (1.f / 64.f) - mean2 * mean2;
        float inv2 = rsqrtf(var2 + 1e-5f);
        float o = h3b[t] + lbias[t];
        for (int k = 0; k < 64; k++) {
            float zc = fmaxf((p[k] - mean2) * inv2 * h2g[k] + h2be[k], 0.f);
            o = fmaf(zc, h3W[k * 2 + t], o);
        }
        if (gate[0] == BF16_MAGIC) ((ushort_t*)outp)[b * 2 + t] = f2b(o);
        else                       ((float*)outp)[b * 2 + t] = o;
    }
}

// ---------------- launch ----------------
extern "C" void kernel_launch(void* const* d_in, const int* in_sizes, int n_in,
                              void* d_out, int out_size, void* d_ws, size_t ws_size,
                              hipStream_t stream)
{
    (void)ws_size; (void)n_in;
    const int N = in_sizes[3];
    const int E = in_sizes[2] / 2;
    const int B = out_size / 2;

    const int* ei = (const int*)d_in[2];
    const int* src = ei;
    const int* dst = ei + E;
    const int* batch = (const int*)d_in[3];
    const unsigned int* gate = (const unsigned int*)d_in[6];  // fe_g = ones(128)

    size_t fN = (size_t)N;
    float* hr    = (float*)d_ws;       // 256N   (reused as t3/t4 after router)
    float* h     = hr + 256 * fN;      // 128N
    float* outb  = h + 128 * fN;       // 128N
    float* t0    = outb + 128 * fN;    // 128N
    float* t1    = t0 + 128 * fN;      // 128N
    float* t2    = t1 + 128 * fN;      // 128N
    float* gates = t2 + 128 * fN;      // 4N
    float* dinv  = gates + 4 * fN;     // N
    float* dinvl = dinv + fN;          // N
    float* bcnt  = dinvl + fN;         // 64
    float* pooled = bcnt + 64;         // 128*B
    float* wbase  = pooled + (size_t)128 * B;
    float* t3 = hr;
    float* t4 = hr + 128 * fN;

    // ---- conversion table: every float input -> fp32 at wbase+off ----
    ConvPack cp;
    float* cv[64];
    for (int i = 0; i < 64; i++) cv[i] = nullptr;
    int nc = 0;
    int off = 0;
    for (int i = 0; i < 47; i++) {
        if (i == 2 || i == 3) continue;  // edge_index, batch (int)
        cp.s[nc] = d_in[i];
        cp.off[nc] = off;
        cp.n[nc] = in_sizes[i];
        cv[i] = wbase + off;
        off += (in_sizes[i] + 3) & ~3;
        nc++;
    }
    int* degi   = (int*)(wbase + off);
    int* cursor = degi + N;
    int* rowptr = cursor + N;
    int* csr    = rowptr + (N + 1);

    dim3 blk(256);
    int gN4 = (N + 3) / 4;
    dim3 gG((N + 127) / 128);

    conv_all_kernel<<<dim3(64, nc), blk, 0, stream>>>(cp, wbase, gate);
    zero_i32_kernel<<<(2 * N + 255) / 256, blk, 0, stream>>>(degi, 2 * N);
    zero_f32_kernel<<<(64 + 128 * B + 255) / 256, blk, 0, stream>>>(bcnt, 64 + 128 * B);

    // encoders + fuse + router
    gemm_kernel<<<gG, blk, 0, stream>>>(cv[0], 200, cv[4], hr, 256, N, 200, cv[5], 0);
    gemm_kernel<<<gG, blk, 0, stream>>>(cv[1], 128, cv[8], hr + 128, 256, N, 128, cv[9], 0);
    ln_relu_kernel<<<gN4, blk, 0, stream>>>(hr, 256, cv[6], cv[7], N);
    ln_relu_kernel<<<gN4, blk, 0, stream>>>(hr + 128, 256, cv[10], cv[11], N);
    router_kernel<<<gN4, blk, 0, stream>>>(hr, cv[16], gates, N);
    gemm_kernel<<<gG, blk, 0, stream>>>(hr, 256, cv[12], h, 128, N, 256, cv[13], 0);
    ln_relu_kernel<<<gN4, blk, 0, stream>>>(h, 128, cv[14], cv[15], N);

    // graph structure (CSR by dst)
    edge_deg_kernel<<<(E + 255) / 256, blk, 0, stream>>>(dst, degi, E);
    batch_count_kernel<<<(N + 255) / 256, blk, 0, stream>>>(batch, bcnt, N);
    scan_kernel<<<1, blk, 0, stream>>>(degi, rowptr, N);
    csr_fill_kernel<<<(E + 255) / 256, blk, 0, stream>>>(src, dst, rowptr, cursor, csr, E);
    dinv_kernel<<<(N + 255) / 256, blk, 0, stream>>>(degi, dinv, dinvl, N);

    // residual accumulator: outb = h
    copy4_kernel<<<(int)((32 * fN + 255) / 256), blk, 0, stream>>>(
        (const float4*)h, (float4*)outb, (int)(32 * fN));

    // expert 0: MLP
    gemm_kernel<<<gG, blk, 0, stream>>>(h, 128, cv[17], t0, 128, N, 128, cv[18], RELUF);
    gemm_kernel<<<gG, blk, 0, stream>>>(t0, 128, cv[19], t1, 128, N, 128, cv[20], 0);
    combine_kernel<<<gN4, blk, 0, stream>>>(t1, gates, 0, cv[33], cv[34], cv[35], outb, N);

    // expert 1: ChebNet K=2
    gather_kernel<<<gN4, blk, 0, stream>>>(h, t0, rowptr, csr, dinv, 0, -1.f, (const float*)0, 0, N);
    gemm_kernel<<<gG, blk, 0, stream>>>(h, 128, cv[21] + 0 * 16384, t1, 128, N, 128, cv[22], 0);
    gemm_kernel<<<gG, blk, 0, stream>>>(t0, 128, cv[21] + 1 * 16384, t1, 128, N, 128, (const float*)0, ACCF | RELUF);
    gather_kernel<<<gN4, blk, 0, stream>>>(t1, t0, rowptr, csr, dinv, 0, -1.f, (const float*)0, 0, N);
    gemm_kernel<<<gG, blk, 0, stream>>>(t1, 128, cv[21] + 2 * 16384, t2, 128, N, 128, cv[22] + 128, 0);
    gemm_kernel<<<gG, blk, 0, stream>>>(t0, 128, cv[21] + 3 * 16384, t2, 128, N, 128, (const float*)0, ACCF);
    combine_kernel<<<gN4, blk, 0, stream>>>(t2, gates, 1, cv[33], cv[34], cv[35], outb, N);

    // expert 2: Graph Transformer (2 layers)
    gemm_kernel<<<gG, blk, 0, stream>>>(h, 128, cv[23], t0, 128, N, 128, cv[24], 0);   // q
    gemm_kernel<<<gG, blk, 0, stream>>>(h, 128, cv[25], t2, 128, N, 128, cv[26], 0);   // k
    gemm_kernel<<<gG, blk, 0, stream>>>(h, 128, cv[27], t3, 128, N, 128, cv[28], 0);   // v
    gt_attn_kernel<<<gN4, blk, 0, stream>>>(t0, t2, t3, rowptr, csr, t4, N);
    gemm_kernel<<<gG, blk, 0, stream>>>(h, 128, cv[29], t4, 128, N, 128, cv[30], ACCF | RELUF); // z1
    gemm_kernel<<<gG, blk, 0, stream>>>(t4, 128, cv[23] + 16384, t0, 128, N, 128, cv[24] + 128, 0);
    gemm_kernel<<<gG, blk, 0, stream>>>(t4, 128, cv[25] + 16384, t2, 128, N, 128, cv[26] + 128, 0);
    gemm_kernel<<<gG, blk, 0, stream>>>(t4, 128, cv[27] + 16384, t3, 128, N, 128, cv[28] + 128, 0);
    gt_attn_kernel<<<gN4, blk, 0, stream>>>(t0, t2, t3, rowptr, csr, t1, N);
    gemm_kernel<<<gG, blk, 0, stream>>>(t4, 128, cv[29] + 16384, t1, 128, N, 128, cv[30] + 128, ACCF);
    combine_kernel<<<gN4, blk, 0, stream>>>(t1, gates, 2, cv[33], cv[34], cv[35], outb, N);

    // expert 3: GCN (2 layers, self loops)
    gemm_kernel<<<gG, blk, 0, stream>>>(h, 128, cv[31], t0, 128, N, 128, (const float*)0, 0);
    gather_kernel<<<gN4, blk, 0, stream>>>(t0, t1, rowptr, csr, dinvl, 1, 1.f, cv[32], 1, N);
    gemm_kernel<<<gG, blk, 0, stream>>>(t1, 128, cv[31] + 16384, t0, 128, N, 128, (const float*)0, 0);
    gather_kernel<<<gN4, blk, 0, stream>>>(t0, t2, rowptr, csr, dinvl, 1, 1.f, cv[32] + 128, 0, N);
    combine_kernel<<<gN4, blk, 0, stream>>>(t2, gates, 3, cv[33], cv[34], cv[35], outb, N);

    // readout + head
    pool_kernel<<<(N * 64 + 255) / 256, blk, 0, stream>>>(outb, batch, pooled, N);
    head_kernel<<<dim3(B), dim3(128), 0, stream>>>(pooled, bcnt,
        cv[36], cv[37], cv[38], cv[39],
        cv[40], cv[41], cv[42], cv[43],
        cv[44], cv[45], cv[46],
        gate, d_out, B);
}

// Round 5
// 1310.505 us; speedup vs baseline: 1.1811x; 1.1811x over previous
//
#include <hip/hip_runtime.h>

#define RELUF 1
#define ACCF  2

// ---------------- utility kernels ----------------
__global__ void zero_i32_kernel(int* __restrict__ p, int n) {
    int i = blockIdx.x * blockDim.x + threadIdx.x;
    if (i < n) p[i] = 0;
}
__global__ void init_bounds_kernel(int* __restrict__ bstart, int* __restrict__ bend, int B, int N) {
    int i = blockIdx.x * blockDim.x + threadIdx.x;
    if (i < B) { bstart[i] = N; bend[i] = 0; }
}
__global__ void bounds_kernel(const int* __restrict__ batch, int* __restrict__ bstart,
                              int* __restrict__ bend, int N) {
    int n = blockIdx.x * blockDim.x + threadIdx.x;
    if (n >= N) return;
    int b = batch[n];
    atomicMin(&bstart[b], n);
    atomicMax(&bend[b], n + 1);
}

// ---------- GEMM: C[M,128] = A[M,K] @ W[K,128] (+bias)(+C)(relu), fp32 ----------
// 64x128 tile, 256 threads, 4x8 per thread. 469 blocks at M=30000 (~1.8/CU).
__global__ __launch_bounds__(256)
void gemm_kernel(const float* __restrict__ A, int lda,
                 const float* __restrict__ W,
                 float* __restrict__ C, int ldc,
                 int M, int K,
                 const float* __restrict__ bias, int flags)
{
    __shared__ float As[16][64];    // [k][m]
    __shared__ float Bs[16][128];   // [k][n]
    const int tid = threadIdx.x;
    const int m0 = blockIdx.x * 64;
    const int ty = tid >> 4, tx = tid & 15;
    const int ar = tid >> 2;          // 0..63 row in tile
    const int akg = (tid & 3) << 2;   // 0,4,8,12 k-offset
    const int wr = tid >> 4;          // 0..15 k-row for W staging
    const int wc = (tid & 15) << 3;   // 0..120 col for W staging
    const bool arow_ok = (m0 + ar) < M;
    const float* Arow = A + (size_t)(m0 + ar) * lda;

    float acc[4][8];
#pragma unroll
    for (int i = 0; i < 4; i++)
#pragma unroll
        for (int j = 0; j < 8; j++) acc[i][j] = 0.f;

    float av[4], wv[8];
    // prologue load (k0=0)
    {
        int kb = akg;
        if (arow_ok && kb + 4 <= K) {
            float4 p0 = *(const float4*)(Arow + kb);
            av[0] = p0.x; av[1] = p0.y; av[2] = p0.z; av[3] = p0.w;
        } else {
            for (int j = 0; j < 4; j++) {
                int k = kb + j;
                av[j] = (arow_ok && k < K) ? Arow[k] : 0.f;
            }
        }
        int kw = wr;
        if (kw < K) {
            float4 q0 = *(const float4*)(W + (size_t)kw * 128 + wc);
            float4 q1 = *(const float4*)(W + (size_t)kw * 128 + wc + 4);
            wv[0] = q0.x; wv[1] = q0.y; wv[2] = q0.z; wv[3] = q0.w;
            wv[4] = q1.x; wv[5] = q1.y; wv[6] = q1.z; wv[7] = q1.w;
        } else {
            for (int j = 0; j < 8; j++) wv[j] = 0.f;
        }
    }
    for (int k0 = 0; k0 < K; k0 += 16) {
        __syncthreads();
#pragma unroll
        for (int j = 0; j < 4; j++) As[akg + j][ar] = av[j];
#pragma unroll
        for (int j = 0; j < 8; j++) Bs[wr][wc + j] = wv[j];
        __syncthreads();
        if (k0 + 16 < K) {   // prefetch next tile while computing this one
            int kb = k0 + 16 + akg;
            if (arow_ok && kb + 4 <= K) {
                float4 p0 = *(const float4*)(Arow + kb);
                av[0] = p0.x; av[1] = p0.y; av[2] = p0.z; av[3] = p0.w;
            } else {
                for (int j = 0; j < 4; j++) {
                    int k = kb + j;
                    av[j] = (arow_ok && k < K) ? Arow[k] : 0.f;
                }
            }
            int kw = k0 + 16 + wr;
            if (kw < K) {
                float4 q0 = *(const float4*)(W + (size_t)kw * 128 + wc);
                float4 q1 = *(const float4*)(W + (size_t)kw * 128 + wc + 4);
                wv[0] = q0.x; wv[1] = q0.y; wv[2] = q0.z; wv[3] = q0.w;
                wv[4] = q1.x; wv[5] = q1.y; wv[6] = q1.z; wv[7] = q1.w;
            } else {
                for (int j = 0; j < 8; j++) wv[j] = 0.f;
            }
        }
#pragma unroll
        for (int kk = 0; kk < 16; kk++) {
            float4 a0 = *(const float4*)&As[kk][ty * 4];
            float4 w0 = *(const float4*)&Bs[kk][tx * 4];
            float4 w1 = *(const float4*)&Bs[kk][64 + tx * 4];
            float aa[4] = {a0.x, a0.y, a0.z, a0.w};
            float ww[8] = {w0.x, w0.y, w0.z, w0.w, w1.x, w1.y, w1.z, w1.w};
#pragma unroll
            for (int i = 0; i < 4; i++)
#pragma unroll
                for (int j = 0; j < 8; j++) acc[i][j] = fmaf(aa[i], ww[j], acc[i][j]);
        }
    }
#pragma unroll
    for (int i = 0; i < 4; i++) {
        int gm = m0 + ty * 4 + i;
        if (gm >= M) continue;
        float* crow = C + (size_t)gm * ldc;
#pragma unroll
        for (int jh = 0; jh < 2; jh++) {
            int gn = jh * 64 + tx * 4;
            float4 r = make_float4(acc[i][jh * 4 + 0], acc[i][jh * 4 + 1],
                                   acc[i][jh * 4 + 2], acc[i][jh * 4 + 3]);
            if (bias) {
                float4 bb = *(const float4*)(bias + gn);
                r.x += bb.x; r.y += bb.y; r.z += bb.z; r.w += bb.w;
            }
            if (flags & ACCF) {
                float4 c0 = *(const float4*)(crow + gn);
                r.x += c0.x; r.y += c0.y; r.z += c0.z; r.w += c0.w;
            }
            if (flags & RELUF) {
                r.x = fmaxf(r.x, 0.f); r.y = fmaxf(r.y, 0.f);
                r.z = fmaxf(r.z, 0.f); r.w = fmaxf(r.w, 0.f);
            }
            *(float4*)(crow + gn) = r;
        }
    }
}

// ---------- LayerNorm(128) + ReLU in place ----------
__global__ void ln_relu_kernel(float* __restrict__ X, int ld,
                               const float* __restrict__ g,
                               const float* __restrict__ b, int M)
{
    int node = blockIdx.x * 4 + (threadIdx.x >> 6);
    int lane = threadIdx.x & 63;
    if (node >= M) return;
    float* row = X + (size_t)node * ld;
    float2 v = *(float2*)(row + lane * 2);
    float s = v.x + v.y, sq = v.x * v.x + v.y * v.y;
#pragma unroll
    for (int off = 32; off; off >>= 1) { s += __shfl_xor(s, off); sq += __shfl_xor(sq, off); }
    float mean = s * (1.f / 128.f);
    float var = sq * (1.f / 128.f) - mean * mean;
    float inv = rsqrtf(var + 1e-5f);
    float y0 = fmaxf((v.x - mean) * inv * g[lane * 2] + b[lane * 2], 0.f);
    float y1 = fmaxf((v.y - mean) * inv * g[lane * 2 + 1] + b[lane * 2 + 1], 0.f);
    *(float2*)(row + lane * 2) = make_float2(y0, y1);
}

// ---------- router ----------
__global__ void router_kernel(const float* __restrict__ hr, const float* __restrict__ rW,
                              float* __restrict__ gates, int M)
{
    int node = blockIdx.x * 4 + (threadIdx.x >> 6);
    int lane = threadIdx.x & 63;
    if (node >= M) return;
    const float* row = hr + (size_t)node * 256;
    float a0 = 0, a1 = 0, a2 = 0, a3 = 0;
#pragma unroll
    for (int i = 0; i < 4; i++) {
        int k = lane + i * 64;
        float xv = row[k];
        float4 wv = *(const float4*)(rW + k * 4);
        a0 = fmaf(xv, wv.x, a0); a1 = fmaf(xv, wv.y, a1);
        a2 = fmaf(xv, wv.z, a2); a3 = fmaf(xv, wv.w, a3);
    }
#pragma unroll
    for (int off = 32; off; off >>= 1) {
        a0 += __shfl_xor(a0, off); a1 += __shfl_xor(a1, off);
        a2 += __shfl_xor(a2, off); a3 += __shfl_xor(a3, off);
    }
    if (lane == 0) {
        float l[4] = {a0 * (1.f / 1.5f), a1 * (1.f / 1.5f), a2 * (1.f / 1.5f), a3 * (1.f / 1.5f)};
        float mx = fmaxf(fmaxf(l[0], l[1]), fmaxf(l[2], l[3]));
        float e[4], ssum = 0.f;
#pragma unroll
        for (int i = 0; i < 4; i++) { e[i] = expf(l[i] - mx); ssum += e[i]; }
        float p[4];
#pragma unroll
        for (int i = 0; i < 4; i++) p[i] = e[i] / ssum;
        int i0 = 0;
        for (int i = 1; i < 4; i++) if (p[i] > p[i0]) i0 = i;
        int i1 = -1;
        for (int i = 0; i < 4; i++) {
            if (i == i0) continue;
            if (i1 < 0 || p[i] > p[i1]) i1 = i;
        }
        float wsum = fmaxf(p[i0] + p[i1], 1e-9f);
        float gg[4] = {0.f, 0.f, 0.f, 0.f};
        gg[i0] = p[i0] / wsum;
        gg[i1] = p[i1] / wsum;
        *(float4*)(gates + (size_t)node * 4) = make_float4(gg[0], gg[1], gg[2], gg[3]);
    }
}

// ---------- graph structure ----------
__global__ void edge_deg_kernel(const int* __restrict__ dst, int* __restrict__ degi, int E) {
    int e = blockIdx.x * blockDim.x + threadIdx.x;
    if (e < E) atomicAdd(&degi[dst[e]], 1);
}
__global__ void scan_kernel(const int* __restrict__ degi, int* __restrict__ rowptr, int n) {
    __shared__ int sh[256];
    __shared__ int sbase;
    int tid = threadIdx.x;
    if (tid == 0) { sbase = 0; rowptr[0] = 0; }
    __syncthreads();
    const int CH = 256 * 8;
    for (int c0 = 0; c0 < n; c0 += CH) {
        int loc[8]; int s = 0;
        int base_i = c0 + tid * 8;
#pragma unroll
        for (int j = 0; j < 8; j++) {
            int idx = base_i + j;
            int v = (idx < n) ? degi[idx] : 0;
            s += v; loc[j] = s;
        }
        sh[tid] = s;
        __syncthreads();
        for (int off = 1; off < 256; off <<= 1) {
            int t = (tid >= off) ? sh[tid - off] : 0;
            __syncthreads();
            sh[tid] += t;
            __syncthreads();
        }
        int prev = (tid > 0) ? sh[tid - 1] : 0;
        int b = sbase;
        int total = sh[255];
#pragma unroll
        for (int j = 0; j < 8; j++) {
            int idx = base_i + j;
            if (idx < n) rowptr[idx + 1] = b + prev + loc[j];
        }
        __syncthreads();
        if (tid == 0) sbase = b + total;
        __syncthreads();
    }
}
__global__ void csr_fill_kernel(const int* __restrict__ src, const int* __restrict__ dst,
                                const int* __restrict__ rowptr, int* __restrict__ cursor,
                                int* __restrict__ csr, int E) {
    int e = blockIdx.x * blockDim.x + threadIdx.x;
    if (e >= E) return;
    int d = dst[e];
    int pos = atomicAdd(&cursor[d], 1);
    csr[rowptr[d] + pos] = src[e];
}
__global__ void dinv_kernel(const int* __restrict__ degi, float* __restrict__ dinv,
                            float* __restrict__ dinvl, int N) {
    int n = blockIdx.x * blockDim.x + threadIdx.x;
    if (n >= N) return;
    float deg = (float)degi[n];
    dinv[n] = (deg > 0.f) ? rsqrtf(fmaxf(deg, 1.f)) : 0.f;
    dinvl[n] = rsqrtf(deg + 1.f);
}

// ---------- gather propagation ----------
__global__ void gather_kernel(const float* __restrict__ X, float* __restrict__ Out,
                              const int* __restrict__ rowptr, const int* __restrict__ csr,
                              const float* __restrict__ dv, int self_loop, float scale,
                              const float* __restrict__ bias, int relu, int M)
{
    int node = blockIdx.x * 4 + (threadIdx.x >> 6);
    int lane = threadIdx.x & 63;
    if (node >= M) return;
    int beg = rowptr[node], end = rowptr[node + 1];
    float dn = dv[node];
    float ax = 0.f, ay = 0.f;
    int e = beg;
    for (; e + 3 < end; e += 4) {
        int s0 = csr[e], s1 = csr[e + 1], s2 = csr[e + 2], s3 = csr[e + 3];
        float c0 = dn * dv[s0], c1 = dn * dv[s1], c2 = dn * dv[s2], c3 = dn * dv[s3];
        float2 x0 = *(const float2*)(X + (size_t)s0 * 128 + lane * 2);
        float2 x1 = *(const float2*)(X + (size_t)s1 * 128 + lane * 2);
        float2 x2 = *(const float2*)(X + (size_t)s2 * 128 + lane * 2);
        float2 x3 = *(const float2*)(X + (size_t)s3 * 128 + lane * 2);
        ax = fmaf(c0, x0.x, fmaf(c1, x1.x, fmaf(c2, x2.x, fmaf(c3, x3.x, ax))));
        ay = fmaf(c0, x0.y, fmaf(c1, x1.y, fmaf(c2, x2.y, fmaf(c3, x3.y, ay))));
    }
    for (; e < end; e++) {
        int s = csr[e];
        float c = dn * dv[s];
        float2 xv = *(const float2*)(X + (size_t)s * 128 + lane * 2);
        ax = fmaf(c, xv.x, ax); ay = fmaf(c, xv.y, ay);
    }
    if (self_loop) {
        float c = dn * dn;
        float2 xv = *(const float2*)(X + (size_t)node * 128 + lane * 2);
        ax = fmaf(c, xv.x, ax); ay = fmaf(c, xv.y, ay);
    }
    ax *= scale; ay *= scale;
    if (bias) { ax += bias[lane * 2]; ay += bias[lane * 2 + 1]; }
    if (relu) { ax = fmaxf(ax, 0.f); ay = fmaxf(ay, 0.f); }
    *(float2*)(Out + (size_t)node * 128 + lane * 2) = make_float2(ax, ay);
}

// ---------- graph-transformer attention: single-pass online softmax ----------
__global__ void gt_attn_kernel(const float* __restrict__ Q, const float* __restrict__ Km,
                               const float* __restrict__ V, const int* __restrict__ rowptr,
                               const int* __restrict__ csr, float* __restrict__ Out, int M)
{
    const float SC = 0.17677669529663689f; // 1/sqrt(32)
    int node = blockIdx.x * 4 + (threadIdx.x >> 6);
    int lane = threadIdx.x & 63;
    if (node >= M) return;
    int beg = rowptr[node], end = rowptr[node + 1];
    float2 q = *(const float2*)(Q + (size_t)node * 128 + lane * 2);
    float m = -1e30f, den = 0.f, ax = 0.f, ay = 0.f;
    for (int e = beg; e < end; e++) {
        int s = csr[e];
        float2 kv = *(const float2*)(Km + (size_t)s * 128 + lane * 2);
        float2 vv = *(const float2*)(V + (size_t)s * 128 + lane * 2);
        float p = q.x * kv.x + q.y * kv.y;
        p += __shfl_xor(p, 1); p += __shfl_xor(p, 2); p += __shfl_xor(p, 4); p += __shfl_xor(p, 8);
        float logit = p * SC;
        float mn = fmaxf(m, logit);
        float scale = expf(m - mn);
        float w = expf(logit - mn);
        den = den * scale + w;
        ax = ax * scale + w * vv.x;
        ay = ay * scale + w * vv.y;
        m = mn;
    }
    float d = fmaxf(den, 1e-9f);
    *(float2*)(Out + (size_t)node * 128 + lane * 2) = make_float2(ax / d, ay / d);
}

// ---------- fused: out = h + sum_e gates[e] * (LN(e_i)*scale_e) ----------
__global__ void combine4_kernel(const float* __restrict__ h,
                                const float* __restrict__ e0, const float* __restrict__ e1,
                                const float* __restrict__ e2, const float* __restrict__ e3,
                                const float* __restrict__ gates,
                                const float* __restrict__ png, const float* __restrict__ pnb,
                                const float* __restrict__ esc,
                                float* __restrict__ Out, int M)
{
    int node = blockIdx.x * 4 + (threadIdx.x >> 6);
    int lane = threadIdx.x & 63;
    if (node >= M) return;
    size_t ofs = (size_t)node * 128 + lane * 2;
    const float* ep[4] = {e0 + ofs, e1 + ofs, e2 + ofs, e3 + ofs};
    float4 gg = *(const float4*)(gates + (size_t)node * 4);
    float gv[4] = {gg.x, gg.y, gg.z, gg.w};
    float2 hv = *(const float2*)(h + ofs);
    float ox = hv.x, oy = hv.y;
#pragma unroll
    for (int e = 0; e < 4; e++) {
        float2 v = *(const float2*)ep[e];
        float s = v.x + v.y, sq = v.x * v.x + v.y * v.y;
#pragma unroll
        for (int off = 32; off; off >>= 1) { s += __shfl_xor(s, off); sq += __shfl_xor(sq, off); }
        float mean = s * (1.f / 128.f);
        float var = sq * (1.f / 128.f) - mean * mean;
        float inv = rsqrtf(var + 1e-5f);
        float g0 = png[e * 128 + lane * 2], g1 = png[e * 128 + lane * 2 + 1];
        float b0 = pnb[e * 128 + lane * 2], b1 = pnb[e * 128 + lane * 2 + 1];
        float c = esc[e] * gv[e];
        ox = fmaf(c, (v.x - mean) * inv * g0 + b0, ox);
        oy = fmaf(c, (v.y - mean) * inv * g1 + b1, oy);
    }
    *(float2*)(Out + ofs) = make_float2(ox, oy);
}

// ---------- segmented mean-pool (batch sorted -> contiguous ranges) ----------
__global__ void pool_seg_kernel(const float* __restrict__ Out,
                                const int* __restrict__ bstart, const int* __restrict__ bend,
                                float* __restrict__ pooled)
{
    int b = blockIdx.x, t = threadIdx.x;  // 128 threads
    int s = bstart[b], e = bend[b];
    float sum = 0.f;
    for (int n = s; n < e; n++) sum += Out[(size_t)n * 128 + t];
    float cnt = fmaxf((float)(e - s), 1.f);
    pooled[(size_t)b * 128 + t] = sum / cnt;
}

// ---------- classification head (fp32 out) ----------
__global__ void head_kernel(const float* __restrict__ pooled,
                            const float* __restrict__ h1W, const float* __restrict__ h1b,
                            const float* __restrict__ h1g, const float* __restrict__ h1be,
                            const float* __restrict__ h2W, const float* __restrict__ h2b,
                            const float* __restrict__ h2g, const float* __restrict__ h2be,
                            const float* __restrict__ h3W, const float* __restrict__ h3b,
                            const float* __restrict__ lbias,
                            float* __restrict__ out, int B)
{
    __shared__ float p[128], z[128];
    int b = blockIdx.x, t = threadIdx.x;
    p[t] = pooled[(size_t)b * 128 + t];
    __syncthreads();
    float a = h1b[t];
    for (int k = 0; k < 128; k++) a = fmaf(p[k], h1W[k * 128 + t], a);
    z[t] = a;
    __syncthreads();
    float s = 0.f, sq = 0.f;
    for (int k = 0; k < 128; k++) { float x = z[k]; s += x; sq += x * x; }
    float mean = s * (1.f / 128.f), var = sq * (1.f / 128.f) - mean * mean;
    float y = fmaxf((a - mean) * rsqrtf(var + 1e-5f) * h1g[t] + h1be[t], 0.f);
    __syncthreads();
    z[t] = y;
    __syncthreads();
    float a2 = 0.f;
    if (t < 64) {
        a2 = h2b[t];
        for (int k = 0; k < 128; k++) a2 = fmaf(z[k], h2W[k * 64 + t], a2);
    }
    __syncthreads();
    if (t < 64) p[t] = a2;
    __syncthreads();
    if (t < 2) {
        float s2 = 0.f, sq2 = 0.f;
        for (int k = 0; k < 64; k++) { float x = p[k]; s2 += x; sq2 += x * x; }
        float mean2 = s2 * (1.f / 64.f), var2 = sq2 * (1.f / 64.f) - mean2 * mean2;
        float inv2 = rsqrtf(var2 + 1e-5f);
        float o = h3b[t] + lbias[t];
        for (int k = 0; k < 64; k++) {
            float zc = fmaxf((p[k] - mean2) * inv2 * h2g[k] + h2be[k], 0.f);
            o = fmaf(zc, h3W[k * 2 + t], o);
        }
        out[b * 2 + t] = o;
    }
}

// ---------------- launch ----------------
extern "C" void kernel_launch(void* const* d_in, const int* in_sizes, int n_in,
                              void* d_out, int out_size, void* d_ws, size_t ws_size,
                              hipStream_t stream)
{
    (void)ws_size; (void)n_in;
    const int N = in_sizes[3];
    const int E = in_sizes[2] / 2;
    const int B = out_size / 2;

    const int* ei = (const int*)d_in[2];
    const int* src = ei;
    const int* dst = ei + E;
    const int* batch = (const int*)d_in[3];

    // fp32 input pointers (verified round 4: inputs are fp32, output fp32)
    const float* W[47];
    for (int i = 0; i < 47; i++) W[i] = (const float*)d_in[i];

    size_t fN = (size_t)N;
    float* hr    = (float*)d_ws;        // 256N: bufA = hr, bufB = hr+128N after router
    float* h     = hr + 256 * fN;       // 128N
    float* e0    = h + 128 * fN;        // 128N
    float* e1    = e0 + 128 * fN;       // 128N
    float* e2    = e1 + 128 * fN;       // 128N
    float* e3    = e2 + 128 * fN;       // 128N
    float* tmp0  = e3 + 128 * fN;       // 128N (v buf; later outb)
    float* tmp1  = tmp0 + 128 * fN;     // 128N (agg/z1 buf)
    float* gates = tmp1 + 128 * fN;     // 4N
    float* dinv  = gates + 4 * fN;      // N
    float* dinvl = dinv + fN;           // N
    float* pooled = dinvl + fN;         // 128*B
    int* degi   = (int*)(pooled + (size_t)128 * B);
    int* cursor = degi + N;
    int* rowptr = cursor + N;
    int* csr    = rowptr + (N + 1);
    int* bstart = csr + E;
    int* bend   = bstart + B;
    float* bufA = hr;
    float* bufB = hr + 128 * fN;
    float* outb = tmp0;

    dim3 blk(256);
    int gN4 = (N + 3) / 4;
    dim3 gG((N + 63) / 64);

    zero_i32_kernel<<<(2 * N + 255) / 256, blk, 0, stream>>>(degi, 2 * N);
    init_bounds_kernel<<<1, blk, 0, stream>>>(bstart, bend, B, N);
    bounds_kernel<<<(N + 255) / 256, blk, 0, stream>>>(batch, bstart, bend, N);

    // encoders + fuse + router
    gemm_kernel<<<gG, blk, 0, stream>>>(W[0], 200, W[4], hr, 256, N, 200, W[5], 0);
    gemm_kernel<<<gG, blk, 0, stream>>>(W[1], 128, W[8], hr + 128, 256, N, 128, W[9], 0);
    ln_relu_kernel<<<gN4, blk, 0, stream>>>(hr, 256, W[6], W[7], N);
    ln_relu_kernel<<<gN4, blk, 0, stream>>>(hr + 128, 256, W[10], W[11], N);
    router_kernel<<<gN4, blk, 0, stream>>>(hr, W[16], gates, N);
    gemm_kernel<<<gG, blk, 0, stream>>>(hr, 256, W[12], h, 128, N, 256, W[13], 0);
    ln_relu_kernel<<<gN4, blk, 0, stream>>>(h, 128, W[14], W[15], N);

    // graph structure (CSR by dst)
    edge_deg_kernel<<<(E + 255) / 256, blk, 0, stream>>>(dst, degi, E);
    scan_kernel<<<1, blk, 0, stream>>>(degi, rowptr, N);
    csr_fill_kernel<<<(E + 255) / 256, blk, 0, stream>>>(src, dst, rowptr, cursor, csr, E);
    dinv_kernel<<<(N + 255) / 256, blk, 0, stream>>>(degi, dinv, dinvl, N);

    // expert 0: MLP  (hr free after fuse GEMM)
    gemm_kernel<<<gG, blk, 0, stream>>>(h, 128, W[17], bufA, 128, N, 128, W[18], RELUF);
    gemm_kernel<<<gG, blk, 0, stream>>>(bufA, 128, W[19], e0, 128, N, 128, W[20], 0);

    // expert 1: ChebNet K=2
    gather_kernel<<<gN4, blk, 0, stream>>>(h, bufA, rowptr, csr, dinv, 0, -1.f, (const float*)0, 0, N);
    gemm_kernel<<<gG, blk, 0, stream>>>(h, 128, W[21] + 0 * 16384, bufB, 128, N, 128, W[22], 0);
    gemm_kernel<<<gG, blk, 0, stream>>>(bufA, 128, W[21] + 1 * 16384, bufB, 128, N, 128, (const float*)0, ACCF | RELUF);
    gather_kernel<<<gN4, blk, 0, stream>>>(bufB, bufA, rowptr, csr, dinv, 0, -1.f, (const float*)0, 0, N);
    gemm_kernel<<<gG, blk, 0, stream>>>(bufB, 128, W[21] + 2 * 16384, e1, 128, N, 128, W[22] + 128, 0);
    gemm_kernel<<<gG, blk, 0, stream>>>(bufA, 128, W[21] + 3 * 16384, e1, 128, N, 128, (const float*)0, ACCF);

    // expert 3: GCN (2 layers, self loops)
    gemm_kernel<<<gG, blk, 0, stream>>>(h, 128, W[31], bufA, 128, N, 128, (const float*)0, 0);
    gather_kernel<<<gN4, blk, 0, stream>>>(bufA, bufB, rowptr, csr, dinvl, 1, 1.f, W[32], 1, N);
    gemm_kernel<<<gG, blk, 0, stream>>>(bufB, 128, W[31] + 16384, bufA, 128, N, 128, (const float*)0, 0);
    gather_kernel<<<gN4, blk, 0, stream>>>(bufA, e3, rowptr, csr, dinvl, 1, 1.f, W[32] + 128, 0, N);

    // expert 2: Graph Transformer (2 layers)
    gemm_kernel<<<gG, blk, 0, stream>>>(h, 128, W[23], bufA, 128, N, 128, W[24], 0);   // q
    gemm_kernel<<<gG, blk, 0, stream>>>(h, 128, W[25], bufB, 128, N, 128, W[26], 0);   // k
    gemm_kernel<<<gG, blk, 0, stream>>>(h, 128, W[27], tmp0, 128, N, 128, W[28], 0);   // v
    gt_attn_kernel<<<gN4, blk, 0, stream>>>(bufA, bufB, tmp0, rowptr, csr, tmp1, N);
    gemm_kernel<<<gG, blk, 0, stream>>>(h, 128, W[29], tmp1, 128, N, 128, W[30], ACCF | RELUF); // z1
    gemm_kernel<<<gG, blk, 0, stream>>>(tmp1, 128, W[23] + 16384, bufA, 128, N, 128, W[24] + 128, 0);
    gemm_kernel<<<gG, blk, 0, stream>>>(tmp1, 128, W[25] + 16384, bufB, 128, N, 128, W[26] + 128, 0);
    gemm_kernel<<<gG, blk, 0, stream>>>(tmp1, 128, W[27] + 16384, tmp0, 128, N, 128, W[28] + 128, 0);
    gt_attn_kernel<<<gN4, blk, 0, stream>>>(bufA, bufB, tmp0, rowptr, csr, e2, N);
    gemm_kernel<<<gG, blk, 0, stream>>>(tmp1, 128, W[29] + 16384, e2, 128, N, 128, W[30] + 128, ACCF);

    // fused combine + segmented pool + head
    combine4_kernel<<<gN4, blk, 0, stream>>>(h, e0, e1, e2, e3, gates,
                                             W[33], W[34], W[35], outb, N);
    pool_seg_kernel<<<dim3(B), dim3(128), 0, stream>>>(outb, bstart, bend, pooled);
    head_kernel<<<dim3(B), dim3(128), 0, stream>>>(pooled,
        W[36], W[37], W[38], W[39],
        W[40], W[41], W[42], W[43],
        W[44], W[45], W[46],
        (float*)d_out, B);
}

// Round 6
// 1140.908 us; speedup vs baseline: 1.3567x; 1.1487x over previous
//
#include <hip/hip_runtime.h>

#define RELUF 1
#define ACCF  2

typedef unsigned short ushort_t;

__device__ __forceinline__ float bf2f(unsigned int v) {
    return __uint_as_float(v << 16);
}
__device__ __forceinline__ ushort_t f2b(float f) {
    unsigned int u = __float_as_uint(f);
    return (ushort_t)((u + 0x7fffu + ((u >> 16) & 1u)) >> 16);
}

// ---------------- utility kernels ----------------
__global__ void zero_i32_kernel(int* __restrict__ p, int n) {
    int i = blockIdx.x * blockDim.x + threadIdx.x;
    if (i < n) p[i] = 0;
}
// batch is sorted: boundary detection, no atomics
__global__ void seg_bounds_kernel(const int* __restrict__ batch, int* __restrict__ bstart,
                                  int* __restrict__ bend, int N) {
    int n = blockIdx.x * blockDim.x + threadIdx.x;
    if (n >= N) return;
    int b = batch[n];
    if (n == 0) bstart[b] = 0;
    else {
        int pb = batch[n - 1];
        if (pb != b) { bstart[b] = n; bend[pb] = n; }
    }
    if (n == N - 1) bend[b] = N;
}

// ---------- GEMM: C[M,128] = A[M,K] @ W[K,128] (+bias)(+C)(relu), fp32 ----------
// optional bf16 shadow copy Cb (for gather/attn consumers).
// 64x128 tile, 256 threads, 4x8 per thread.
__global__ __launch_bounds__(256)
void gemm_kernel(const float* __restrict__ A, int lda,
                 const float* __restrict__ W,
                 float* __restrict__ C, int ldc,
                 int M, int K,
                 const float* __restrict__ bias, int flags,
                 ushort_t* __restrict__ Cb)
{
    __shared__ float As[16][64];    // [k][m]
    __shared__ float Bs[16][128];   // [k][n]
    const int tid = threadIdx.x;
    const int m0 = blockIdx.x * 64;
    const int ty = tid >> 4, tx = tid & 15;
    const int ar = tid >> 2;          // 0..63 row in tile
    const int akg = (tid & 3) << 2;   // 0,4,8,12 k-offset
    const int wr = tid >> 4;          // 0..15 k-row for W staging
    const int wc = (tid & 15) << 3;   // 0..120 col for W staging
    const bool arow_ok = (m0 + ar) < M;
    const float* Arow = A + (size_t)(m0 + ar) * lda;

    float acc[4][8];
#pragma unroll
    for (int i = 0; i < 4; i++)
#pragma unroll
        for (int j = 0; j < 8; j++) acc[i][j] = 0.f;

    float av[4], wv[8];
    {
        int kb = akg;
        if (arow_ok && kb + 4 <= K) {
            float4 p0 = *(const float4*)(Arow + kb);
            av[0] = p0.x; av[1] = p0.y; av[2] = p0.z; av[3] = p0.w;
        } else {
            for (int j = 0; j < 4; j++) {
                int k = kb + j;
                av[j] = (arow_ok && k < K) ? Arow[k] : 0.f;
            }
        }
        int kw = wr;
        if (kw < K) {
            float4 q0 = *(const float4*)(W + (size_t)kw * 128 + wc);
            float4 q1 = *(const float4*)(W + (size_t)kw * 128 + wc + 4);
            wv[0] = q0.x; wv[1] = q0.y; wv[2] = q0.z; wv[3] = q0.w;
            wv[4] = q1.x; wv[5] = q1.y; wv[6] = q1.z; wv[7] = q1.w;
        } else {
            for (int j = 0; j < 8; j++) wv[j] = 0.f;
        }
    }
    for (int k0 = 0; k0 < K; k0 += 16) {
        __syncthreads();
#pragma unroll
        for (int j = 0; j < 4; j++) As[akg + j][ar] = av[j];
#pragma unroll
        for (int j = 0; j < 8; j++) Bs[wr][wc + j] = wv[j];
        __syncthreads();
        if (k0 + 16 < K) {
            int kb = k0 + 16 + akg;
            if (arow_ok && kb + 4 <= K) {
                float4 p0 = *(const float4*)(Arow + kb);
                av[0] = p0.x; av[1] = p0.y; av[2] = p0.z; av[3] = p0.w;
            } else {
                for (int j = 0; j < 4; j++) {
                    int k = kb + j;
                    av[j] = (arow_ok && k < K) ? Arow[k] : 0.f;
                }
            }
            int kw = k0 + 16 + wr;
            if (kw < K) {
                float4 q0 = *(const float4*)(W + (size_t)kw * 128 + wc);
                float4 q1 = *(const float4*)(W + (size_t)kw * 128 + wc + 4);
                wv[0] = q0.x; wv[1] = q0.y; wv[2] = q0.z; wv[3] = q0.w;
                wv[4] = q1.x; wv[5] = q1.y; wv[6] = q1.z; wv[7] = q1.w;
            } else {
                for (int j = 0; j < 8; j++) wv[j] = 0.f;
            }
        }
#pragma unroll
        for (int kk = 0; kk < 16; kk++) {
            float4 a0 = *(const float4*)&As[kk][ty * 4];
            float4 w0 = *(const float4*)&Bs[kk][tx * 4];
            float4 w1 = *(const float4*)&Bs[kk][64 + tx * 4];
            float aa[4] = {a0.x, a0.y, a0.z, a0.w};
            float ww[8] = {w0.x, w0.y, w0.z, w0.w, w1.x, w1.y, w1.z, w1.w};
#pragma unroll
            for (int i = 0; i < 4; i++)
#pragma unroll
                for (int j = 0; j < 8; j++) acc[i][j] = fmaf(aa[i], ww[j], acc[i][j]);
        }
    }
#pragma unroll
    for (int i = 0; i < 4; i++) {
        int gm = m0 + ty * 4 + i;
        if (gm >= M) continue;
        float* crow = C + (size_t)gm * ldc;
#pragma unroll
        for (int jh = 0; jh < 2; jh++) {
            int gn = jh * 64 + tx * 4;
            float4 r = make_float4(acc[i][jh * 4 + 0], acc[i][jh * 4 + 1],
                                   acc[i][jh * 4 + 2], acc[i][jh * 4 + 3]);
            if (bias) {
                float4 bb = *(const float4*)(bias + gn);
                r.x += bb.x; r.y += bb.y; r.z += bb.z; r.w += bb.w;
            }
            if (flags & ACCF) {
                float4 c0 = *(const float4*)(crow + gn);
                r.x += c0.x; r.y += c0.y; r.z += c0.z; r.w += c0.w;
            }
            if (flags & RELUF) {
                r.x = fmaxf(r.x, 0.f); r.y = fmaxf(r.y, 0.f);
                r.z = fmaxf(r.z, 0.f); r.w = fmaxf(r.w, 0.f);
            }
            *(float4*)(crow + gn) = r;
            if (Cb) {
                unsigned int lo = (unsigned int)f2b(r.x) | ((unsigned int)f2b(r.y) << 16);
                unsigned int hi = (unsigned int)f2b(r.z) | ((unsigned int)f2b(r.w) << 16);
                *(uint2*)(Cb + (size_t)gm * 128 + gn) = make_uint2(lo, hi);
            }
        }
    }
}

// ---------- LayerNorm(128) + ReLU in place (+ optional bf16 shadow) ----------
__global__ void ln_relu_kernel(float* __restrict__ X, int ld,
                               const float* __restrict__ g,
                               const float* __restrict__ b, int M,
                               ushort_t* __restrict__ Xb)
{
    int node = blockIdx.x * 4 + (threadIdx.x >> 6);
    int lane = threadIdx.x & 63;
    if (node >= M) return;
    float* row = X + (size_t)node * ld;
    float2 v = *(float2*)(row + lane * 2);
    float s = v.x + v.y, sq = v.x * v.x + v.y * v.y;
#pragma unroll
    for (int off = 32; off; off >>= 1) { s += __shfl_xor(s, off); sq += __shfl_xor(sq, off); }
    float mean = s * (1.f / 128.f);
    float var = sq * (1.f / 128.f) - mean * mean;
    float inv = rsqrtf(var + 1e-5f);
    float y0 = fmaxf((v.x - mean) * inv * g[lane * 2] + b[lane * 2], 0.f);
    float y1 = fmaxf((v.y - mean) * inv * g[lane * 2 + 1] + b[lane * 2 + 1], 0.f);
    *(float2*)(row + lane * 2) = make_float2(y0, y1);
    if (Xb) {
        unsigned int p = (unsigned int)f2b(y0) | ((unsigned int)f2b(y1) << 16);
        *(unsigned int*)(Xb + (size_t)node * 128 + lane * 2) = p;
    }
}

// ---------- router ----------
__global__ void router_kernel(const float* __restrict__ hr, const float* __restrict__ rW,
                              float* __restrict__ gates, int M)
{
    int node = blockIdx.x * 4 + (threadIdx.x >> 6);
    int lane = threadIdx.x & 63;
    if (node >= M) return;
    const float* row = hr + (size_t)node * 256;
    float a0 = 0, a1 = 0, a2 = 0, a3 = 0;
#pragma unroll
    for (int i = 0; i < 4; i++) {
        int k = lane + i * 64;
        float xv = row[k];
        float4 wv = *(const float4*)(rW + k * 4);
        a0 = fmaf(xv, wv.x, a0); a1 = fmaf(xv, wv.y, a1);
        a2 = fmaf(xv, wv.z, a2); a3 = fmaf(xv, wv.w, a3);
    }
#pragma unroll
    for (int off = 32; off; off >>= 1) {
        a0 += __shfl_xor(a0, off); a1 += __shfl_xor(a1, off);
        a2 += __shfl_xor(a2, off); a3 += __shfl_xor(a3, off);
    }
    if (lane == 0) {
        float l[4] = {a0 * (1.f / 1.5f), a1 * (1.f / 1.5f), a2 * (1.f / 1.5f), a3 * (1.f / 1.5f)};
        float mx = fmaxf(fmaxf(l[0], l[1]), fmaxf(l[2], l[3]));
        float e[4], ssum = 0.f;
#pragma unroll
        for (int i = 0; i < 4; i++) { e[i] = expf(l[i] - mx); ssum += e[i]; }
        float p[4];
#pragma unroll
        for (int i = 0; i < 4; i++) p[i] = e[i] / ssum;
        int i0 = 0;
        for (int i = 1; i < 4; i++) if (p[i] > p[i0]) i0 = i;
        int i1 = -1;
        for (int i = 0; i < 4; i++) {
            if (i == i0) continue;
            if (i1 < 0 || p[i] > p[i1]) i1 = i;
        }
        float wsum = fmaxf(p[i0] + p[i1], 1e-9f);
        float gg[4] = {0.f, 0.f, 0.f, 0.f};
        gg[i0] = p[i0] / wsum;
        gg[i1] = p[i1] / wsum;
        *(float4*)(gates + (size_t)node * 4) = make_float4(gg[0], gg[1], gg[2], gg[3]);
    }
}

// ---------- graph structure ----------
__global__ void edge_deg_kernel(const int* __restrict__ dst, int* __restrict__ degi, int E) {
    int e = blockIdx.x * blockDim.x + threadIdx.x;
    if (e < E) atomicAdd(&degi[dst[e]], 1);
}
__global__ void scan_kernel(const int* __restrict__ degi, int* __restrict__ rowptr, int n) {
    __shared__ int sh[256];
    __shared__ int sbase;
    int tid = threadIdx.x;
    if (tid == 0) { sbase = 0; rowptr[0] = 0; }
    __syncthreads();
    const int CH = 256 * 8;
    for (int c0 = 0; c0 < n; c0 += CH) {
        int loc[8]; int s = 0;
        int base_i = c0 + tid * 8;
#pragma unroll
        for (int j = 0; j < 8; j++) {
            int idx = base_i + j;
            int v = (idx < n) ? degi[idx] : 0;
            s += v; loc[j] = s;
        }
        sh[tid] = s;
        __syncthreads();
        for (int off = 1; off < 256; off <<= 1) {
            int t = (tid >= off) ? sh[tid - off] : 0;
            __syncthreads();
            sh[tid] += t;
            __syncthreads();
        }
        int prev = (tid > 0) ? sh[tid - 1] : 0;
        int b = sbase;
        int total = sh[255];
#pragma unroll
        for (int j = 0; j < 8; j++) {
            int idx = base_i + j;
            if (idx < n) rowptr[idx + 1] = b + prev + loc[j];
        }
        __syncthreads();
        if (tid == 0) sbase = b + total;
        __syncthreads();
    }
}
__global__ void csr_fill_kernel(const int* __restrict__ src, const int* __restrict__ dst,
                                const int* __restrict__ rowptr, int* __restrict__ cursor,
                                int* __restrict__ csr, int E) {
    int e = blockIdx.x * blockDim.x + threadIdx.x;
    if (e >= E) return;
    int d = dst[e];
    int pos = atomicAdd(&cursor[d], 1);
    csr[rowptr[d] + pos] = src[e];
}
__global__ void dinv_kernel(const int* __restrict__ degi, float* __restrict__ dinv,
                            float* __restrict__ dinvl, int N) {
    int n = blockIdx.x * blockDim.x + threadIdx.x;
    if (n >= N) return;
    float deg = (float)degi[n];
    dinv[n] = (deg > 0.f) ? rsqrtf(fmaxf(deg, 1.f)) : 0.f;
    dinvl[n] = rsqrtf(deg + 1.f);
}

// ---------- gather propagation over bf16 features, fp32 accumulate ----------
__global__ void gather_kernel(const ushort_t* __restrict__ Xb, float* __restrict__ Out,
                              const int* __restrict__ rowptr, const int* __restrict__ csr,
                              const float* __restrict__ dv, int self_loop, float scale,
                              const float* __restrict__ bias, int relu, int M)
{
    int node = blockIdx.x * 4 + (threadIdx.x >> 6);
    int lane = threadIdx.x & 63;
    if (node >= M) return;
    int beg = rowptr[node], end = rowptr[node + 1];
    float dn = dv[node];
    float ax = 0.f, ay = 0.f;
    int e = beg;
    for (; e + 3 < end; e += 4) {
        int s0 = csr[e], s1 = csr[e + 1], s2 = csr[e + 2], s3 = csr[e + 3];
        float c0 = dn * dv[s0], c1 = dn * dv[s1], c2 = dn * dv[s2], c3 = dn * dv[s3];
        unsigned int u0 = *(const unsigned int*)(Xb + (size_t)s0 * 128 + lane * 2);
        unsigned int u1 = *(const unsigned int*)(Xb + (size_t)s1 * 128 + lane * 2);
        unsigned int u2 = *(const unsigned int*)(Xb + (size_t)s2 * 128 + lane * 2);
        unsigned int u3 = *(const unsigned int*)(Xb + (size_t)s3 * 128 + lane * 2);
        ax = fmaf(c0, bf2f(u0 & 0xffff), fmaf(c1, bf2f(u1 & 0xffff),
             fmaf(c2, bf2f(u2 & 0xffff), fmaf(c3, bf2f(u3 & 0xffff), ax))));
        ay = fmaf(c0, bf2f(u0 >> 16), fmaf(c1, bf2f(u1 >> 16),
             fmaf(c2, bf2f(u2 >> 16), fmaf(c3, bf2f(u3 >> 16), ay))));
    }
    for (; e < end; e++) {
        int s = csr[e];
        float c = dn * dv[s];
        unsigned int u = *(const unsigned int*)(Xb + (size_t)s * 128 + lane * 2);
        ax = fmaf(c, bf2f(u & 0xffff), ax);
        ay = fmaf(c, bf2f(u >> 16), ay);
    }
    if (self_loop) {
        float c = dn * dn;
        unsigned int u = *(const unsigned int*)(Xb + (size_t)node * 128 + lane * 2);
        ax = fmaf(c, bf2f(u & 0xffff), ax);
        ay = fmaf(c, bf2f(u >> 16), ay);
    }
    ax *= scale; ay *= scale;
    if (bias) { ax += bias[lane * 2]; ay += bias[lane * 2 + 1]; }
    if (relu) { ax = fmaxf(ax, 0.f); ay = fmaxf(ay, 0.f); }
    *(float2*)(Out + (size_t)node * 128 + lane * 2) = make_float2(ax, ay);
}

// ---------- graph-transformer attention: single-pass online softmax, bf16 K/V ----------
__global__ void gt_attn_kernel(const float* __restrict__ Q, const ushort_t* __restrict__ Kb,
                               const ushort_t* __restrict__ Vb, const int* __restrict__ rowptr,
                               const int* __restrict__ csr, float* __restrict__ Out, int M)
{
    const float SC = 0.17677669529663689f; // 1/sqrt(32)
    int node = blockIdx.x * 4 + (threadIdx.x >> 6);
    int lane = threadIdx.x & 63;
    if (node >= M) return;
    int beg = rowptr[node], end = rowptr[node + 1];
    float2 q = *(const float2*)(Q + (size_t)node * 128 + lane * 2);
    float m = -1e30f, den = 0.f, ax = 0.f, ay = 0.f;
    for (int e = beg; e < end; e++) {
        int s = csr[e];
        unsigned int ku = *(const unsigned int*)(Kb + (size_t)s * 128 + lane * 2);
        unsigned int vu = *(const unsigned int*)(Vb + (size_t)s * 128 + lane * 2);
        float p = q.x * bf2f(ku & 0xffff) + q.y * bf2f(ku >> 16);
        p += __shfl_xor(p, 1); p += __shfl_xor(p, 2); p += __shfl_xor(p, 4); p += __shfl_xor(p, 8);
        float logit = p * SC;
        float mn = fmaxf(m, logit);
        float sc2 = expf(m - mn);
        float w = expf(logit - mn);
        den = den * sc2 + w;
        ax = ax * sc2 + w * bf2f(vu & 0xffff);
        ay = ay * sc2 + w * bf2f(vu >> 16);
        m = mn;
    }
    float d = fmaxf(den, 1e-9f);
    *(float2*)(Out + (size_t)node * 128 + lane * 2) = make_float2(ax / d, ay / d);
}

// ---------- fused: out = h + sum_e gates[e] * (LN(e_i)*scale_e) ----------
__global__ void combine4_kernel(const float* __restrict__ h,
                                const float* __restrict__ e0, const float* __restrict__ e1,
                                const float* __restrict__ e2, const float* __restrict__ e3,
                                const float* __restrict__ gates,
                                const float* __restrict__ png, const float* __restrict__ pnb,
                                const float* __restrict__ esc,
                                float* __restrict__ Out, int M)
{
    int node = blockIdx.x * 4 + (threadIdx.x >> 6);
    int lane = threadIdx.x & 63;
    if (node >= M) return;
    size_t ofs = (size_t)node * 128 + lane * 2;
    const float* ep[4] = {e0 + ofs, e1 + ofs, e2 + ofs, e3 + ofs};
    float4 gg = *(const float4*)(gates + (size_t)node * 4);
    float gv[4] = {gg.x, gg.y, gg.z, gg.w};
    float2 hv = *(const float2*)(h + ofs);
    float ox = hv.x, oy = hv.y;
#pragma unroll
    for (int e = 0; e < 4; e++) {
        float2 v = *(const float2*)ep[e];
        float s = v.x + v.y, sq = v.x * v.x + v.y * v.y;
#pragma unroll
        for (int off = 32; off; off >>= 1) { s += __shfl_xor(s, off); sq += __shfl_xor(sq, off); }
        float mean = s * (1.f / 128.f);
        float var = sq * (1.f / 128.f) - mean * mean;
        float inv = rsqrtf(var + 1e-5f);
        float g0 = png[e * 128 + lane * 2], g1 = png[e * 128 + lane * 2 + 1];
        float b0 = pnb[e * 128 + lane * 2], b1 = pnb[e * 128 + lane * 2 + 1];
        float c = esc[e] * gv[e];
        ox = fmaf(c, (v.x - mean) * inv * g0 + b0, ox);
        oy = fmaf(c, (v.y - mean) * inv * g1 + b1, oy);
    }
    *(float2*)(Out + ofs) = make_float2(ox, oy);
}

// ---------- segmented mean-pool ----------
__global__ void pool_seg_kernel(const float* __restrict__ Out,
                                const int* __restrict__ bstart, const int* __restrict__ bend,
                                float* __restrict__ pooled)
{
    int b = blockIdx.x, t = threadIdx.x;  // 128 threads
    int s = bstart[b], e = bend[b];
    float sum = 0.f;
    for (int n = s; n < e; n++) sum += Out[(size_t)n * 128 + t];
    float cnt = fmaxf((float)(e - s), 1.f);
    pooled[(size_t)b * 128 + t] = sum / cnt;
}

// ---------- classification head (fp32 out) ----------
__global__ void head_kernel(const float* __restrict__ pooled,
                            const float* __restrict__ h1W, const float* __restrict__ h1b,
                            const float* __restrict__ h1g, const float* __restrict__ h1be,
                            const float* __restrict__ h2W, const float* __restrict__ h2b,
                            const float* __restrict__ h2g, const float* __restrict__ h2be,
                            const float* __restrict__ h3W, const float* __restrict__ h3b,
                            const float* __restrict__ lbias,
                            float* __restrict__ out, int B)
{
    __shared__ float p[128], z[128];
    int b = blockIdx.x, t = threadIdx.x;
    p[t] = pooled[(size_t)b * 128 + t];
    __syncthreads();
    float a = h1b[t];
    for (int k = 0; k < 128; k++) a = fmaf(p[k], h1W[k * 128 + t], a);
    z[t] = a;
    __syncthreads();
    float s = 0.f, sq = 0.f;
    for (int k = 0; k < 128; k++) { float x = z[k]; s += x; sq += x * x; }
    float mean = s * (1.f / 128.f), var = sq * (1.f / 128.f) - mean * mean;
    float y = fmaxf((a - mean) * rsqrtf(var + 1e-5f) * h1g[t] + h1be[t], 0.f);
    __syncthreads();
    z[t] = y;
    __syncthreads();
    float a2 = 0.f;
    if (t < 64) {
        a2 = h2b[t];
        for (int k = 0; k < 128; k++) a2 = fmaf(z[k], h2W[k * 64 + t], a2);
    }
    __syncthreads();
    if (t < 64) p[t] = a2;
    __syncthreads();
    if (t < 2) {
        float s2 = 0.f, sq2 = 0.f;
        for (int k = 0; k < 64; k++) { float x = p[k]; s2 += x; sq2 += x * x; }
        float mean2 = s2 * (1.f / 64.f), var2 = sq2 * (1.f / 64.f) - mean2 * mean2;
        float inv2 = rsqrtf(var2 + 1e-5f);
        float o = h3b[t] + lbias[t];
        for (int k = 0; k < 64; k++) {
            float zc = fmaxf((p[k] - mean2) * inv2 * h2g[k] + h2be[k], 0.f);
            o = fmaf(zc, h3W[k * 2 + t], o);
        }
        out[b * 2 + t] = o;
    }
}

// ---------------- launch ----------------
extern "C" void kernel_launch(void* const* d_in, const int* in_sizes, int n_in,
                              void* d_out, int out_size, void* d_ws, size_t ws_size,
                              hipStream_t stream)
{
    (void)ws_size; (void)n_in;
    const int N = in_sizes[3];
    const int E = in_sizes[2] / 2;
    const int B = out_size / 2;

    const int* ei = (const int*)d_in[2];
    const int* src = ei;
    const int* dst = ei + E;
    const int* batch = (const int*)d_in[3];

    const float* W[47];
    for (int i = 0; i < 47; i++) W[i] = (const float*)d_in[i];

    size_t fN = (size_t)N;
    float* hr    = (float*)d_ws;        // 256N: bufA/bufB after router
    float* h     = hr + 256 * fN;       // 128N
    float* e0    = h + 128 * fN;        // 128N
    float* e1    = e0 + 128 * fN;       // 128N
    float* e2    = e1 + 128 * fN;       // 128N
    float* e3    = e2 + 128 * fN;       // 128N
    float* tmp0  = e3 + 128 * fN;       // 128N (v buf; later outb)
    float* tmp1  = tmp0 + 128 * fN;     // 128N (agg/z1 buf)
    float* gates = tmp1 + 128 * fN;     // 4N
    float* dinv  = gates + 4 * fN;      // N
    float* dinvl = dinv + fN;           // N
    float* pooled = dinvl + fN;         // 128*B
    ushort_t* hb  = (ushort_t*)(pooled + (size_t)128 * B);  // 128N bf16
    ushort_t* bf0 = hb + 128 * fN;                           // 128N bf16
    ushort_t* bf1 = bf0 + 128 * fN;                          // 128N bf16
    int* degi   = (int*)(bf1 + 128 * fN);
    int* cursor = degi + N;
    int* rowptr = cursor + N;
    int* csr    = rowptr + (N + 1);
    int* bstart = csr + E;
    int* bend   = bstart + B;
    float* bufA = hr;
    float* bufB = hr + 128 * fN;
    float* outb = tmp0;

    dim3 blk(256);
    int gN4 = (N + 3) / 4;
    dim3 gG((N + 63) / 64);
    ushort_t* NOB = (ushort_t*)0;

    zero_i32_kernel<<<(2 * N + 255) / 256, blk, 0, stream>>>(degi, 2 * N);
    zero_i32_kernel<<<1, blk, 0, stream>>>(bstart, 2 * B);
    seg_bounds_kernel<<<(N + 255) / 256, blk, 0, stream>>>(batch, bstart, bend, N);

    // encoders + fuse + router (all fp32 — gating must be exact)
    gemm_kernel<<<gG, blk, 0, stream>>>(W[0], 200, W[4], hr, 256, N, 200, W[5], 0, NOB);
    gemm_kernel<<<gG, blk, 0, stream>>>(W[1], 128, W[8], hr + 128, 256, N, 128, W[9], 0, NOB);
    ln_relu_kernel<<<gN4, blk, 0, stream>>>(hr, 256, W[6], W[7], N, NOB);
    ln_relu_kernel<<<gN4, blk, 0, stream>>>(hr + 128, 256, W[10], W[11], N, NOB);
    router_kernel<<<gN4, blk, 0, stream>>>(hr, W[16], gates, N);
    gemm_kernel<<<gG, blk, 0, stream>>>(hr, 256, W[12], h, 128, N, 256, W[13], 0, NOB);
    ln_relu_kernel<<<gN4, blk, 0, stream>>>(h, 128, W[14], W[15], N, hb);  // h + bf16 shadow

    // graph structure (CSR by dst)
    edge_deg_kernel<<<(E + 255) / 256, blk, 0, stream>>>(dst, degi, E);
    scan_kernel<<<1, blk, 0, stream>>>(degi, rowptr, N);
    csr_fill_kernel<<<(E + 255) / 256, blk, 0, stream>>>(src, dst, rowptr, cursor, csr, E);
    dinv_kernel<<<(N + 255) / 256, blk, 0, stream>>>(degi, dinv, dinvl, N);

    // expert 0: MLP
    gemm_kernel<<<gG, blk, 0, stream>>>(h, 128, W[17], bufA, 128, N, 128, W[18], RELUF, NOB);
    gemm_kernel<<<gG, blk, 0, stream>>>(bufA, 128, W[19], e0, 128, N, 128, W[20], 0, NOB);

    // expert 1: ChebNet K=2
    gather_kernel<<<gN4, blk, 0, stream>>>(hb, bufA, rowptr, csr, dinv, 0, -1.f, (const float*)0, 0, N);
    gemm_kernel<<<gG, blk, 0, stream>>>(h, 128, W[21] + 0 * 16384, bufB, 128, N, 128, W[22], 0, NOB);
    gemm_kernel<<<gG, blk, 0, stream>>>(bufA, 128, W[21] + 1 * 16384, bufB, 128, N, 128, (const float*)0, ACCF | RELUF, bf0);
    gather_kernel<<<gN4, blk, 0, stream>>>(bf0, bufA, rowptr, csr, dinv, 0, -1.f, (const float*)0, 0, N);
    gemm_kernel<<<gG, blk, 0, stream>>>(bufB, 128, W[21] + 2 * 16384, e1, 128, N, 128, W[22] + 128, 0, NOB);
    gemm_kernel<<<gG, blk, 0, stream>>>(bufA, 128, W[21] + 3 * 16384, e1, 128, N, 128, (const float*)0, ACCF, NOB);

    // expert 3: GCN (2 layers, self loops)
    gemm_kernel<<<gG, blk, 0, stream>>>(h, 128, W[31], bufA, 128, N, 128, (const float*)0, 0, bf0);
    gather_kernel<<<gN4, blk, 0, stream>>>(bf0, bufB, rowptr, csr, dinvl, 1, 1.f, W[32], 1, N);
    gemm_kernel<<<gG, blk, 0, stream>>>(bufB, 128, W[31] + 16384, bufA, 128, N, 128, (const float*)0, 0, bf0);
    gather_kernel<<<gN4, blk, 0, stream>>>(bf0, e3, rowptr, csr, dinvl, 1, 1.f, W[32] + 128, 0, N);

    // expert 2: Graph Transformer (2 layers)
    gemm_kernel<<<gG, blk, 0, stream>>>(h, 128, W[23], bufA, 128, N, 128, W[24], 0, NOB);       // q
    gemm_kernel<<<gG, blk, 0, stream>>>(h, 128, W[25], bufB, 128, N, 128, W[26], 0, bf0);       // k
    gemm_kernel<<<gG, blk, 0, stream>>>(h, 128, W[27], tmp0, 128, N, 128, W[28], 0, bf1);       // v
    gt_attn_kernel<<<gN4, blk, 0, stream>>>(bufA, bf0, bf1, rowptr, csr, tmp1, N);
    gemm_kernel<<<gG, blk, 0, stream>>>(h, 128, W[29], tmp1, 128, N, 128, W[30], ACCF | RELUF, NOB); // z1
    gemm_kernel<<<gG, blk, 0, stream>>>(tmp1, 128, W[23] + 16384, bufA, 128, N, 128, W[24] + 128, 0, NOB);
    gemm_kernel<<<gG, blk, 0, stream>>>(tmp1, 128, W[25] + 16384, bufB, 128, N, 128, W[26] + 128, 0, bf0);
    gemm_kernel<<<gG, blk, 0, stream>>>(tmp1, 128, W[27] + 16384, tmp0, 128, N, 128, W[28] + 128, 0, bf1);
    gt_attn_kernel<<<gN4, blk, 0, stream>>>(bufA, bf0, bf1, rowptr, csr, e2, N);
    gemm_kernel<<<gG, blk, 0, stream>>>(tmp1, 128, W[29] + 16384, e2, 128, N, 128, W[30] + 128, ACCF, NOB);

    // fused combine + segmented pool + head
    combine4_kernel<<<gN4, blk, 0, stream>>>(h, e0, e1, e2, e3, gates,
                                             W[33], W[34], W[35], outb, N);
    pool_seg_kernel<<<dim3(B), dim3(128), 0, stream>>>(outb, bstart, bend, pooled);
    head_kernel<<<dim3(B), dim3(128), 0, stream>>>(pooled,
        W[36], W[37], W[38], W[39],
        W[40], W[41], W[42], W[43],
        W[44], W[45], W[46],
        (float*)d_out, B);
}

// Round 7
// 1023.599 us; speedup vs baseline: 1.5122x; 1.1146x over previous
//
#include <hip/hip_runtime.h>

#define RELUF 1
#define ACCF  2
#define PCH   16   // pool chunks per graph

typedef unsigned short ushort_t;

__device__ __forceinline__ float bf2f(unsigned int v) {
    return __uint_as_float(v << 16);
}
__device__ __forceinline__ ushort_t f2b(float f) {
    unsigned int u = __float_as_uint(f);
    return (ushort_t)((u + 0x7fffu + ((u >> 16) & 1u)) >> 16);
}

// ---------------- utility kernels ----------------
__global__ void zero_i32_kernel(int* __restrict__ p, int n) {
    int i = blockIdx.x * blockDim.x + threadIdx.x;
    if (i < n) p[i] = 0;
}
// batch is sorted: boundary detection, no atomics
__global__ void seg_bounds_kernel(const int* __restrict__ batch, int* __restrict__ bstart,
                                  int* __restrict__ bend, int N) {
    int n = blockIdx.x * blockDim.x + threadIdx.x;
    if (n >= N) return;
    int b = batch[n];
    if (n == 0) bstart[b] = 0;
    else {
        int pb = batch[n - 1];
        if (pb != b) { bstart[b] = n; bend[pb] = n; }
    }
    if (n == N - 1) bend[b] = N;
}

// ---------- GEMM: C[M,128] = A[M,K] @ W[K,128] (+bias)(+C)(relu), fp32 ----------
// optional bf16 shadow copy Cb. 64x128 tile, 256 threads, 4x8 per thread.
__global__ __launch_bounds__(256)
void gemm_kernel(const float* __restrict__ A, int lda,
                 const float* __restrict__ W,
                 float* __restrict__ C, int ldc,
                 int M, int K,
                 const float* __restrict__ bias, int flags,
                 ushort_t* __restrict__ Cb)
{
    __shared__ float As[16][64];    // [k][m]
    __shared__ float Bs[16][128];   // [k][n]
    const int tid = threadIdx.x;
    const int m0 = blockIdx.x * 64;
    const int ty = tid >> 4, tx = tid & 15;
    const int ar = tid >> 2;
    const int akg = (tid & 3) << 2;
    const int wr = tid >> 4;
    const int wc = (tid & 15) << 3;
    const bool arow_ok = (m0 + ar) < M;
    const float* Arow = A + (size_t)(m0 + ar) * lda;

    float acc[4][8];
#pragma unroll
    for (int i = 0; i < 4; i++)
#pragma unroll
        for (int j = 0; j < 8; j++) acc[i][j] = 0.f;

    float av[4], wv[8];
    {
        int kb = akg;
        if (arow_ok && kb + 4 <= K) {
            float4 p0 = *(const float4*)(Arow + kb);
            av[0] = p0.x; av[1] = p0.y; av[2] = p0.z; av[3] = p0.w;
        } else {
            for (int j = 0; j < 4; j++) {
                int k = kb + j;
                av[j] = (arow_ok && k < K) ? Arow[k] : 0.f;
            }
        }
        int kw = wr;
        if (kw < K) {
            float4 q0 = *(const float4*)(W + (size_t)kw * 128 + wc);
            float4 q1 = *(const float4*)(W + (size_t)kw * 128 + wc + 4);
            wv[0] = q0.x; wv[1] = q0.y; wv[2] = q0.z; wv[3] = q0.w;
            wv[4] = q1.x; wv[5] = q1.y; wv[6] = q1.z; wv[7] = q1.w;
        } else {
            for (int j = 0; j < 8; j++) wv[j] = 0.f;
        }
    }
    for (int k0 = 0; k0 < K; k0 += 16) {
        __syncthreads();
#pragma unroll
        for (int j = 0; j < 4; j++) As[akg + j][ar] = av[j];
#pragma unroll
        for (int j = 0; j < 8; j++) Bs[wr][wc + j] = wv[j];
        __syncthreads();
        if (k0 + 16 < K) {
            int kb = k0 + 16 + akg;
            if (arow_ok && kb + 4 <= K) {
                float4 p0 = *(const float4*)(Arow + kb);
                av[0] = p0.x; av[1] = p0.y; av[2] = p0.z; av[3] = p0.w;
            } else {
                for (int j = 0; j < 4; j++) {
                    int k = kb + j;
                    av[j] = (arow_ok && k < K) ? Arow[k] : 0.f;
                }
            }
            int kw = k0 + 16 + wr;
            if (kw < K) {
                float4 q0 = *(const float4*)(W + (size_t)kw * 128 + wc);
                float4 q1 = *(const float4*)(W + (size_t)kw * 128 + wc + 4);
                wv[0] = q0.x; wv[1] = q0.y; wv[2] = q0.z; wv[3] = q0.w;
                wv[4] = q1.x; wv[5] = q1.y; wv[6] = q1.z; wv[7] = q1.w;
            } else {
                for (int j = 0; j < 8; j++) wv[j] = 0.f;
            }
        }
#pragma unroll
        for (int kk = 0; kk < 16; kk++) {
            float4 a0 = *(const float4*)&As[kk][ty * 4];
            float4 w0 = *(const float4*)&Bs[kk][tx * 4];
            float4 w1 = *(const float4*)&Bs[kk][64 + tx * 4];
            float aa[4] = {a0.x, a0.y, a0.z, a0.w};
            float ww[8] = {w0.x, w0.y, w0.z, w0.w, w1.x, w1.y, w1.z, w1.w};
#pragma unroll
            for (int i = 0; i < 4; i++)
#pragma unroll
                for (int j = 0; j < 8; j++) acc[i][j] = fmaf(aa[i], ww[j], acc[i][j]);
        }
    }
#pragma unroll
    for (int i = 0; i < 4; i++) {
        int gm = m0 + ty * 4 + i;
        if (gm >= M) continue;
        float* crow = C + (size_t)gm * ldc;
#pragma unroll
        for (int jh = 0; jh < 2; jh++) {
            int gn = jh * 64 + tx * 4;
            float4 r = make_float4(acc[i][jh * 4 + 0], acc[i][jh * 4 + 1],
                                   acc[i][jh * 4 + 2], acc[i][jh * 4 + 3]);
            if (bias) {
                float4 bb = *(const float4*)(bias + gn);
                r.x += bb.x; r.y += bb.y; r.z += bb.z; r.w += bb.w;
            }
            if (flags & ACCF) {
                float4 c0 = *(const float4*)(crow + gn);
                r.x += c0.x; r.y += c0.y; r.z += c0.z; r.w += c0.w;
            }
            if (flags & RELUF) {
                r.x = fmaxf(r.x, 0.f); r.y = fmaxf(r.y, 0.f);
                r.z = fmaxf(r.z, 0.f); r.w = fmaxf(r.w, 0.f);
            }
            *(float4*)(crow + gn) = r;
            if (Cb) {
                unsigned int lo = (unsigned int)f2b(r.x) | ((unsigned int)f2b(r.y) << 16);
                unsigned int hi = (unsigned int)f2b(r.z) | ((unsigned int)f2b(r.w) << 16);
                *(uint2*)(Cb + (size_t)gm * 128 + gn) = make_uint2(lo, hi);
            }
        }
    }
}

// ---------- LayerNorm(128) + ReLU in place (+ optional bf16 shadow) ----------
__global__ void ln_relu_kernel(float* __restrict__ X, int ld,
                               const float* __restrict__ g,
                               const float* __restrict__ b, int M,
                               ushort_t* __restrict__ Xb)
{
    int node = blockIdx.x * 4 + (threadIdx.x >> 6);
    int lane = threadIdx.x & 63;
    if (node >= M) return;
    float* row = X + (size_t)node * ld;
    float2 v = *(float2*)(row + lane * 2);
    float s = v.x + v.y, sq = v.x * v.x + v.y * v.y;
#pragma unroll
    for (int off = 32; off; off >>= 1) { s += __shfl_xor(s, off); sq += __shfl_xor(sq, off); }
    float mean = s * (1.f / 128.f);
    float var = sq * (1.f / 128.f) - mean * mean;
    float inv = rsqrtf(var + 1e-5f);
    float y0 = fmaxf((v.x - mean) * inv * g[lane * 2] + b[lane * 2], 0.f);
    float y1 = fmaxf((v.y - mean) * inv * g[lane * 2 + 1] + b[lane * 2 + 1], 0.f);
    *(float2*)(row + lane * 2) = make_float2(y0, y1);
    if (Xb) {
        unsigned int p = (unsigned int)f2b(y0) | ((unsigned int)f2b(y1) << 16);
        *(unsigned int*)(Xb + (size_t)node * 128 + lane * 2) = p;
    }
}

// ---------- router ----------
__global__ void router_kernel(const float* __restrict__ hr, const float* __restrict__ rW,
                              float* __restrict__ gates, int M)
{
    int node = blockIdx.x * 4 + (threadIdx.x >> 6);
    int lane = threadIdx.x & 63;
    if (node >= M) return;
    const float* row = hr + (size_t)node * 256;
    float a0 = 0, a1 = 0, a2 = 0, a3 = 0;
#pragma unroll
    for (int i = 0; i < 4; i++) {
        int k = lane + i * 64;
        float xv = row[k];
        float4 wv = *(const float4*)(rW + k * 4);
        a0 = fmaf(xv, wv.x, a0); a1 = fmaf(xv, wv.y, a1);
        a2 = fmaf(xv, wv.z, a2); a3 = fmaf(xv, wv.w, a3);
    }
#pragma unroll
    for (int off = 32; off; off >>= 1) {
        a0 += __shfl_xor(a0, off); a1 += __shfl_xor(a1, off);
        a2 += __shfl_xor(a2, off); a3 += __shfl_xor(a3, off);
    }
    if (lane == 0) {
        float l[4] = {a0 * (1.f / 1.5f), a1 * (1.f / 1.5f), a2 * (1.f / 1.5f), a3 * (1.f / 1.5f)};
        float mx = fmaxf(fmaxf(l[0], l[1]), fmaxf(l[2], l[3]));
        float e[4], ssum = 0.f;
#pragma unroll
        for (int i = 0; i < 4; i++) { e[i] = expf(l[i] - mx); ssum += e[i]; }
        float p[4];
#pragma unroll
        for (int i = 0; i < 4; i++) p[i] = e[i] / ssum;
        int i0 = 0;
        for (int i = 1; i < 4; i++) if (p[i] > p[i0]) i0 = i;
        int i1 = -1;
        for (int i = 0; i < 4; i++) {
            if (i == i0) continue;
            if (i1 < 0 || p[i] > p[i1]) i1 = i;
        }
        float wsum = fmaxf(p[i0] + p[i1], 1e-9f);
        float gg[4] = {0.f, 0.f, 0.f, 0.f};
        gg[i0] = p[i0] / wsum;
        gg[i1] = p[i1] / wsum;
        *(float4*)(gates + (size_t)node * 4) = make_float4(gg[0], gg[1], gg[2], gg[3]);
    }
}

// ---------- graph structure ----------
__global__ void edge_deg_kernel(const int* __restrict__ dst, int* __restrict__ degi, int E) {
    int e = blockIdx.x * blockDim.x + threadIdx.x;
    if (e < E) atomicAdd(&degi[dst[e]], 1);
}
__global__ void scan_kernel(const int* __restrict__ degi, int* __restrict__ rowptr, int n) {
    __shared__ int sh[256];
    __shared__ int sbase;
    int tid = threadIdx.x;
    if (tid == 0) { sbase = 0; rowptr[0] = 0; }
    __syncthreads();
    const int CH = 256 * 8;
    for (int c0 = 0; c0 < n; c0 += CH) {
        int loc[8]; int s = 0;
        int base_i = c0 + tid * 8;
#pragma unroll
        for (int j = 0; j < 8; j++) {
            int idx = base_i + j;
            int v = (idx < n) ? degi[idx] : 0;
            s += v; loc[j] = s;
        }
        sh[tid] = s;
        __syncthreads();
        for (int off = 1; off < 256; off <<= 1) {
            int t = (tid >= off) ? sh[tid - off] : 0;
            __syncthreads();
            sh[tid] += t;
            __syncthreads();
        }
        int prev = (tid > 0) ? sh[tid - 1] : 0;
        int b = sbase;
        int total = sh[255];
#pragma unroll
        for (int j = 0; j < 8; j++) {
            int idx = base_i + j;
            if (idx < n) rowptr[idx + 1] = b + prev + loc[j];
        }
        __syncthreads();
        if (tid == 0) sbase = b + total;
        __syncthreads();
    }
}
__global__ void csr_fill_kernel(const int* __restrict__ src, const int* __restrict__ dst,
                                const int* __restrict__ rowptr, int* __restrict__ cursor,
                                int* __restrict__ csr, int E) {
    int e = blockIdx.x * blockDim.x + threadIdx.x;
    if (e >= E) return;
    int d = dst[e];
    int pos = atomicAdd(&cursor[d], 1);
    csr[rowptr[d] + pos] = src[e];
}
__global__ void dinv_kernel(const int* __restrict__ degi, float* __restrict__ dinv,
                            float* __restrict__ dinvl, int N) {
    int n = blockIdx.x * blockDim.x + threadIdx.x;
    if (n >= N) return;
    float deg = (float)degi[n];
    dinv[n] = (deg > 0.f) ? rsqrtf(fmaxf(deg, 1.f)) : 0.f;
    dinvl[n] = rsqrtf(deg + 1.f);
}

// ---------- gather propagation over bf16 features, fp32 accumulate ----------
__global__ void gather_kernel(const ushort_t* __restrict__ Xb, float* __restrict__ Out,
                              const int* __restrict__ rowptr, const int* __restrict__ csr,
                              const float* __restrict__ dv, int self_loop, float scale,
                              const float* __restrict__ bias, int relu, int M)
{
    int node = blockIdx.x * 4 + (threadIdx.x >> 6);
    int lane = threadIdx.x & 63;
    if (node >= M) return;
    int beg = rowptr[node], end = rowptr[node + 1];
    float dn = dv[node];
    float ax = 0.f, ay = 0.f;
    int e = beg;
    for (; e + 3 < end; e += 4) {
        int s0 = csr[e], s1 = csr[e + 1], s2 = csr[e + 2], s3 = csr[e + 3];
        float c0 = dn * dv[s0], c1 = dn * dv[s1], c2 = dn * dv[s2], c3 = dn * dv[s3];
        unsigned int u0 = *(const unsigned int*)(Xb + (size_t)s0 * 128 + lane * 2);
        unsigned int u1 = *(const unsigned int*)(Xb + (size_t)s1 * 128 + lane * 2);
        unsigned int u2 = *(const unsigned int*)(Xb + (size_t)s2 * 128 + lane * 2);
        unsigned int u3 = *(const unsigned int*)(Xb + (size_t)s3 * 128 + lane * 2);
        ax = fmaf(c0, bf2f(u0 & 0xffff), fmaf(c1, bf2f(u1 & 0xffff),
             fmaf(c2, bf2f(u2 & 0xffff), fmaf(c3, bf2f(u3 & 0xffff), ax))));
        ay = fmaf(c0, bf2f(u0 >> 16), fmaf(c1, bf2f(u1 >> 16),
             fmaf(c2, bf2f(u2 >> 16), fmaf(c3, bf2f(u3 >> 16), ay))));
    }
    for (; e < end; e++) {
        int s = csr[e];
        float c = dn * dv[s];
        unsigned int u = *(const unsigned int*)(Xb + (size_t)s * 128 + lane * 2);
        ax = fmaf(c, bf2f(u & 0xffff), ax);
        ay = fmaf(c, bf2f(u >> 16), ay);
    }
    if (self_loop) {
        float c = dn * dn;
        unsigned int u = *(const unsigned int*)(Xb + (size_t)node * 128 + lane * 2);
        ax = fmaf(c, bf2f(u & 0xffff), ax);
        ay = fmaf(c, bf2f(u >> 16), ay);
    }
    ax *= scale; ay *= scale;
    if (bias) { ax += bias[lane * 2]; ay += bias[lane * 2 + 1]; }
    if (relu) { ax = fmaxf(ax, 0.f); ay = fmaxf(ay, 0.f); }
    *(float2*)(Out + (size_t)node * 128 + lane * 2) = make_float2(ax, ay);
}

// ---------- graph-transformer attention: single-pass online softmax, bf16 K/V ----------
__global__ void gt_attn_kernel(const float* __restrict__ Q, const ushort_t* __restrict__ Kb,
                               const ushort_t* __restrict__ Vb, const int* __restrict__ rowptr,
                               const int* __restrict__ csr, float* __restrict__ Out, int M)
{
    const float SC = 0.17677669529663689f; // 1/sqrt(32)
    int node = blockIdx.x * 4 + (threadIdx.x >> 6);
    int lane = threadIdx.x & 63;
    if (node >= M) return;
    int beg = rowptr[node], end = rowptr[node + 1];
    float2 q = *(const float2*)(Q + (size_t)node * 128 + lane * 2);
    float m = -1e30f, den = 0.f, ax = 0.f, ay = 0.f;
    for (int e = beg; e < end; e++) {
        int s = csr[e];
        unsigned int ku = *(const unsigned int*)(Kb + (size_t)s * 128 + lane * 2);
        unsigned int vu = *(const unsigned int*)(Vb + (size_t)s * 128 + lane * 2);
        float p = q.x * bf2f(ku & 0xffff) + q.y * bf2f(ku >> 16);
        p += __shfl_xor(p, 1); p += __shfl_xor(p, 2); p += __shfl_xor(p, 4); p += __shfl_xor(p, 8);
        float logit = p * SC;
        float mn = fmaxf(m, logit);
        float sc2 = expf(m - mn);
        float w = expf(logit - mn);
        den = den * sc2 + w;
        ax = ax * sc2 + w * bf2f(vu & 0xffff);
        ay = ay * sc2 + w * bf2f(vu >> 16);
        m = mn;
    }
    float d = fmaxf(den, 1e-9f);
    *(float2*)(Out + (size_t)node * 128 + lane * 2) = make_float2(ax / d, ay / d);
}

// ---------- fused: out = h + sum_e gates[e] * (LN(e_i)*scale_e) ----------
__global__ void combine4_kernel(const float* __restrict__ h,
                                const float* __restrict__ e0, const float* __restrict__ e1,
                                const float* __restrict__ e2, const float* __restrict__ e3,
                                const float* __restrict__ gates,
                                const float* __restrict__ png, const float* __restrict__ pnb,
                                const float* __restrict__ esc,
                                float* __restrict__ Out, int M)
{
    int node = blockIdx.x * 4 + (threadIdx.x >> 6);
    int lane = threadIdx.x & 63;
    if (node >= M) return;
    size_t ofs = (size_t)node * 128 + lane * 2;
    const float* ep[4] = {e0 + ofs, e1 + ofs, e2 + ofs, e3 + ofs};
    float4 gg = *(const float4*)(gates + (size_t)node * 4);
    float gv[4] = {gg.x, gg.y, gg.z, gg.w};
    float2 hv = *(const float2*)(h + ofs);
    float ox = hv.x, oy = hv.y;
#pragma unroll
    for (int e = 0; e < 4; e++) {
        float2 v = *(const float2*)ep[e];
        float s = v.x + v.y, sq = v.x * v.x + v.y * v.y;
#pragma unroll
        for (int off = 32; off; off >>= 1) { s += __shfl_xor(s, off); sq += __shfl_xor(sq, off); }
        float mean = s * (1.f / 128.f);
        float var = sq * (1.f / 128.f) - mean * mean;
        float inv = rsqrtf(var + 1e-5f);
        float g0 = png[e * 128 + lane * 2], g1 = png[e * 128 + lane * 2 + 1];
        float b0 = pnb[e * 128 + lane * 2], b1 = pnb[e * 128 + lane * 2 + 1];
        float c = esc[e] * gv[e];
        ox = fmaf(c, (v.x - mean) * inv * g0 + b0, ox);
        oy = fmaf(c, (v.y - mean) * inv * g1 + b1, oy);
    }
    *(float2*)(Out + ofs) = make_float2(ox, oy);
}

// ---------- two-phase segmented mean-pool ----------
// phase 1: grid (B, PCH) x 128 threads; strided partial sums
__global__ void pool_partial_kernel(const float* __restrict__ Out,
                                    const int* __restrict__ bstart, const int* __restrict__ bend,
                                    float* __restrict__ partial)
{
    int b = blockIdx.x, c = blockIdx.y, t = threadIdx.x;
    int s = bstart[b], e = bend[b];
    float sum = 0.f;
    for (int n = s + c; n < e; n += PCH) sum += Out[(size_t)n * 128 + t];
    partial[((size_t)b * PCH + c) * 128 + t] = sum;
}
// phase 2: B blocks x 128 threads
__global__ void pool_reduce_kernel(const float* __restrict__ partial,
                                   const int* __restrict__ bstart, const int* __restrict__ bend,
                                   float* __restrict__ pooled)
{
    int b = blockIdx.x, t = threadIdx.x;
    float sum = 0.f;
#pragma unroll
    for (int c = 0; c < PCH; c++) sum += partial[((size_t)b * PCH + c) * 128 + t];
    float cnt = fmaxf((float)(bend[b] - bstart[b]), 1.f);
    pooled[(size_t)b * 128 + t] = sum / cnt;
}

// ---------- classification head (fp32 out) ----------
__global__ void head_kernel(const float* __restrict__ pooled,
                            const float* __restrict__ h1W, const float* __restrict__ h1b,
                            const float* __restrict__ h1g, const float* __restrict__ h1be,
                            const float* __restrict__ h2W, const float* __restrict__ h2b,
                            const float* __restrict__ h2g, const float* __restrict__ h2be,
                            const float* __restrict__ h3W, const float* __restrict__ h3b,
                            const float* __restrict__ lbias,
                            float* __restrict__ out, int B)
{
    __shared__ float p[128], z[128];
    int b = blockIdx.x, t = threadIdx.x;
    p[t] = pooled[(size_t)b * 128 + t];
    __syncthreads();
    float a = h1b[t];
    for (int k = 0; k < 128; k++) a = fmaf(p[k], h1W[k * 128 + t], a);
    z[t] = a;
    __syncthreads();
    float s = 0.f, sq = 0.f;
    for (int k = 0; k < 128; k++) { float x = z[k]; s += x; sq += x * x; }
    float mean = s * (1.f / 128.f), var = sq * (1.f / 128.f) - mean * mean;
    float y = fmaxf((a - mean) * rsqrtf(var + 1e-5f) * h1g[t] + h1be[t], 0.f);
    __syncthreads();
    z[t] = y;
    __syncthreads();
    float a2 = 0.f;
    if (t < 64) {
        a2 = h2b[t];
        for (int k = 0; k < 128; k++) a2 = fmaf(z[k], h2W[k * 64 + t], a2);
    }
    __syncthreads();
    if (t < 64) p[t] = a2;
    __syncthreads();
    if (t < 2) {
        float s2 = 0.f, sq2 = 0.f;
        for (int k = 0; k < 64; k++) { float x = p[k]; s2 += x; sq2 += x * x; }
        float mean2 = s2 * (1.f / 64.f), var2 = sq2 * (1.f / 64.f) - mean2 * mean2;
        float inv2 = rsqrtf(var2 + 1e-5f);
        float o = h3b[t] + lbias[t];
        for (int k = 0; k < 64; k++) {
            float zc = fmaxf((p[k] - mean2) * inv2 * h2g[k] + h2be[k], 0.f);
            o = fmaf(zc, h3W[k * 2 + t], o);
        }
        out[b * 2 + t] = o;
    }
}

// ---------------- launch ----------------
extern "C" void kernel_launch(void* const* d_in, const int* in_sizes, int n_in,
                              void* d_out, int out_size, void* d_ws, size_t ws_size,
                              hipStream_t stream)
{
    (void)ws_size; (void)n_in;
    const int N = in_sizes[3];
    const int E = in_sizes[2] / 2;
    const int B = out_size / 2;

    const int* ei = (const int*)d_in[2];
    const int* src = ei;
    const int* dst = ei + E;
    const int* batch = (const int*)d_in[3];

    const float* W[47];
    for (int i = 0; i < 47; i++) W[i] = (const float*)d_in[i];

    size_t fN = (size_t)N;
    float* hr    = (float*)d_ws;        // 256N: bufA/bufB after router
    float* h     = hr + 256 * fN;       // 128N
    float* e0    = h + 128 * fN;        // 128N
    float* e1    = e0 + 128 * fN;       // 128N
    float* e2    = e1 + 128 * fN;       // 128N
    float* e3    = e2 + 128 * fN;       // 128N
    float* tmp0  = e3 + 128 * fN;       // 128N (v buf; later outb)
    float* tmp1  = tmp0 + 128 * fN;     // 128N (agg/z1 buf)
    float* gates = tmp1 + 128 * fN;     // 4N
    float* dinv  = gates + 4 * fN;      // N
    float* dinvl = dinv + fN;           // N
    float* pooled = dinvl + fN;         // 128*B
    float* partial = pooled + (size_t)128 * B;               // 128*B*PCH
    ushort_t* hb  = (ushort_t*)(partial + (size_t)128 * B * PCH);  // 128N bf16
    ushort_t* bf0 = hb + 128 * fN;                           // 128N bf16
    ushort_t* bf1 = bf0 + 128 * fN;                          // 128N bf16
    int* degi   = (int*)(bf1 + 128 * fN);
    int* cursor = degi + N;
    int* rowptr = cursor + N;
    int* csr    = rowptr + (N + 1);
    int* bstart = csr + E;
    int* bend   = bstart + B;
    float* bufA = hr;
    float* bufB = hr + 128 * fN;
    float* outb = tmp0;

    dim3 blk(256);
    int gN4 = (N + 3) / 4;
    dim3 gG((N + 63) / 64);
    ushort_t* NOB = (ushort_t*)0;

    // graph structure first (independent of features)
    zero_i32_kernel<<<(2 * N + 255) / 256, blk, 0, stream>>>(degi, 2 * N);
    zero_i32_kernel<<<1, blk, 0, stream>>>(bstart, 2 * B);
    seg_bounds_kernel<<<(N + 255) / 256, blk, 0, stream>>>(batch, bstart, bend, N);
    edge_deg_kernel<<<(E + 255) / 256, blk, 0, stream>>>(dst, degi, E);
    scan_kernel<<<1, blk, 0, stream>>>(degi, rowptr, N);
    csr_fill_kernel<<<(E + 255) / 256, blk, 0, stream>>>(src, dst, rowptr, cursor, csr, E);
    dinv_kernel<<<(N + 255) / 256, blk, 0, stream>>>(degi, dinv, dinvl, N);

    // encoders + fuse + router (all fp32 — gating must be exact)
    gemm_kernel<<<gG, blk, 0, stream>>>(W[0], 200, W[4], hr, 256, N, 200, W[5], 0, NOB);
    gemm_kernel<<<gG, blk, 0, stream>>>(W[1], 128, W[8], hr + 128, 256, N, 128, W[9], 0, NOB);
    ln_relu_kernel<<<gN4, blk, 0, stream>>>(hr, 256, W[6], W[7], N, NOB);
    ln_relu_kernel<<<gN4, blk, 0, stream>>>(hr + 128, 256, W[10], W[11], N, NOB);
    router_kernel<<<gN4, blk, 0, stream>>>(hr, W[16], gates, N);
    gemm_kernel<<<gG, blk, 0, stream>>>(hr, 256, W[12], h, 128, N, 256, W[13], 0, NOB);
    ln_relu_kernel<<<gN4, blk, 0, stream>>>(h, 128, W[14], W[15], N, hb);  // h + bf16 shadow

    // expert 0: MLP
    gemm_kernel<<<gG, blk, 0, stream>>>(h, 128, W[17], bufA, 128, N, 128, W[18], RELUF, NOB);
    gemm_kernel<<<gG, blk, 0, stream>>>(bufA, 128, W[19], e0, 128, N, 128, W[20], 0, NOB);

    // expert 1: ChebNet K=2
    gather_kernel<<<gN4, blk, 0, stream>>>(hb, bufA, rowptr, csr, dinv, 0, -1.f, (const float*)0, 0, N);
    gemm_kernel<<<gG, blk, 0, stream>>>(h, 128, W[21] + 0 * 16384, bufB, 128, N, 128, W[22], 0, NOB);
    gemm_kernel<<<gG, blk, 0, stream>>>(bufA, 128, W[21] + 1 * 16384, bufB, 128, N, 128, (const float*)0, ACCF | RELUF, bf0);
    gather_kernel<<<gN4, blk, 0, stream>>>(bf0, bufA, rowptr, csr, dinv, 0, -1.f, (const float*)0, 0, N);
    gemm_kernel<<<gG, blk, 0, stream>>>(bufB, 128, W[21] + 2 * 16384, e1, 128, N, 128, W[22] + 128, 0, NOB);
    gemm_kernel<<<gG, blk, 0, stream>>>(bufA, 128, W[21] + 3 * 16384, e1, 128, N, 128, (const float*)0, ACCF, NOB);

    // expert 3: GCN (2 layers, self loops)
    gemm_kernel<<<gG, blk, 0, stream>>>(h, 128, W[31], bufA, 128, N, 128, (const float*)0, 0, bf0);
    gather_kernel<<<gN4, blk, 0, stream>>>(bf0, bufB, rowptr, csr, dinvl, 1, 1.f, W[32], 1, N);
    gemm_kernel<<<gG, blk, 0, stream>>>(bufB, 128, W[31] + 16384, bufA, 128, N, 128, (const float*)0, 0, bf0);
    gather_kernel<<<gN4, blk, 0, stream>>>(bf0, e3, rowptr, csr, dinvl, 1, 1.f, W[32] + 128, 0, N);

    // expert 2: Graph Transformer (2 layers)
    gemm_kernel<<<gG, blk, 0, stream>>>(h, 128, W[23], bufA, 128, N, 128, W[24], 0, NOB);       // q
    gemm_kernel<<<gG, blk, 0, stream>>>(h, 128, W[25], bufB, 128, N, 128, W[26], 0, bf0);       // k
    gemm_kernel<<<gG, blk, 0, stream>>>(h, 128, W[27], tmp0, 128, N, 128, W[28], 0, bf1);       // v
    gt_attn_kernel<<<gN4, blk, 0, stream>>>(bufA, bf0, bf1, rowptr, csr, tmp1, N);
    gemm_kernel<<<gG, blk, 0, stream>>>(h, 128, W[29], tmp1, 128, N, 128, W[30], ACCF | RELUF, NOB); // z1
    gemm_kernel<<<gG, blk, 0, stream>>>(tmp1, 128, W[23] + 16384, bufA, 128, N, 128, W[24] + 128, 0, NOB);
    gemm_kernel<<<gG, blk, 0, stream>>>(tmp1, 128, W[25] + 16384, bufB, 128, N, 128, W[26] + 128, 0, bf0);
    gemm_kernel<<<gG, blk, 0, stream>>>(tmp1, 128, W[27] + 16384, tmp0, 128, N, 128, W[28] + 128, 0, bf1);
    gt_attn_kernel<<<gN4, blk, 0, stream>>>(bufA, bf0, bf1, rowptr, csr, e2, N);
    gemm_kernel<<<gG, blk, 0, stream>>>(tmp1, 128, W[29] + 16384, e2, 128, N, 128, W[30] + 128, ACCF, NOB);

    // fused combine + two-phase pool + head
    combine4_kernel<<<gN4, blk, 0, stream>>>(h, e0, e1, e2, e3, gates,
                                             W[33], W[34], W[35], outb, N);
    pool_partial_kernel<<<dim3(B, PCH), dim3(128), 0, stream>>>(outb, bstart, bend, partial);
    pool_reduce_kernel<<<dim3(B), dim3(128), 0, stream>>>(partial, bstart, bend, pooled);
    head_kernel<<<dim3(B), dim3(128), 0, stream>>>(pooled,
        W[36], W[37], W[38], W[39],
        W[40], W[41], W[42], W[43],
        W[44], W[45], W[46],
        (float*)d_out, B);
}

// Round 8
// 769.042 us; speedup vs baseline: 2.0127x; 1.3310x over previous
//
#include <hip/hip_runtime.h>

#define RELUF 1
#define ACCF  2
#define PCH   16   // pool chunks per graph
#define NWT   19   // transposed weight matrices

typedef unsigned short ushort_t;
typedef __attribute__((ext_vector_type(8))) short bf16x8;
typedef __attribute__((ext_vector_type(4))) float f32x4;

__device__ __forceinline__ float bf2f(unsigned int v) {
    return __uint_as_float(v << 16);
}
__device__ __forceinline__ unsigned int f2bu(float f) {
    unsigned int u = __float_as_uint(f);
    return (u + 0x7fffu + ((u >> 16) & 1u)) >> 16;
}

// ---------------- utility kernels ----------------
__global__ void zero_i32_kernel(int* __restrict__ p, int n) {
    int i = blockIdx.x * blockDim.x + threadIdx.x;
    if (i < n) p[i] = 0;
}
__global__ void seg_bounds_kernel(const int* __restrict__ batch, int* __restrict__ bstart,
                                  int* __restrict__ bend, int N) {
    int n = blockIdx.x * blockDim.x + threadIdx.x;
    if (n >= N) return;
    int b = batch[n];
    if (n == 0) bstart[b] = 0;
    else {
        int pb = batch[n - 1];
        if (pb != b) { bstart[b] = n; bend[pb] = n; }
    }
    if (n == N - 1) bend[b] = N;
}

// ---------- batched W transpose+convert: Wt[n][k] bf16 <- W[k][n] fp32 ----------
struct WtPack {
    const float* src[NWT];
    unsigned long long off[NWT];
    int K[NWT];
};
__global__ void wconv_kernel(WtPack p, ushort_t* __restrict__ base) {
    int a = blockIdx.y;
    const float* s = p.src[a];
    ushort_t* d = base + p.off[a];
    int K = p.K[a];
    int total = K * 128;
    for (int i = blockIdx.x * blockDim.x + threadIdx.x; i < total; i += gridDim.x * blockDim.x) {
        int k = i >> 7, n = i & 127;
        d[n * K + k] = (ushort_t)f2bu(s[i]);
    }
}

// ---------- MFMA GEMM: C[M,128] = A[M,K] @ W[K,128] (+bias)(+C)(relu) ----------
// A fp32 (converted to bf16 in staging); Wt bf16 n-major [128][K].
// 64x128 tile, 256 threads = 4 waves; wave w does rows 16w..16w+15, 8 col-tiles.
__global__ __launch_bounds__(256)
void gemm_kernel(const float* __restrict__ A, int lda,
                 const ushort_t* __restrict__ Wt,
                 float* __restrict__ C, int ldc,
                 int M, int K,
                 const float* __restrict__ bias, int flags,
                 ushort_t* __restrict__ Cb)
{
    __shared__ ushort_t As[64][40];    // [m][k], pad 40 to break banks
    __shared__ ushort_t Bs[128][40];   // [n][k]
    const int tid = threadIdx.x;
    const int m0 = blockIdx.x * 64;
    const int lane = tid & 63;
    const int wv = tid >> 6;           // wave 0..3
    const int q = lane >> 4;           // quad 0..3
    const int l16 = lane & 15;

    const int sar = tid >> 2;          // A stage row 0..63
    const int sak = (tid & 3) << 3;    // A stage k 0,8,16,24
    const int sbn = tid >> 1;          // B stage n 0..127
    const int sbk = (tid & 1) << 4;    // B stage k 0,16

    const bool arow_ok = (m0 + sar) < M;
    const float* Arow = A + (size_t)(m0 + sar) * lda;
    const ushort_t* Wrow = Wt + (size_t)sbn * K;

    f32x4 acc[8];
#pragma unroll
    for (int t = 0; t < 8; t++) acc[t] = (f32x4){0.f, 0.f, 0.f, 0.f};

    for (int k0 = 0; k0 < K; k0 += 32) {
        // ---- load A chunk (8 fp32 -> bf16) ----
        uint4 apk;
        if (arow_ok && k0 + sak + 8 <= K) {
            float4 p0 = *(const float4*)(Arow + k0 + sak);
            float4 p1 = *(const float4*)(Arow + k0 + sak + 4);
            apk.x = f2bu(p0.x) | (f2bu(p0.y) << 16);
            apk.y = f2bu(p0.z) | (f2bu(p0.w) << 16);
            apk.z = f2bu(p1.x) | (f2bu(p1.y) << 16);
            apk.w = f2bu(p1.z) | (f2bu(p1.w) << 16);
        } else {
            unsigned int t4[4] = {0, 0, 0, 0};
            for (int j = 0; j < 8; j++) {
                int k = k0 + sak + j;
                unsigned int bv = (arow_ok && k < K) ? f2bu(Arow[k]) : 0u;
                t4[j >> 1] |= bv << ((j & 1) * 16);
            }
            apk = make_uint4(t4[0], t4[1], t4[2], t4[3]);
        }
        // ---- load B chunk (16 bf16 contiguous) ----
        uint4 b0, b1;
        if (k0 + sbk + 16 <= K) {
            b0 = *(const uint4*)(Wrow + k0 + sbk);
            b1 = *(const uint4*)(Wrow + k0 + sbk + 8);
        } else {
            unsigned int t8[8] = {0, 0, 0, 0, 0, 0, 0, 0};
            for (int j = 0; j < 16; j++) {
                int k = k0 + sbk + j;
                unsigned int bv = (k < K) ? (unsigned int)Wrow[k] : 0u;
                t8[j >> 1] |= bv << ((j & 1) * 16);
            }
            b0 = make_uint4(t8[0], t8[1], t8[2], t8[3]);
            b1 = make_uint4(t8[4], t8[5], t8[6], t8[7]);
        }
        __syncthreads();   // previous iteration's frag reads done
        *(uint4*)&As[sar][sak] = apk;
        *(uint4*)&Bs[sbn][sbk] = b0;
        *(uint4*)&Bs[sbn][sbk + 8] = b1;
        __syncthreads();
        bf16x8 af = *(const bf16x8*)&As[16 * wv + l16][q * 8];
#pragma unroll
        for (int t = 0; t < 8; t++) {
            bf16x8 bf = *(const bf16x8*)&Bs[t * 16 + l16][q * 8];
            acc[t] = __builtin_amdgcn_mfma_f32_16x16x32_bf16(af, bf, acc[t], 0, 0, 0);
        }
    }
    // ---- epilogue ----
#pragma unroll
    for (int t = 0; t < 8; t++) {
        int col = t * 16 + l16;
        float bb = bias ? bias[col] : 0.f;
#pragma unroll
        for (int r = 0; r < 4; r++) {
            int row = m0 + 16 * wv + q * 4 + r;
            bool ok = row < M;
            float val = acc[t][r] + bb;
            float* cp = C + (size_t)row * ldc + col;
            if (flags & ACCF) { if (ok) val += *cp; }
            if (flags & RELUF) val = fmaxf(val, 0.f);
            if (ok) *cp = val;
            if (Cb) {
                float other = __shfl_xor(val, 1);
                if (!(lane & 1) && ok) {
                    unsigned int pk = f2bu(val) | (f2bu(other) << 16);
                    *(unsigned int*)(Cb + (size_t)row * 128 + col) = pk;
                }
            }
        }
    }
}

// ---------- LayerNorm(128) + ReLU in place (+ optional bf16 shadow) ----------
__global__ void ln_relu_kernel(float* __restrict__ X, int ld,
                               const float* __restrict__ g,
                               const float* __restrict__ b, int M,
                               ushort_t* __restrict__ Xb)
{
    int node = blockIdx.x * 4 + (threadIdx.x >> 6);
    int lane = threadIdx.x & 63;
    if (node >= M) return;
    float* row = X + (size_t)node * ld;
    float2 v = *(float2*)(row + lane * 2);
    float s = v.x + v.y, sq = v.x * v.x + v.y * v.y;
#pragma unroll
    for (int off = 32; off; off >>= 1) { s += __shfl_xor(s, off); sq += __shfl_xor(sq, off); }
    float mean = s * (1.f / 128.f);
    float var = sq * (1.f / 128.f) - mean * mean;
    float inv = rsqrtf(var + 1e-5f);
    float y0 = fmaxf((v.x - mean) * inv * g[lane * 2] + b[lane * 2], 0.f);
    float y1 = fmaxf((v.y - mean) * inv * g[lane * 2 + 1] + b[lane * 2 + 1], 0.f);
    *(float2*)(row + lane * 2) = make_float2(y0, y1);
    if (Xb) {
        unsigned int p = f2bu(y0) | (f2bu(y1) << 16);
        *(unsigned int*)(Xb + (size_t)node * 128 + lane * 2) = p;
    }
}

// ---------- router ----------
__global__ void router_kernel(const float* __restrict__ hr, const float* __restrict__ rW,
                              float* __restrict__ gates, int M)
{
    int node = blockIdx.x * 4 + (threadIdx.x >> 6);
    int lane = threadIdx.x & 63;
    if (node >= M) return;
    const float* row = hr + (size_t)node * 256;
    float a0 = 0, a1 = 0, a2 = 0, a3 = 0;
#pragma unroll
    for (int i = 0; i < 4; i++) {
        int k = lane + i * 64;
        float xv = row[k];
        float4 wv = *(const float4*)(rW + k * 4);
        a0 = fmaf(xv, wv.x, a0); a1 = fmaf(xv, wv.y, a1);
        a2 = fmaf(xv, wv.z, a2); a3 = fmaf(xv, wv.w, a3);
    }
#pragma unroll
    for (int off = 32; off; off >>= 1) {
        a0 += __shfl_xor(a0, off); a1 += __shfl_xor(a1, off);
        a2 += __shfl_xor(a2, off); a3 += __shfl_xor(a3, off);
    }
    if (lane == 0) {
        float l[4] = {a0 * (1.f / 1.5f), a1 * (1.f / 1.5f), a2 * (1.f / 1.5f), a3 * (1.f / 1.5f)};
        float mx = fmaxf(fmaxf(l[0], l[1]), fmaxf(l[2], l[3]));
        float e[4], ssum = 0.f;
#pragma unroll
        for (int i = 0; i < 4; i++) { e[i] = expf(l[i] - mx); ssum += e[i]; }
        float p[4];
#pragma unroll
        for (int i = 0; i < 4; i++) p[i] = e[i] / ssum;
        int i0 = 0;
        for (int i = 1; i < 4; i++) if (p[i] > p[i0]) i0 = i;
        int i1 = -1;
        for (int i = 0; i < 4; i++) {
            if (i == i0) continue;
            if (i1 < 0 || p[i] > p[i1]) i1 = i;
        }
        float wsum = fmaxf(p[i0] + p[i1], 1e-9f);
        float gg[4] = {0.f, 0.f, 0.f, 0.f};
        gg[i0] = p[i0] / wsum;
        gg[i1] = p[i1] / wsum;
        *(float4*)(gates + (size_t)node * 4) = make_float4(gg[0], gg[1], gg[2], gg[3]);
    }
}

// ---------- graph structure ----------
__global__ void edge_deg_kernel(const int* __restrict__ dst, int* __restrict__ degi, int E) {
    int e = blockIdx.x * blockDim.x + threadIdx.x;
    if (e < E) atomicAdd(&degi[dst[e]], 1);
}
__global__ void scan_kernel(const int* __restrict__ degi, int* __restrict__ rowptr, int n) {
    __shared__ int sh[256];
    __shared__ int sbase;
    int tid = threadIdx.x;
    if (tid == 0) { sbase = 0; rowptr[0] = 0; }
    __syncthreads();
    const int CH = 256 * 8;
    for (int c0 = 0; c0 < n; c0 += CH) {
        int loc[8]; int s = 0;
        int base_i = c0 + tid * 8;
#pragma unroll
        for (int j = 0; j < 8; j++) {
            int idx = base_i + j;
            int v = (idx < n) ? degi[idx] : 0;
            s += v; loc[j] = s;
        }
        sh[tid] = s;
        __syncthreads();
        for (int off = 1; off < 256; off <<= 1) {
            int t = (tid >= off) ? sh[tid - off] : 0;
            __syncthreads();
            sh[tid] += t;
            __syncthreads();
        }
        int prev = (tid > 0) ? sh[tid - 1] : 0;
        int b = sbase;
        int total = sh[255];
#pragma unroll
        for (int j = 0; j < 8; j++) {
            int idx = base_i + j;
            if (idx < n) rowptr[idx + 1] = b + prev + loc[j];
        }
        __syncthreads();
        if (tid == 0) sbase = b + total;
        __syncthreads();
    }
}
__global__ void csr_fill_kernel(const int* __restrict__ src, const int* __restrict__ dst,
                                const int* __restrict__ rowptr, int* __restrict__ cursor,
                                int* __restrict__ csr, int E) {
    int e = blockIdx.x * blockDim.x + threadIdx.x;
    if (e >= E) return;
    int d = dst[e];
    int pos = atomicAdd(&cursor[d], 1);
    csr[rowptr[d] + pos] = src[e];
}
__global__ void dinv_kernel(const int* __restrict__ degi, float* __restrict__ dinv,
                            float* __restrict__ dinvl, int N) {
    int n = blockIdx.x * blockDim.x + threadIdx.x;
    if (n >= N) return;
    float deg = (float)degi[n];
    dinv[n] = (deg > 0.f) ? rsqrtf(fmaxf(deg, 1.f)) : 0.f;
    dinvl[n] = rsqrtf(deg + 1.f);
}

// ---------- gather propagation over bf16 features, fp32 accumulate ----------
__global__ void gather_kernel(const ushort_t* __restrict__ Xb, float* __restrict__ Out,
                              const int* __restrict__ rowptr, const int* __restrict__ csr,
                              const float* __restrict__ dv, int self_loop, float scale,
                              const float* __restrict__ bias, int relu, int M)
{
    int node = blockIdx.x * 4 + (threadIdx.x >> 6);
    int lane = threadIdx.x & 63;
    if (node >= M) return;
    int beg = rowptr[node], end = rowptr[node + 1];
    float dn = dv[node];
    float ax = 0.f, ay = 0.f;
    int e = beg;
    for (; e + 3 < end; e += 4) {
        int s0 = csr[e], s1 = csr[e + 1], s2 = csr[e + 2], s3 = csr[e + 3];
        float c0 = dn * dv[s0], c1 = dn * dv[s1], c2 = dn * dv[s2], c3 = dn * dv[s3];
        unsigned int u0 = *(const unsigned int*)(Xb + (size_t)s0 * 128 + lane * 2);
        unsigned int u1 = *(const unsigned int*)(Xb + (size_t)s1 * 128 + lane * 2);
        unsigned int u2 = *(const unsigned int*)(Xb + (size_t)s2 * 128 + lane * 2);
        unsigned int u3 = *(const unsigned int*)(Xb + (size_t)s3 * 128 + lane * 2);
        ax = fmaf(c0, bf2f(u0 & 0xffff), fmaf(c1, bf2f(u1 & 0xffff),
             fmaf(c2, bf2f(u2 & 0xffff), fmaf(c3, bf2f(u3 & 0xffff), ax))));
        ay = fmaf(c0, bf2f(u0 >> 16), fmaf(c1, bf2f(u1 >> 16),
             fmaf(c2, bf2f(u2 >> 16), fmaf(c3, bf2f(u3 >> 16), ay))));
    }
    for (; e < end; e++) {
        int s = csr[e];
        float c = dn * dv[s];
        unsigned int u = *(const unsigned int*)(Xb + (size_t)s * 128 + lane * 2);
        ax = fmaf(c, bf2f(u & 0xffff), ax);
        ay = fmaf(c, bf2f(u >> 16), ay);
    }
    if (self_loop) {
        float c = dn * dn;
        unsigned int u = *(const unsigned int*)(Xb + (size_t)node * 128 + lane * 2);
        ax = fmaf(c, bf2f(u & 0xffff), ax);
        ay = fmaf(c, bf2f(u >> 16), ay);
    }
    ax *= scale; ay *= scale;
    if (bias) { ax += bias[lane * 2]; ay += bias[lane * 2 + 1]; }
    if (relu) { ax = fmaxf(ax, 0.f); ay = fmaxf(ay, 0.f); }
    *(float2*)(Out + (size_t)node * 128 + lane * 2) = make_float2(ax, ay);
}

// ---------- attention: no-max softmax (shift-invariant; logits tiny), unroll 4 ----------
__global__ void gt_attn_kernel(const float* __restrict__ Q, const ushort_t* __restrict__ Kb,
                               const ushort_t* __restrict__ Vb, const int* __restrict__ rowptr,
                               const int* __restrict__ csr, float* __restrict__ Out, int M)
{
    const float SCL = 0.17677669529663689f * 1.4426950408889634f; // 1/sqrt(32) * log2(e)
    int node = blockIdx.x * 4 + (threadIdx.x >> 6);
    int lane = threadIdx.x & 63;
    if (node >= M) return;
    int beg = rowptr[node], end = rowptr[node + 1];
    float2 q = *(const float2*)(Q + (size_t)node * 128 + lane * 2);
    q.x *= SCL; q.y *= SCL;
    float den = 0.f, ax = 0.f, ay = 0.f;
    int e = beg;
    for (; e + 3 < end; e += 4) {
        int s0 = csr[e], s1 = csr[e + 1], s2 = csr[e + 2], s3 = csr[e + 3];
        unsigned int k0 = *(const unsigned int*)(Kb + (size_t)s0 * 128 + lane * 2);
        unsigned int k1 = *(const unsigned int*)(Kb + (size_t)s1 * 128 + lane * 2);
        unsigned int k2 = *(const unsigned int*)(Kb + (size_t)s2 * 128 + lane * 2);
        unsigned int k3 = *(const unsigned int*)(Kb + (size_t)s3 * 128 + lane * 2);
        unsigned int v0 = *(const unsigned int*)(Vb + (size_t)s0 * 128 + lane * 2);
        unsigned int v1 = *(const unsigned int*)(Vb + (size_t)s1 * 128 + lane * 2);
        unsigned int v2 = *(const unsigned int*)(Vb + (size_t)s2 * 128 + lane * 2);
        unsigned int v3 = *(const unsigned int*)(Vb + (size_t)s3 * 128 + lane * 2);
        float p0 = q.x * bf2f(k0 & 0xffff) + q.y * bf2f(k0 >> 16);
        float p1 = q.x * bf2f(k1 & 0xffff) + q.y * bf2f(k1 >> 16);
        float p2 = q.x * bf2f(k2 & 0xffff) + q.y * bf2f(k2 >> 16);
        float p3 = q.x * bf2f(k3 & 0xffff) + q.y * bf2f(k3 >> 16);
#pragma unroll
        for (int off = 1; off <= 8; off <<= 1) {
            p0 += __shfl_xor(p0, off); p1 += __shfl_xor(p1, off);
            p2 += __shfl_xor(p2, off); p3 += __shfl_xor(p3, off);
        }
        float w0 = exp2f(fminf(p0, 80.f));
        float w1 = exp2f(fminf(p1, 80.f));
        float w2 = exp2f(fminf(p2, 80.f));
        float w3 = exp2f(fminf(p3, 80.f));
        den += (w0 + w1) + (w2 + w3);
        ax = fmaf(w0, bf2f(v0 & 0xffff), fmaf(w1, bf2f(v1 & 0xffff),
             fmaf(w2, bf2f(v2 & 0xffff), fmaf(w3, bf2f(v3 & 0xffff), ax))));
        ay = fmaf(w0, bf2f(v0 >> 16), fmaf(w1, bf2f(v1 >> 16),
             fmaf(w2, bf2f(v2 >> 16), fmaf(w3, bf2f(v3 >> 16), ay))));
    }
    for (; e < end; e++) {
        int s = csr[e];
        unsigned int ku = *(const unsigned int*)(Kb + (size_t)s * 128 + lane * 2);
        unsigned int vu = *(const unsigned int*)(Vb + (size_t)s * 128 + lane * 2);
        float p = q.x * bf2f(ku & 0xffff) + q.y * bf2f(ku >> 16);
#pragma unroll
        for (int off = 1; off <= 8; off <<= 1) p += __shfl_xor(p, off);
        float w = exp2f(fminf(p, 80.f));
        den += w;
        ax = fmaf(w, bf2f(vu & 0xffff), ax);
        ay = fmaf(w, bf2f(vu >> 16), ay);
    }
    float d = fmaxf(den, 1e-9f);
    *(float2*)(Out + (size_t)node * 128 + lane * 2) = make_float2(ax / d, ay / d);
}

// ---------- fused: out = h + sum_e gates[e] * (LN(e_i)*scale_e) ----------
__global__ void combine4_kernel(const float* __restrict__ h,
                                const float* __restrict__ e0, const float* __restrict__ e1,
                                const float* __restrict__ e2, const float* __restrict__ e3,
                                const float* __restrict__ gates,
                                const float* __restrict__ png, const float* __restrict__ pnb,
                                const float* __restrict__ esc,
                                float* __restrict__ Out, int M)
{
    int node = blockIdx.x * 4 + (threadIdx.x >> 6);
    int lane = threadIdx.x & 63;
    if (node >= M) return;
    size_t ofs = (size_t)node * 128 + lane * 2;
    const float* ep[4] = {e0 + ofs, e1 + ofs, e2 + ofs, e3 + ofs};
    float4 gg = *(const float4*)(gates + (size_t)node * 4);
    float gv[4] = {gg.x, gg.y, gg.z, gg.w};
    float2 hv = *(const float2*)(h + ofs);
    float ox = hv.x, oy = hv.y;
#pragma unroll
    for (int e = 0; e < 4; e++) {
        float2 v = *(const float2*)ep[e];
        float s = v.x + v.y, sq = v.x * v.x + v.y * v.y;
#pragma unroll
        for (int off = 32; off; off >>= 1) { s += __shfl_xor(s, off); sq += __shfl_xor(sq, off); }
        float mean = s * (1.f / 128.f);
        float var = sq * (1.f / 128.f) - mean * mean;
        float inv = rsqrtf(var + 1e-5f);
        float g0 = png[e * 128 + lane * 2], g1 = png[e * 128 + lane * 2 + 1];
        float b0 = pnb[e * 128 + lane * 2], b1 = pnb[e * 128 + lane * 2 + 1];
        float c = esc[e] * gv[e];
        ox = fmaf(c, (v.x - mean) * inv * g0 + b0, ox);
        oy = fmaf(c, (v.y - mean) * inv * g1 + b1, oy);
    }
    *(float2*)(Out + ofs) = make_float2(ox, oy);
}

// ---------- two-phase segmented mean-pool ----------
__global__ void pool_partial_kernel(const float* __restrict__ Out,
                                    const int* __restrict__ bstart, const int* __restrict__ bend,
                                    float* __restrict__ partial)
{
    int b = blockIdx.x, c = blockIdx.y, t = threadIdx.x;
    int s = bstart[b], e = bend[b];
    float sum = 0.f;
    for (int n = s + c; n < e; n += PCH) sum += Out[(size_t)n * 128 + t];
    partial[((size_t)b * PCH + c) * 128 + t] = sum;
}
__global__ void pool_reduce_kernel(const float* __restrict__ partial,
                                   const int* __restrict__ bstart, const int* __restrict__ bend,
                                   float* __restrict__ pooled)
{
    int b = blockIdx.x, t = threadIdx.x;
    float sum = 0.f;
#pragma unroll
    for (int c = 0; c < PCH; c++) sum += partial[((size_t)b * PCH + c) * 128 + t];
    float cnt = fmaxf((float)(bend[b] - bstart[b]), 1.f);
    pooled[(size_t)b * 128 + t] = sum / cnt;
}

// ---------- classification head (fp32 out) ----------
__global__ void head_kernel(const float* __restrict__ pooled,
                            const float* __restrict__ h1W, const float* __restrict__ h1b,
                            const float* __restrict__ h1g, const float* __restrict__ h1be,
                            const float* __restrict__ h2W, const float* __restrict__ h2b,
                            const float* __restrict__ h2g, const float* __restrict__ h2be,
                            const float* __restrict__ h3W, const float* __restrict__ h3b,
                            const float* __restrict__ lbias,
                            float* __restrict__ out, int B)
{
    __shared__ float p[128], z[128];
    int b = blockIdx.x, t = threadIdx.x;
    p[t] = pooled[(size_t)b * 128 + t];
    __syncthreads();
    float a = h1b[t];
    for (int k = 0; k < 128; k++) a = fmaf(p[k], h1W[k * 128 + t], a);
    z[t] = a;
    __syncthreads();
    float s = 0.f, sq = 0.f;
    for (int k = 0; k < 128; k++) { float x = z[k]; s += x; sq += x * x; }
    float mean = s * (1.f / 128.f), var = sq * (1.f / 128.f) - mean * mean;
    float y = fmaxf((a - mean) * rsqrtf(var + 1e-5f) * h1g[t] + h1be[t], 0.f);
    __syncthreads();
    z[t] = y;
    __syncthreads();
    float a2 = 0.f;
    if (t < 64) {
        a2 = h2b[t];
        for (int k = 0; k < 128; k++) a2 = fmaf(z[k], h2W[k * 64 + t], a2);
    }
    __syncthreads();
    if (t < 64) p[t] = a2;
    __syncthreads();
    if (t < 2) {
        float s2 = 0.f, sq2 = 0.f;
        for (int k = 0; k < 64; k++) { float x = p[k]; s2 += x; sq2 += x * x; }
        float mean2 = s2 * (1.f / 64.f), var2 = sq2 * (1.f / 64.f) - mean2 * mean2;
        float inv2 = rsqrtf(var2 + 1e-5f);
        float o = h3b[t] + lbias[t];
        for (int k = 0; k < 64; k++) {
            float zc = fmaxf((p[k] - mean2) * inv2 * h2g[k] + h2be[k], 0.f);
            o = fmaf(zc, h3W[k * 2 + t], o);
        }
        out[b * 2 + t] = o;
    }
}

// ---------------- launch ----------------
extern "C" void kernel_launch(void* const* d_in, const int* in_sizes, int n_in,
                              void* d_out, int out_size, void* d_ws, size_t ws_size,
                              hipStream_t stream)
{
    (void)ws_size; (void)n_in;
    const int N = in_sizes[3];
    const int E = in_sizes[2] / 2;
    const int B = out_size / 2;

    const int* ei = (const int*)d_in[2];
    const int* src = ei;
    const int* dst = ei + E;
    const int* batch = (const int*)d_in[3];

    const float* W[47];
    for (int i = 0; i < 47; i++) W[i] = (const float*)d_in[i];

    size_t fN = (size_t)N;
    float* hr    = (float*)d_ws;        // 256N: bufA/bufB after router
    float* h     = hr + 256 * fN;
    float* e0    = h + 128 * fN;
    float* e1    = e0 + 128 * fN;
    float* e2    = e1 + 128 * fN;
    float* e3    = e2 + 128 * fN;
    float* tmp0  = e3 + 128 * fN;
    float* tmp1  = tmp0 + 128 * fN;
    float* gates = tmp1 + 128 * fN;
    float* dinv  = gates + 4 * fN;
    float* dinvl = dinv + fN;
    float* pooled = dinvl + fN;                              // 128*B
    float* partial = pooled + (size_t)128 * B;               // 128*B*PCH
    ushort_t* hb  = (ushort_t*)(partial + (size_t)128 * B * PCH);
    ushort_t* bf0 = hb + 128 * fN;
    ushort_t* bf1 = bf0 + 128 * fN;
    ushort_t* wt  = bf1 + 128 * fN;                          // transposed weights (~670KB)
    // wt layout table
    WtPack wp;
    const float* wsrc[NWT] = {
        W[4], W[8], W[12], W[17], W[19],
        W[21], W[21] + 16384, W[21] + 32768, W[21] + 49152,
        W[23], W[23] + 16384, W[25], W[25] + 16384,
        W[27], W[27] + 16384, W[29], W[29] + 16384,
        W[31], W[31] + 16384
    };
    const int wk[NWT] = {200, 128, 256, 128, 128,
                         128, 128, 128, 128,
                         128, 128, 128, 128,
                         128, 128, 128, 128,
                         128, 128};
    unsigned long long woff[NWT];
    unsigned long long acc_off = 0;
    for (int i = 0; i < NWT; i++) {
        wp.src[i] = wsrc[i];
        wp.K[i] = wk[i];
        wp.off[i] = acc_off;
        woff[i] = acc_off;
        acc_off += (unsigned long long)128 * wk[i];
    }
    int* degi   = (int*)(wt + acc_off + 8);
    int* cursor = degi + N;
    int* rowptr = cursor + N;
    int* csr    = rowptr + (N + 1);
    int* bstart = csr + E;
    int* bend   = bstart + B;
    float* bufA = hr;
    float* bufB = hr + 128 * fN;
    float* outb = tmp0;

    dim3 blk(256);
    int gN4 = (N + 3) / 4;
    dim3 gG((N + 63) / 64);
    ushort_t* NOB = (ushort_t*)0;

    // weight transpose+convert, graph structure
    wconv_kernel<<<dim3(32, NWT), blk, 0, stream>>>(wp, wt);
    zero_i32_kernel<<<(2 * N + 255) / 256, blk, 0, stream>>>(degi, 2 * N);
    zero_i32_kernel<<<1, blk, 0, stream>>>(bstart, 2 * B);
    seg_bounds_kernel<<<(N + 255) / 256, blk, 0, stream>>>(batch, bstart, bend, N);
    edge_deg_kernel<<<(E + 255) / 256, blk, 0, stream>>>(dst, degi, E);
    scan_kernel<<<1, blk, 0, stream>>>(degi, rowptr, N);
    csr_fill_kernel<<<(E + 255) / 256, blk, 0, stream>>>(src, dst, rowptr, cursor, csr, E);
    dinv_kernel<<<(N + 255) / 256, blk, 0, stream>>>(degi, dinv, dinvl, N);

    // encoders + fuse + router
    gemm_kernel<<<gG, blk, 0, stream>>>(W[0], 200, wt + woff[0], hr, 256, N, 200, W[5], 0, NOB);
    gemm_kernel<<<gG, blk, 0, stream>>>(W[1], 128, wt + woff[1], hr + 128, 256, N, 128, W[9], 0, NOB);
    ln_relu_kernel<<<gN4, blk, 0, stream>>>(hr, 256, W[6], W[7], N, NOB);
    ln_relu_kernel<<<gN4, blk, 0, stream>>>(hr + 128, 256, W[10], W[11], N, NOB);
    router_kernel<<<gN4, blk, 0, stream>>>(hr, W[16], gates, N);
    gemm_kernel<<<gG, blk, 0, stream>>>(hr, 256, wt + woff[2], h, 128, N, 256, W[13], 0, NOB);
    ln_relu_kernel<<<gN4, blk, 0, stream>>>(h, 128, W[14], W[15], N, hb);

    // expert 0: MLP
    gemm_kernel<<<gG, blk, 0, stream>>>(h, 128, wt + woff[3], bufA, 128, N, 128, W[18], RELUF, NOB);
    gemm_kernel<<<gG, blk, 0, stream>>>(bufA, 128, wt + woff[4], e0, 128, N, 128, W[20], 0, NOB);

    // expert 1: ChebNet K=2
    gather_kernel<<<gN4, blk, 0, stream>>>(hb, bufA, rowptr, csr, dinv, 0, -1.f, (const float*)0, 0, N);
    gemm_kernel<<<gG, blk, 0, stream>>>(h, 128, wt + woff[5], bufB, 128, N, 128, W[22], 0, NOB);
    gemm_kernel<<<gG, blk, 0, stream>>>(bufA, 128, wt + woff[6], bufB, 128, N, 128, (const float*)0, ACCF | RELUF, bf0);
    gather_kernel<<<gN4, blk, 0, stream>>>(bf0, bufA, rowptr, csr, dinv, 0, -1.f, (const float*)0, 0, N);
    gemm_kernel<<<gG, blk, 0, stream>>>(bufB, 128, wt + woff[7], e1, 128, N, 128, W[22] + 128, 0, NOB);
    gemm_kernel<<<gG, blk, 0, stream>>>(bufA, 128, wt + woff[8], e1, 128, N, 128, (const float*)0, ACCF, NOB);

    // expert 3: GCN
    gemm_kernel<<<gG, blk, 0, stream>>>(h, 128, wt + woff[17], bufA, 128, N, 128, (const float*)0, 0, bf0);
    gather_kernel<<<gN4, blk, 0, stream>>>(bf0, bufB, rowptr, csr, dinvl, 1, 1.f, W[32], 1, N);
    gemm_kernel<<<gG, blk, 0, stream>>>(bufB, 128, wt + woff[18], bufA, 128, N, 128, (const float*)0, 0, bf0);
    gather_kernel<<<gN4, blk, 0, stream>>>(bf0, e3, rowptr, csr, dinvl, 1, 1.f, W[32] + 128, 0, N);

    // expert 2: Graph Transformer (2 layers)
    gemm_kernel<<<gG, blk, 0, stream>>>(h, 128, wt + woff[9], bufA, 128, N, 128, W[24], 0, NOB);   // q
    gemm_kernel<<<gG, blk, 0, stream>>>(h, 128, wt + woff[11], bufB, 128, N, 128, W[26], 0, bf0);  // k
    gemm_kernel<<<gG, blk, 0, stream>>>(h, 128, wt + woff[13], tmp0, 128, N, 128, W[28], 0, bf1);  // v
    gt_attn_kernel<<<gN4, blk, 0, stream>>>(bufA, bf0, bf1, rowptr, csr, tmp1, N);
    gemm_kernel<<<gG, blk, 0, stream>>>(h, 128, wt + woff[15], tmp1, 128, N, 128, W[30], ACCF | RELUF, NOB);
    gemm_kernel<<<gG, blk, 0, stream>>>(tmp1, 128, wt + woff[10], bufA, 128, N, 128, W[24] + 128, 0, NOB);
    gemm_kernel<<<gG, blk, 0, stream>>>(tmp1, 128, wt + woff[12], bufB, 128, N, 128, W[26] + 128, 0, bf0);
    gemm_kernel<<<gG, blk, 0, stream>>>(tmp1, 128, wt + woff[14], tmp0, 128, N, 128, W[28] + 128, 0, bf1);
    gt_attn_kernel<<<gN4, blk, 0, stream>>>(bufA, bf0, bf1, rowptr, csr, e2, N);
    gemm_kernel<<<gG, blk, 0, stream>>>(tmp1, 128, wt + woff[16], e2, 128, N, 128, W[30] + 128, ACCF, NOB);

    // fused combine + two-phase pool + head
    combine4_kernel<<<gN4, blk, 0, stream>>>(h, e0, e1, e2, e3, gates,
                                             W[33], W[34], W[35], outb, N);
    pool_partial_kernel<<<dim3(B, PCH), dim3(128), 0, stream>>>(outb, bstart, bend, partial);
    pool_reduce_kernel<<<dim3(B), dim3(128), 0, stream>>>(partial, bstart, bend, pooled);
    head_kernel<<<dim3(B), dim3(128), 0, stream>>>(pooled,
        W[36], W[37], W[38], W[39],
        W[40], W[41], W[42], W[43],
        W[44], W[45], W[46],
        (float*)d_out, B);
}

// Round 9
// 715.452 us; speedup vs baseline: 2.1635x; 1.0749x over previous
//
#include <hip/hip_runtime.h>

#define RELUF 1
#define ACCF  2
#define PCH   16    // pool chunks per graph
#define NWT   19    // transposed weight matrices
#define SCH   2048  // elements per scan block

typedef unsigned short ushort_t;
typedef __attribute__((ext_vector_type(8))) short bf16x8;
typedef __attribute__((ext_vector_type(4))) float f32x4;

__device__ __forceinline__ float bf2f(unsigned int v) {
    return __uint_as_float(v << 16);
}
__device__ __forceinline__ unsigned int f2bu(float f) {
    unsigned int u = __float_as_uint(f);
    return (u + 0x7fffu + ((u >> 16) & 1u)) >> 16;
}

// ---------------- utility kernels ----------------
__global__ void zero_i32_kernel(int* __restrict__ p, int n) {
    int i = blockIdx.x * blockDim.x + threadIdx.x;
    if (i < n) p[i] = 0;
}
__global__ void seg_bounds_kernel(const int* __restrict__ batch, int* __restrict__ bstart,
                                  int* __restrict__ bend, int N) {
    int n = blockIdx.x * blockDim.x + threadIdx.x;
    if (n >= N) return;
    int b = batch[n];
    if (n == 0) bstart[b] = 0;
    else {
        int pb = batch[n - 1];
        if (pb != b) { bstart[b] = n; bend[pb] = n; }
    }
    if (n == N - 1) bend[b] = N;
}

// ---------- parallel 3-phase exclusive scan (rowptr from degi) ----------
__global__ void scan1_kernel(const int* __restrict__ degi, int* __restrict__ rowptr,
                             int* __restrict__ bsum, int n) {
    __shared__ int sh[256];
    int tid = threadIdx.x;
    int base = blockIdx.x * SCH + tid * 8;
    int loc[8]; int s = 0;
#pragma unroll
    for (int j = 0; j < 8; j++) {
        int idx = base + j;
        int v = (idx < n) ? degi[idx] : 0;
        s += v; loc[j] = s;
    }
    sh[tid] = s;
    __syncthreads();
    for (int off = 1; off < 256; off <<= 1) {
        int t = (tid >= off) ? sh[tid - off] : 0;
        __syncthreads();
        sh[tid] += t;
        __syncthreads();
    }
    int prev = (tid > 0) ? sh[tid - 1] : 0;
#pragma unroll
    for (int j = 0; j < 8; j++) {
        int idx = base + j;
        if (idx < n) rowptr[idx + 1] = prev + loc[j];  // block-local inclusive
    }
    if (tid == 255) bsum[blockIdx.x] = sh[255];
}
__global__ void scan2_kernel(int* __restrict__ bsum, int nb) {
    __shared__ int sh[256];
    int tid = threadIdx.x;
    sh[tid] = (tid < nb) ? bsum[tid] : 0;
    __syncthreads();
    for (int off = 1; off < 256; off <<= 1) {
        int t = (tid >= off) ? sh[tid - off] : 0;
        __syncthreads();
        sh[tid] += t;
        __syncthreads();
    }
    if (tid < nb) bsum[tid] = (tid > 0) ? sh[tid - 1] : 0;  // exclusive base
}
__global__ void scan3_kernel(int* __restrict__ rowptr, const int* __restrict__ bsum, int n) {
    int i = blockIdx.x * blockDim.x + threadIdx.x;
    if (i == 0) rowptr[0] = 0;
    if (i < n) rowptr[i + 1] += bsum[i / SCH];
}

// ---------- batched W transpose+convert: Wt[n][k] bf16 <- W[k][n] fp32 ----------
struct WtPack {
    const float* src[NWT];
    unsigned long long off[NWT];
    int K[NWT];
};
__global__ void wconv_kernel(WtPack p, ushort_t* __restrict__ base) {
    int a = blockIdx.y;
    const float* s = p.src[a];
    ushort_t* d = base + p.off[a];
    int K = p.K[a];
    int total = K * 128;
    for (int i = blockIdx.x * blockDim.x + threadIdx.x; i < total; i += gridDim.x * blockDim.x) {
        int k = i >> 7, n = i & 127;
        d[n * K + k] = (ushort_t)f2bu(s[i]);
    }
}

// ---------- MFMA GEMM: C[M,128] = A[M,K] @ W[K,128] (+bias)(+C)(relu) ----------
__global__ __launch_bounds__(256)
void gemm_kernel(const float* __restrict__ A, int lda,
                 const ushort_t* __restrict__ Wt,
                 float* __restrict__ C, int ldc,
                 int M, int K,
                 const float* __restrict__ bias, int flags,
                 ushort_t* __restrict__ Cb)
{
    __shared__ ushort_t As[64][40];
    __shared__ ushort_t Bs[128][40];
    const int tid = threadIdx.x;
    const int m0 = blockIdx.x * 64;
    const int lane = tid & 63;
    const int wv = tid >> 6;
    const int q = lane >> 4;
    const int l16 = lane & 15;

    const int sar = tid >> 2;
    const int sak = (tid & 3) << 3;
    const int sbn = tid >> 1;
    const int sbk = (tid & 1) << 4;

    const bool arow_ok = (m0 + sar) < M;
    const float* Arow = A + (size_t)(m0 + sar) * lda;
    const ushort_t* Wrow = Wt + (size_t)sbn * K;

    f32x4 acc[8];
#pragma unroll
    for (int t = 0; t < 8; t++) acc[t] = (f32x4){0.f, 0.f, 0.f, 0.f};

    for (int k0 = 0; k0 < K; k0 += 32) {
        uint4 apk;
        if (arow_ok && k0 + sak + 8 <= K) {
            float4 p0 = *(const float4*)(Arow + k0 + sak);
            float4 p1 = *(const float4*)(Arow + k0 + sak + 4);
            apk.x = f2bu(p0.x) | (f2bu(p0.y) << 16);
            apk.y = f2bu(p0.z) | (f2bu(p0.w) << 16);
            apk.z = f2bu(p1.x) | (f2bu(p1.y) << 16);
            apk.w = f2bu(p1.z) | (f2bu(p1.w) << 16);
        } else {
            unsigned int t4[4] = {0, 0, 0, 0};
            for (int j = 0; j < 8; j++) {
                int k = k0 + sak + j;
                unsigned int bv = (arow_ok && k < K) ? f2bu(Arow[k]) : 0u;
                t4[j >> 1] |= bv << ((j & 1) * 16);
            }
            apk = make_uint4(t4[0], t4[1], t4[2], t4[3]);
        }
        uint4 b0, b1;
        if (k0 + sbk + 16 <= K) {
            b0 = *(const uint4*)(Wrow + k0 + sbk);
            b1 = *(const uint4*)(Wrow + k0 + sbk + 8);
        } else {
            unsigned int t8[8] = {0, 0, 0, 0, 0, 0, 0, 0};
            for (int j = 0; j < 16; j++) {
                int k = k0 + sbk + j;
                unsigned int bv = (k < K) ? (unsigned int)Wrow[k] : 0u;
                t8[j >> 1] |= bv << ((j & 1) * 16);
            }
            b0 = make_uint4(t8[0], t8[1], t8[2], t8[3]);
            b1 = make_uint4(t8[4], t8[5], t8[6], t8[7]);
        }
        __syncthreads();
        *(uint4*)&As[sar][sak] = apk;
        *(uint4*)&Bs[sbn][sbk] = b0;
        *(uint4*)&Bs[sbn][sbk + 8] = b1;
        __syncthreads();
        bf16x8 af = *(const bf16x8*)&As[16 * wv + l16][q * 8];
#pragma unroll
        for (int t = 0; t < 8; t++) {
            bf16x8 bf = *(const bf16x8*)&Bs[t * 16 + l16][q * 8];
            acc[t] = __builtin_amdgcn_mfma_f32_16x16x32_bf16(af, bf, acc[t], 0, 0, 0);
        }
    }
#pragma unroll
    for (int t = 0; t < 8; t++) {
        int col = t * 16 + l16;
        float bb = bias ? bias[col] : 0.f;
#pragma unroll
        for (int r = 0; r < 4; r++) {
            int row = m0 + 16 * wv + q * 4 + r;
            bool ok = row < M;
            float val = acc[t][r] + bb;
            float* cp = C + (size_t)row * ldc + col;
            if (flags & ACCF) { if (ok) val += *cp; }
            if (flags & RELUF) val = fmaxf(val, 0.f);
            if (ok) *cp = val;
            if (Cb) {
                float other = __shfl_xor(val, 1);
                if (!(lane & 1) && ok) {
                    unsigned int pk = f2bu(val) | (f2bu(other) << 16);
                    *(unsigned int*)(Cb + (size_t)row * 128 + col) = pk;
                }
            }
        }
    }
}

// ---------- LayerNorm(128) + ReLU in place (+ optional bf16 shadow) ----------
__global__ void ln_relu_kernel(float* __restrict__ X, int ld,
                               const float* __restrict__ g,
                               const float* __restrict__ b, int M,
                               ushort_t* __restrict__ Xb)
{
    int node = blockIdx.x * 4 + (threadIdx.x >> 6);
    int lane = threadIdx.x & 63;
    if (node >= M) return;
    float* row = X + (size_t)node * ld;
    float2 v = *(float2*)(row + lane * 2);
    float s = v.x + v.y, sq = v.x * v.x + v.y * v.y;
#pragma unroll
    for (int off = 32; off; off >>= 1) { s += __shfl_xor(s, off); sq += __shfl_xor(sq, off); }
    float mean = s * (1.f / 128.f);
    float var = sq * (1.f / 128.f) - mean * mean;
    float inv = rsqrtf(var + 1e-5f);
    float y0 = fmaxf((v.x - mean) * inv * g[lane * 2] + b[lane * 2], 0.f);
    float y1 = fmaxf((v.y - mean) * inv * g[lane * 2 + 1] + b[lane * 2 + 1], 0.f);
    *(float2*)(row + lane * 2) = make_float2(y0, y1);
    if (Xb) {
        unsigned int p = f2bu(y0) | (f2bu(y1) << 16);
        *(unsigned int*)(Xb + (size_t)node * 128 + lane * 2) = p;
    }
}

// ---------- router ----------
__global__ void router_kernel(const float* __restrict__ hr, const float* __restrict__ rW,
                              float* __restrict__ gates, int M)
{
    int node = blockIdx.x * 4 + (threadIdx.x >> 6);
    int lane = threadIdx.x & 63;
    if (node >= M) return;
    const float* row = hr + (size_t)node * 256;
    float a0 = 0, a1 = 0, a2 = 0, a3 = 0;
#pragma unroll
    for (int i = 0; i < 4; i++) {
        int k = lane + i * 64;
        float xv = row[k];
        float4 wv = *(const float4*)(rW + k * 4);
        a0 = fmaf(xv, wv.x, a0); a1 = fmaf(xv, wv.y, a1);
        a2 = fmaf(xv, wv.z, a2); a3 = fmaf(xv, wv.w, a3);
    }
#pragma unroll
    for (int off = 32; off; off >>= 1) {
        a0 += __shfl_xor(a0, off); a1 += __shfl_xor(a1, off);
        a2 += __shfl_xor(a2, off); a3 += __shfl_xor(a3, off);
    }
    if (lane == 0) {
        float l[4] = {a0 * (1.f / 1.5f), a1 * (1.f / 1.5f), a2 * (1.f / 1.5f), a3 * (1.f / 1.5f)};
        float mx = fmaxf(fmaxf(l[0], l[1]), fmaxf(l[2], l[3]));
        float e[4], ssum = 0.f;
#pragma unroll
        for (int i = 0; i < 4; i++) { e[i] = expf(l[i] - mx); ssum += e[i]; }
        float p[4];
#pragma unroll
        for (int i = 0; i < 4; i++) p[i] = e[i] / ssum;
        int i0 = 0;
        for (int i = 1; i < 4; i++) if (p[i] > p[i0]) i0 = i;
        int i1 = -1;
        for (int i = 0; i < 4; i++) {
            if (i == i0) continue;
            if (i1 < 0 || p[i] > p[i1]) i1 = i;
        }
        float wsum = fmaxf(p[i0] + p[i1], 1e-9f);
        float gg[4] = {0.f, 0.f, 0.f, 0.f};
        gg[i0] = p[i0] / wsum;
        gg[i1] = p[i1] / wsum;
        *(float4*)(gates + (size_t)node * 4) = make_float4(gg[0], gg[1], gg[2], gg[3]);
    }
}

// ---------- graph structure ----------
__global__ void edge_deg_kernel(const int* __restrict__ dst, int* __restrict__ degi, int E) {
    int e = blockIdx.x * blockDim.x + threadIdx.x;
    if (e < E) atomicAdd(&degi[dst[e]], 1);
}
__global__ void csr_fill_kernel(const int* __restrict__ src, const int* __restrict__ dst,
                                const int* __restrict__ rowptr, int* __restrict__ cursor,
                                int* __restrict__ csr, int E) {
    int e = blockIdx.x * blockDim.x + threadIdx.x;
    if (e >= E) return;
    int d = dst[e];
    int pos = atomicAdd(&cursor[d], 1);
    csr[rowptr[d] + pos] = src[e];
}
__global__ void dinv_kernel(const int* __restrict__ degi, float* __restrict__ dinv,
                            float* __restrict__ dinvl, int N) {
    int n = blockIdx.x * blockDim.x + threadIdx.x;
    if (n >= N) return;
    float deg = (float)degi[n];
    dinv[n] = (deg > 0.f) ? rsqrtf(fmaxf(deg, 1.f)) : 0.f;
    dinvl[n] = rsqrtf(deg + 1.f);
}

// ---------- single gather (bf16 in, fp32 out) ----------
__global__ void gather_kernel(const ushort_t* __restrict__ Xb, float* __restrict__ Out,
                              const int* __restrict__ rowptr, const int* __restrict__ csr,
                              const float* __restrict__ dv, int self_loop, float scale,
                              const float* __restrict__ bias, int relu, int M)
{
    int node = blockIdx.x * 4 + (threadIdx.x >> 6);
    int lane = threadIdx.x & 63;
    if (node >= M) return;
    int beg = rowptr[node], end = rowptr[node + 1];
    float dn = dv[node];
    float ax = 0.f, ay = 0.f;
    int e = beg;
    for (; e + 3 < end; e += 4) {
        int s0 = csr[e], s1 = csr[e + 1], s2 = csr[e + 2], s3 = csr[e + 3];
        float c0 = dn * dv[s0], c1 = dn * dv[s1], c2 = dn * dv[s2], c3 = dn * dv[s3];
        unsigned int u0 = *(const unsigned int*)(Xb + (size_t)s0 * 128 + lane * 2);
        unsigned int u1 = *(const unsigned int*)(Xb + (size_t)s1 * 128 + lane * 2);
        unsigned int u2 = *(const unsigned int*)(Xb + (size_t)s2 * 128 + lane * 2);
        unsigned int u3 = *(const unsigned int*)(Xb + (size_t)s3 * 128 + lane * 2);
        ax = fmaf(c0, bf2f(u0 & 0xffff), fmaf(c1, bf2f(u1 & 0xffff),
             fmaf(c2, bf2f(u2 & 0xffff), fmaf(c3, bf2f(u3 & 0xffff), ax))));
        ay = fmaf(c0, bf2f(u0 >> 16), fmaf(c1, bf2f(u1 >> 16),
             fmaf(c2, bf2f(u2 >> 16), fmaf(c3, bf2f(u3 >> 16), ay))));
    }
    for (; e < end; e++) {
        int s = csr[e];
        float c = dn * dv[s];
        unsigned int u = *(const unsigned int*)(Xb + (size_t)s * 128 + lane * 2);
        ax = fmaf(c, bf2f(u & 0xffff), ax);
        ay = fmaf(c, bf2f(u >> 16), ay);
    }
    if (self_loop) {
        float c = dn * dn;
        unsigned int u = *(const unsigned int*)(Xb + (size_t)node * 128 + lane * 2);
        ax = fmaf(c, bf2f(u & 0xffff), ax);
        ay = fmaf(c, bf2f(u >> 16), ay);
    }
    ax *= scale; ay *= scale;
    if (bias) { ax += bias[lane * 2]; ay += bias[lane * 2 + 1]; }
    if (relu) { ax = fmaxf(ax, 0.f); ay = fmaxf(ay, 0.f); }
    *(float2*)(Out + (size_t)node * 128 + lane * 2) = make_float2(ax, ay);
}

// ---------- fused dual gather: OutA = -aprop_dinv(X); OutB = aprop_dinvl(X) + X*dinvl^2 ----------
__global__ void gather2_kernel(const ushort_t* __restrict__ Xb,
                               float* __restrict__ OutA, float* __restrict__ OutB,
                               const int* __restrict__ rowptr, const int* __restrict__ csr,
                               const float* __restrict__ dinv, const float* __restrict__ dinvl,
                               int M)
{
    int node = blockIdx.x * 4 + (threadIdx.x >> 6);
    int lane = threadIdx.x & 63;
    if (node >= M) return;
    int beg = rowptr[node], end = rowptr[node + 1];
    float dn = dinv[node], dnl = dinvl[node];
    float axA = 0.f, ayA = 0.f, axB = 0.f, ayB = 0.f;
    int e = beg;
    for (; e + 1 < end; e += 2) {
        int s0 = csr[e], s1 = csr[e + 1];
        float c0 = dn * dinv[s0], c1 = dn * dinv[s1];
        float l0 = dnl * dinvl[s0], l1 = dnl * dinvl[s1];
        unsigned int u0 = *(const unsigned int*)(Xb + (size_t)s0 * 128 + lane * 2);
        unsigned int u1 = *(const unsigned int*)(Xb + (size_t)s1 * 128 + lane * 2);
        float x00 = bf2f(u0 & 0xffff), x01 = bf2f(u0 >> 16);
        float x10 = bf2f(u1 & 0xffff), x11 = bf2f(u1 >> 16);
        axA = fmaf(c0, x00, fmaf(c1, x10, axA));
        ayA = fmaf(c0, x01, fmaf(c1, x11, ayA));
        axB = fmaf(l0, x00, fmaf(l1, x10, axB));
        ayB = fmaf(l0, x01, fmaf(l1, x11, ayB));
    }
    for (; e < end; e++) {
        int s = csr[e];
        float c = dn * dinv[s], l = dnl * dinvl[s];
        unsigned int u = *(const unsigned int*)(Xb + (size_t)s * 128 + lane * 2);
        float x0 = bf2f(u & 0xffff), x1 = bf2f(u >> 16);
        axA = fmaf(c, x0, axA); ayA = fmaf(c, x1, ayA);
        axB = fmaf(l, x0, axB); ayB = fmaf(l, x1, ayB);
    }
    {   // GCN self-loop term
        float c = dnl * dnl;
        unsigned int u = *(const unsigned int*)(Xb + (size_t)node * 128 + lane * 2);
        axB = fmaf(c, bf2f(u & 0xffff), axB);
        ayB = fmaf(c, bf2f(u >> 16), ayB);
    }
    size_t ofs = (size_t)node * 128 + lane * 2;
    *(float2*)(OutA + ofs) = make_float2(-axA, -ayA);
    *(float2*)(OutB + ofs) = make_float2(axB, ayB);
}

// ---------- attention: no-max softmax, unroll 4 ----------
__global__ void gt_attn_kernel(const float* __restrict__ Q, const ushort_t* __restrict__ Kb,
                               const ushort_t* __restrict__ Vb, const int* __restrict__ rowptr,
                               const int* __restrict__ csr, float* __restrict__ Out, int M)
{
    const float SCL = 0.17677669529663689f * 1.4426950408889634f;
    int node = blockIdx.x * 4 + (threadIdx.x >> 6);
    int lane = threadIdx.x & 63;
    if (node >= M) return;
    int beg = rowptr[node], end = rowptr[node + 1];
    float2 q = *(const float2*)(Q + (size_t)node * 128 + lane * 2);
    q.x *= SCL; q.y *= SCL;
    float den = 0.f, ax = 0.f, ay = 0.f;
    int e = beg;
    for (; e + 3 < end; e += 4) {
        int s0 = csr[e], s1 = csr[e + 1], s2 = csr[e + 2], s3 = csr[e + 3];
        unsigned int k0 = *(const unsigned int*)(Kb + (size_t)s0 * 128 + lane * 2);
        unsigned int k1 = *(const unsigned int*)(Kb + (size_t)s1 * 128 + lane * 2);
        unsigned int k2 = *(const unsigned int*)(Kb + (size_t)s2 * 128 + lane * 2);
        unsigned int k3 = *(const unsigned int*)(Kb + (size_t)s3 * 128 + lane * 2);
        unsigned int v0 = *(const unsigned int*)(Vb + (size_t)s0 * 128 + lane * 2);
        unsigned int v1 = *(const unsigned int*)(Vb + (size_t)s1 * 128 + lane * 2);
        unsigned int v2 = *(const unsigned int*)(Vb + (size_t)s2 * 128 + lane * 2);
        unsigned int v3 = *(const unsigned int*)(Vb + (size_t)s3 * 128 + lane * 2);
        float p0 = q.x * bf2f(k0 & 0xffff) + q.y * bf2f(k0 >> 16);
        float p1 = q.x * bf2f(k1 & 0xffff) + q.y * bf2f(k1 >> 16);
        float p2 = q.x * bf2f(k2 & 0xffff) + q.y * bf2f(k2 >> 16);
        float p3 = q.x * bf2f(k3 & 0xffff) + q.y * bf2f(k3 >> 16);
#pragma unroll
        for (int off = 1; off <= 8; off <<= 1) {
            p0 += __shfl_xor(p0, off); p1 += __shfl_xor(p1, off);
            p2 += __shfl_xor(p2, off); p3 += __shfl_xor(p3, off);
        }
        float w0 = exp2f(fminf(p0, 80.f));
        float w1 = exp2f(fminf(p1, 80.f));
        float w2 = exp2f(fminf(p2, 80.f));
        float w3 = exp2f(fminf(p3, 80.f));
        den += (w0 + w1) + (w2 + w3);
        ax = fmaf(w0, bf2f(v0 & 0xffff), fmaf(w1, bf2f(v1 & 0xffff),
             fmaf(w2, bf2f(v2 & 0xffff), fmaf(w3, bf2f(v3 & 0xffff), ax))));
        ay = fmaf(w0, bf2f(v0 >> 16), fmaf(w1, bf2f(v1 >> 16),
             fmaf(w2, bf2f(v2 >> 16), fmaf(w3, bf2f(v3 >> 16), ay))));
    }
    for (; e < end; e++) {
        int s = csr[e];
        unsigned int ku = *(const unsigned int*)(Kb + (size_t)s * 128 + lane * 2);
        unsigned int vu = *(const unsigned int*)(Vb + (size_t)s * 128 + lane * 2);
        float p = q.x * bf2f(ku & 0xffff) + q.y * bf2f(ku >> 16);
#pragma unroll
        for (int off = 1; off <= 8; off <<= 1) p += __shfl_xor(p, off);
        float w = exp2f(fminf(p, 80.f));
        den += w;
        ax = fmaf(w, bf2f(vu & 0xffff), ax);
        ay = fmaf(w, bf2f(vu >> 16), ay);
    }
    float d = fmaxf(den, 1e-9f);
    *(float2*)(Out + (size_t)node * 128 + lane * 2) = make_float2(ax / d, ay / d);
}

// ---------- fused: out = h + sum_e gates[e] * (LN(e_i)*scale_e) ----------
__global__ void combine4_kernel(const float* __restrict__ h,
                                const float* __restrict__ e0, const float* __restrict__ e1,
                                const float* __restrict__ e2, const float* __restrict__ e3,
                                const float* __restrict__ gates,
                                const float* __restrict__ png, const float* __restrict__ pnb,
                                const float* __restrict__ esc,
                                float* __restrict__ Out, int M)
{
    int node = blockIdx.x * 4 + (threadIdx.x >> 6);
    int lane = threadIdx.x & 63;
    if (node >= M) return;
    size_t ofs = (size_t)node * 128 + lane * 2;
    const float* ep[4] = {e0 + ofs, e1 + ofs, e2 + ofs, e3 + ofs};
    float4 gg = *(const float4*)(gates + (size_t)node * 4);
    float gv[4] = {gg.x, gg.y, gg.z, gg.w};
    float2 hv = *(const float2*)(h + ofs);
    float ox = hv.x, oy = hv.y;
#pragma unroll
    for (int e = 0; e < 4; e++) {
        float2 v = *(const float2*)ep[e];
        float s = v.x + v.y, sq = v.x * v.x + v.y * v.y;
#pragma unroll
        for (int off = 32; off; off >>= 1) { s += __shfl_xor(s, off); sq += __shfl_xor(sq, off); }
        float mean = s * (1.f / 128.f);
        float var = sq * (1.f / 128.f) - mean * mean;
        float inv = rsqrtf(var + 1e-5f);
        float g0 = png[e * 128 + lane * 2], g1 = png[e * 128 + lane * 2 + 1];
        float b0 = pnb[e * 128 + lane * 2], b1 = pnb[e * 128 + lane * 2 + 1];
        float c = esc[e] * gv[e];
        ox = fmaf(c, (v.x - mean) * inv * g0 + b0, ox);
        oy = fmaf(c, (v.y - mean) * inv * g1 + b1, oy);
    }
    *(float2*)(Out + ofs) = make_float2(ox, oy);
}

// ---------- two-phase segmented mean-pool ----------
__global__ void pool_partial_kernel(const float* __restrict__ Out,
                                    const int* __restrict__ bstart, const int* __restrict__ bend,
                                    float* __restrict__ partial)
{
    int b = blockIdx.x, c = blockIdx.y, t = threadIdx.x;
    int s = bstart[b], e = bend[b];
    float sum = 0.f;
    for (int n = s + c; n < e; n += PCH) sum += Out[(size_t)n * 128 + t];
    partial[((size_t)b * PCH + c) * 128 + t] = sum;
}
__global__ void pool_reduce_kernel(const float* __restrict__ partial,
                                   const int* __restrict__ bstart, const int* __restrict__ bend,
                                   float* __restrict__ pooled)
{
    int b = blockIdx.x, t = threadIdx.x;
    float sum = 0.f;
#pragma unroll
    for (int c = 0; c < PCH; c++) sum += partial[((size_t)b * PCH + c) * 128 + t];
    float cnt = fmaxf((float)(bend[b] - bstart[b]), 1.f);
    pooled[(size_t)b * 128 + t] = sum / cnt;
}

// ---------- classification head (fp32 out) ----------
__global__ void head_kernel(const float* __restrict__ pooled,
                            const float* __restrict__ h1W, const float* __restrict__ h1b,
                            const float* __restrict__ h1g, const float* __restrict__ h1be,
                            const float* __restrict__ h2W, const float* __restrict__ h2b,
                            const float* __restrict__ h2g, const float* __restrict__ h2be,
                            const float* __restrict__ h3W, const float* __restrict__ h3b,
                            const float* __restrict__ lbias,
                            float* __restrict__ out, int B)
{
    __shared__ float p[128], z[128];
    int b = blockIdx.x, t = threadIdx.x;
    p[t] = pooled[(size_t)b * 128 + t];
    __syncthreads();
    float a = h1b[t];
    for (int k = 0; k < 128; k++) a = fmaf(p[k], h1W[k * 128 + t], a);
    z[t] = a;
    __syncthreads();
    float s = 0.f, sq = 0.f;
    for (int k = 0; k < 128; k++) { float x = z[k]; s += x; sq += x * x; }
    float mean = s * (1.f / 128.f), var = sq * (1.f / 128.f) - mean * mean;
    float y = fmaxf((a - mean) * rsqrtf(var + 1e-5f) * h1g[t] + h1be[t], 0.f);
    __syncthreads();
    z[t] = y;
    __syncthreads();
    float a2 = 0.f;
    if (t < 64) {
        a2 = h2b[t];
        for (int k = 0; k < 128; k++) a2 = fmaf(z[k], h2W[k * 64 + t], a2);
    }
    __syncthreads();
    if (t < 64) p[t] = a2;
    __syncthreads();
    if (t < 2) {
        float s2 = 0.f, sq2 = 0.f;
        for (int k = 0; k < 64; k++) { float x = p[k]; s2 += x; sq2 += x * x; }
        float mean2 = s2 * (1.f / 64.f), var2 = sq2 * (1.f / 64.f) - mean2 * mean2;
        float inv2 = rsqrtf(var2 + 1e-5f);
        float o = h3b[t] + lbias[t];
        for (int k = 0; k < 64; k++) {
            float zc = fmaxf((p[k] - mean2) * inv2 * h2g[k] + h2be[k], 0.f);
            o = fmaf(zc, h3W[k * 2 + t], o);
        }
        out[b * 2 + t] = o;
    }
}

// ---------------- launch ----------------
extern "C" void kernel_launch(void* const* d_in, const int* in_sizes, int n_in,
                              void* d_out, int out_size, void* d_ws, size_t ws_size,
                              hipStream_t stream)
{
    (void)ws_size; (void)n_in;
    const int N = in_sizes[3];
    const int E = in_sizes[2] / 2;
    const int B = out_size / 2;

    const int* ei = (const int*)d_in[2];
    const int* src = ei;
    const int* dst = ei + E;
    const int* batch = (const int*)d_in[3];

    const float* W[47];
    for (int i = 0; i < 47; i++) W[i] = (const float*)d_in[i];

    size_t fN = (size_t)N;
    float* hr    = (float*)d_ws;        // 256N: bufA/bufB after router
    float* h     = hr + 256 * fN;
    float* e0    = h + 128 * fN;
    float* e1    = e0 + 128 * fN;
    float* e2    = e1 + 128 * fN;
    float* e3    = e2 + 128 * fN;
    float* tmp0  = e3 + 128 * fN;
    float* tmp1  = tmp0 + 128 * fN;
    float* gates = tmp1 + 128 * fN;
    float* dinv  = gates + 4 * fN;
    float* dinvl = dinv + fN;
    float* pooled = dinvl + fN;                              // 128*B
    float* partial = pooled + (size_t)128 * B;               // 128*B*PCH
    ushort_t* hb  = (ushort_t*)(partial + (size_t)128 * B * PCH);
    ushort_t* bf0 = hb + 128 * fN;
    ushort_t* bf1 = bf0 + 128 * fN;
    ushort_t* wt  = bf1 + 128 * fN;                          // transposed weights
    WtPack wp;
    const float* wsrc[NWT] = {
        W[4], W[8], W[12], W[17], W[19],
        W[21], W[21] + 16384, W[21] + 32768, W[21] + 49152,
        W[23], W[23] + 16384, W[25], W[25] + 16384,
        W[27], W[27] + 16384, W[29], W[29] + 16384,
        W[31], W[31] + 16384
    };
    const int wk[NWT] = {200, 128, 256, 128, 128,
                         128, 128, 128, 128,
                         128, 128, 128, 128,
                         128, 128, 128, 128,
                         128, 128};
    unsigned long long woff[NWT];
    unsigned long long acc_off = 0;
    for (int i = 0; i < NWT; i++) {
        wp.src[i] = wsrc[i];
        wp.K[i] = wk[i];
        wp.off[i] = acc_off;
        woff[i] = acc_off;
        acc_off += (unsigned long long)128 * wk[i];
    }
    int* degi   = (int*)(wt + acc_off + 8);
    int* cursor = degi + N;
    int* rowptr = cursor + N;
    int* csr    = rowptr + (N + 1);
    int* bstart = csr + E;
    int* bend   = bstart + B;
    int* bsum   = bend + B;   // scan block sums (<=256)
    float* bufA = hr;
    float* bufB = hr + 128 * fN;
    float* outb = tmp0;

    dim3 blk(256);
    int gN4 = (N + 3) / 4;
    dim3 gG((N + 63) / 64);
    int nsb = (N + SCH - 1) / SCH;
    ushort_t* NOB = (ushort_t*)0;

    // weight transpose+convert, graph structure
    wconv_kernel<<<dim3(32, NWT), blk, 0, stream>>>(wp, wt);
    zero_i32_kernel<<<(2 * N + 255) / 256, blk, 0, stream>>>(degi, 2 * N);
    zero_i32_kernel<<<1, blk, 0, stream>>>(bstart, 2 * B);
    seg_bounds_kernel<<<(N + 255) / 256, blk, 0, stream>>>(batch, bstart, bend, N);
    edge_deg_kernel<<<(E + 255) / 256, blk, 0, stream>>>(dst, degi, E);
    scan1_kernel<<<dim3(nsb), blk, 0, stream>>>(degi, rowptr, bsum, N);
    scan2_kernel<<<1, blk, 0, stream>>>(bsum, nsb);
    scan3_kernel<<<(N + 255) / 256, blk, 0, stream>>>(rowptr, bsum, N);
    csr_fill_kernel<<<(E + 255) / 256, blk, 0, stream>>>(src, dst, rowptr, cursor, csr, E);
    dinv_kernel<<<(N + 255) / 256, blk, 0, stream>>>(degi, dinv, dinvl, N);

    // encoders + fuse + router
    gemm_kernel<<<gG, blk, 0, stream>>>(W[0], 200, wt + woff[0], hr, 256, N, 200, W[5], 0, NOB);
    gemm_kernel<<<gG, blk, 0, stream>>>(W[1], 128, wt + woff[1], hr + 128, 256, N, 128, W[9], 0, NOB);
    ln_relu_kernel<<<gN4, blk, 0, stream>>>(hr, 256, W[6], W[7], N, NOB);
    ln_relu_kernel<<<gN4, blk, 0, stream>>>(hr + 128, 256, W[10], W[11], N, NOB);
    router_kernel<<<gN4, blk, 0, stream>>>(hr, W[16], gates, N);
    gemm_kernel<<<gG, blk, 0, stream>>>(hr, 256, wt + woff[2], h, 128, N, 256, W[13], 0, NOB);
    ln_relu_kernel<<<gN4, blk, 0, stream>>>(h, 128, W[14], W[15], N, hb);

    // expert 0: MLP (bufA free after fuse)
    gemm_kernel<<<gG, blk, 0, stream>>>(h, 128, wt + woff[3], bufA, 128, N, 128, W[18], RELUF, NOB);
    gemm_kernel<<<gG, blk, 0, stream>>>(bufA, 128, wt + woff[4], e0, 128, N, 128, W[20], 0, NOB);

    // fused layer-1 gather: bufA = -aprop_dinv(h) [Cheb]; tmp1 = aprop_dinvl_self(h) [GCN]
    gather2_kernel<<<gN4, blk, 0, stream>>>(hb, bufA, tmp1, rowptr, csr, dinv, dinvl, N);

    // expert 1: ChebNet K=2
    gemm_kernel<<<gG, blk, 0, stream>>>(h, 128, wt + woff[5], bufB, 128, N, 128, W[22], 0, NOB);
    gemm_kernel<<<gG, blk, 0, stream>>>(bufA, 128, wt + woff[6], bufB, 128, N, 128, (const float*)0, ACCF | RELUF, bf0);
    gather_kernel<<<gN4, blk, 0, stream>>>(bf0, bufA, rowptr, csr, dinv, 0, -1.f, (const float*)0, 0, N);
    gemm_kernel<<<gG, blk, 0, stream>>>(bufB, 128, wt + woff[7], e1, 128, N, 128, W[22] + 128, 0, NOB);
    gemm_kernel<<<gG, blk, 0, stream>>>(bufA, 128, wt + woff[8], e1, 128, N, 128, (const float*)0, ACCF, NOB);

    // expert 3: GCN (gather-then-GEMM via linearity)
    gemm_kernel<<<gG, blk, 0, stream>>>(tmp1, 128, wt + woff[17], bufA, 128, N, 128, W[32], RELUF, bf0);
    gather_kernel<<<gN4, blk, 0, stream>>>(bf0, tmp1, rowptr, csr, dinvl, 1, 1.f, (const float*)0, 0, N);
    gemm_kernel<<<gG, blk, 0, stream>>>(tmp1, 128, wt + woff[18], e3, 128, N, 128, W[32] + 128, 0, NOB);

    // expert 2: Graph Transformer (2 layers)
    gemm_kernel<<<gG, blk, 0, stream>>>(h, 128, wt + woff[9], bufA, 128, N, 128, W[24], 0, NOB);   // q
    gemm_kernel<<<gG, blk, 0, stream>>>(h, 128, wt + woff[11], bufB, 128, N, 128, W[26], 0, bf0);  // k
    gemm_kernel<<<gG, blk, 0, stream>>>(h, 128, wt + woff[13], tmp0, 128, N, 128, W[28], 0, bf1);  // v
    gt_attn_kernel<<<gN4, blk, 0, stream>>>(bufA, bf0, bf1, rowptr, csr, tmp1, N);
    gemm_kernel<<<gG, blk, 0, stream>>>(h, 128, wt + woff[15], tmp1, 128, N, 128, W[30], ACCF | RELUF, NOB);
    gemm_kernel<<<gG, blk, 0, stream>>>(tmp1, 128, wt + woff[10], bufA, 128, N, 128, W[24] + 128, 0, NOB);
    gemm_kernel<<<gG, blk, 0, stream>>>(tmp1, 128, wt + woff[12], bufB, 128, N, 128, W[26] + 128, 0, bf0);
    gemm_kernel<<<gG, blk, 0, stream>>>(tmp1, 128, wt + woff[14], tmp0, 128, N, 128, W[28] + 128, 0, bf1);
    gt_attn_kernel<<<gN4, blk, 0, stream>>>(bufA, bf0, bf1, rowptr, csr, e2, N);
    gemm_kernel<<<gG, blk, 0, stream>>>(tmp1, 128, wt + woff[16], e2, 128, N, 128, W[30] + 128, ACCF, NOB);

    // fused combine + two-phase pool + head
    combine4_kernel<<<gN4, blk, 0, stream>>>(h, e0, e1, e2, e3, gates,
                                             W[33], W[34], W[35], outb, N);
    pool_partial_kernel<<<dim3(B, PCH), dim3(128), 0, stream>>>(outb, bstart, bend, partial);
    pool_reduce_kernel<<<dim3(B), dim3(128), 0, stream>>>(partial, bstart, bend, pooled);
    head_kernel<<<dim3(B), dim3(128), 0, stream>>>(pooled,
        W[36], W[37], W[38], W[39],
        W[40], W[41], W[42], W[43],
        W[44], W[45], W[46],
        (float*)d_out, B);
}

// Round 10
// 699.003 us; speedup vs baseline: 2.2144x; 1.0235x over previous
//
#include <hip/hip_runtime.h>

#define RELUF 1
#define ACCF  2
#define PCH   16    // pool chunks per graph
#define NWT   19    // transposed weight matrices
#define SCH   2048  // elements per scan block

typedef unsigned short ushort_t;
typedef __attribute__((ext_vector_type(8))) short bf16x8;
typedef __attribute__((ext_vector_type(4))) float f32x4;

__device__ __forceinline__ float bf2f(unsigned int v) {
    return __uint_as_float(v << 16);
}
__device__ __forceinline__ unsigned int f2bu(float f) {
    unsigned int u = __float_as_uint(f);
    return (u + 0x7fffu + ((u >> 16) & 1u)) >> 16;
}

// ---------------- utility kernels ----------------
__global__ void zero_i32_kernel(int* __restrict__ p, int n) {
    int i = blockIdx.x * blockDim.x + threadIdx.x;
    if (i < n) p[i] = 0;
}
__global__ void seg_bounds_kernel(const int* __restrict__ batch, int* __restrict__ bstart,
                                  int* __restrict__ bend, int N) {
    int n = blockIdx.x * blockDim.x + threadIdx.x;
    if (n >= N) return;
    int b = batch[n];
    if (n == 0) bstart[b] = 0;
    else {
        int pb = batch[n - 1];
        if (pb != b) { bstart[b] = n; bend[pb] = n; }
    }
    if (n == N - 1) bend[b] = N;
}

// ---------- parallel 3-phase exclusive scan ----------
__global__ void scan1_kernel(const int* __restrict__ degi, int* __restrict__ rowptr,
                             int* __restrict__ bsum, int n) {
    __shared__ int sh[256];
    int tid = threadIdx.x;
    int base = blockIdx.x * SCH + tid * 8;
    int loc[8]; int s = 0;
#pragma unroll
    for (int j = 0; j < 8; j++) {
        int idx = base + j;
        int v = (idx < n) ? degi[idx] : 0;
        s += v; loc[j] = s;
    }
    sh[tid] = s;
    __syncthreads();
    for (int off = 1; off < 256; off <<= 1) {
        int t = (tid >= off) ? sh[tid - off] : 0;
        __syncthreads();
        sh[tid] += t;
        __syncthreads();
    }
    int prev = (tid > 0) ? sh[tid - 1] : 0;
#pragma unroll
    for (int j = 0; j < 8; j++) {
        int idx = base + j;
        if (idx < n) rowptr[idx + 1] = prev + loc[j];
    }
    if (tid == 255) bsum[blockIdx.x] = sh[255];
}
__global__ void scan2_kernel(int* __restrict__ bsum, int nb) {
    __shared__ int sh[256];
    int tid = threadIdx.x;
    sh[tid] = (tid < nb) ? bsum[tid] : 0;
    __syncthreads();
    for (int off = 1; off < 256; off <<= 1) {
        int t = (tid >= off) ? sh[tid - off] : 0;
        __syncthreads();
        sh[tid] += t;
        __syncthreads();
    }
    if (tid < nb) bsum[tid] = (tid > 0) ? sh[tid - 1] : 0;
}
__global__ void scan3_kernel(int* __restrict__ rowptr, const int* __restrict__ bsum, int n) {
    int i = blockIdx.x * blockDim.x + threadIdx.x;
    if (i == 0) rowptr[0] = 0;
    if (i < n) rowptr[i + 1] += bsum[i / SCH];
}

// ---------- batched W transpose+convert ----------
struct WtPack {
    const float* src[NWT];
    unsigned long long off[NWT];
    int K[NWT];
};
__global__ void wconv_kernel(WtPack p, ushort_t* __restrict__ base) {
    int a = blockIdx.y;
    const float* s = p.src[a];
    ushort_t* d = base + p.off[a];
    int K = p.K[a];
    int total = K * 128;
    for (int i = blockIdx.x * blockDim.x + threadIdx.x; i < total; i += gridDim.x * blockDim.x) {
        int k = i >> 7, n = i & 127;
        d[n * K + k] = (ushort_t)f2bu(s[i]);
    }
}

// ---------- MFMA GEMM (single) ----------
__global__ __launch_bounds__(256)
void gemm_kernel(const float* __restrict__ A, int lda,
                 const ushort_t* __restrict__ Wt,
                 float* __restrict__ C, int ldc,
                 int M, int K,
                 const float* __restrict__ bias, int flags,
                 ushort_t* __restrict__ Cb)
{
    __shared__ ushort_t As[64][40];
    __shared__ ushort_t Bs[128][40];
    const int tid = threadIdx.x;
    const int m0 = blockIdx.x * 64;
    const int lane = tid & 63;
    const int wv = tid >> 6;
    const int q = lane >> 4;
    const int l16 = lane & 15;
    const int sar = tid >> 2;
    const int sak = (tid & 3) << 3;
    const int sbn = tid >> 1;
    const int sbk = (tid & 1) << 4;
    const bool arow_ok = (m0 + sar) < M;
    const float* Arow = A + (size_t)(m0 + sar) * lda;
    const ushort_t* Wrow = Wt + (size_t)sbn * K;

    f32x4 acc[8];
#pragma unroll
    for (int t = 0; t < 8; t++) acc[t] = (f32x4){0.f, 0.f, 0.f, 0.f};

    for (int k0 = 0; k0 < K; k0 += 32) {
        uint4 apk;
        if (arow_ok && k0 + sak + 8 <= K) {
            float4 p0 = *(const float4*)(Arow + k0 + sak);
            float4 p1 = *(const float4*)(Arow + k0 + sak + 4);
            apk.x = f2bu(p0.x) | (f2bu(p0.y) << 16);
            apk.y = f2bu(p0.z) | (f2bu(p0.w) << 16);
            apk.z = f2bu(p1.x) | (f2bu(p1.y) << 16);
            apk.w = f2bu(p1.z) | (f2bu(p1.w) << 16);
        } else {
            unsigned int t4[4] = {0, 0, 0, 0};
            for (int j = 0; j < 8; j++) {
                int k = k0 + sak + j;
                unsigned int bv = (arow_ok && k < K) ? f2bu(Arow[k]) : 0u;
                t4[j >> 1] |= bv << ((j & 1) * 16);
            }
            apk = make_uint4(t4[0], t4[1], t4[2], t4[3]);
        }
        uint4 b0, b1;
        if (k0 + sbk + 16 <= K) {
            b0 = *(const uint4*)(Wrow + k0 + sbk);
            b1 = *(const uint4*)(Wrow + k0 + sbk + 8);
        } else {
            unsigned int t8[8] = {0, 0, 0, 0, 0, 0, 0, 0};
            for (int j = 0; j < 16; j++) {
                int k = k0 + sbk + j;
                unsigned int bv = (k < K) ? (unsigned int)Wrow[k] : 0u;
                t8[j >> 1] |= bv << ((j & 1) * 16);
            }
            b0 = make_uint4(t8[0], t8[1], t8[2], t8[3]);
            b1 = make_uint4(t8[4], t8[5], t8[6], t8[7]);
        }
        __syncthreads();
        *(uint4*)&As[sar][sak] = apk;
        *(uint4*)&Bs[sbn][sbk] = b0;
        *(uint4*)&Bs[sbn][sbk + 8] = b1;
        __syncthreads();
        bf16x8 af = *(const bf16x8*)&As[16 * wv + l16][q * 8];
#pragma unroll
        for (int t = 0; t < 8; t++) {
            bf16x8 bf = *(const bf16x8*)&Bs[t * 16 + l16][q * 8];
            acc[t] = __builtin_amdgcn_mfma_f32_16x16x32_bf16(af, bf, acc[t], 0, 0, 0);
        }
    }
#pragma unroll
    for (int t = 0; t < 8; t++) {
        int col = t * 16 + l16;
        float bb = bias ? bias[col] : 0.f;
#pragma unroll
        for (int r = 0; r < 4; r++) {
            int row = m0 + 16 * wv + q * 4 + r;
            bool ok = row < M;
            float val = acc[t][r] + bb;
            float* cp = C + (size_t)row * ldc + col;
            if (flags & ACCF) { if (ok) val += *cp; }
            if (flags & RELUF) val = fmaxf(val, 0.f);
            if (ok) *cp = val;
            if (Cb) {
                float other = __shfl_xor(val, 1);
                if (!(lane & 1) && ok) {
                    unsigned int pk = f2bu(val) | (f2bu(other) << 16);
                    *(unsigned int*)(Cb + (size_t)row * 128 + col) = pk;
                }
            }
        }
    }
}

// ---------- MFMA dual GEMM: C = A1@W1 + A2@W2 (+bias)(+relu) ----------
__global__ __launch_bounds__(256)
void gemm_dual_kernel(const float* __restrict__ A1, const ushort_t* __restrict__ Wt1,
                      const float* __restrict__ A2, const ushort_t* __restrict__ Wt2,
                      float* __restrict__ C, int M, int K,
                      const float* __restrict__ bias, int flags,
                      ushort_t* __restrict__ Cb)
{
    __shared__ ushort_t As[64][40];
    __shared__ ushort_t Bs[128][40];
    const int tid = threadIdx.x;
    const int m0 = blockIdx.x * 64;
    const int lane = tid & 63;
    const int wv = tid >> 6;
    const int q = lane >> 4;
    const int l16 = lane & 15;
    const int sar = tid >> 2;
    const int sak = (tid & 3) << 3;
    const int sbn = tid >> 1;
    const int sbk = (tid & 1) << 4;
    const bool arow_ok = (m0 + sar) < M;

    f32x4 acc[8];
#pragma unroll
    for (int t = 0; t < 8; t++) acc[t] = (f32x4){0.f, 0.f, 0.f, 0.f};

    for (int ph = 0; ph < 2; ph++) {
        const float* Arow = (ph ? A2 : A1) + (size_t)(m0 + sar) * K;
        const ushort_t* Wrow = (ph ? Wt2 : Wt1) + (size_t)sbn * K;
        for (int k0 = 0; k0 < K; k0 += 32) {
            uint4 apk;
            if (arow_ok) {
                float4 p0 = *(const float4*)(Arow + k0 + sak);
                float4 p1 = *(const float4*)(Arow + k0 + sak + 4);
                apk.x = f2bu(p0.x) | (f2bu(p0.y) << 16);
                apk.y = f2bu(p0.z) | (f2bu(p0.w) << 16);
                apk.z = f2bu(p1.x) | (f2bu(p1.y) << 16);
                apk.w = f2bu(p1.z) | (f2bu(p1.w) << 16);
            } else {
                apk = make_uint4(0, 0, 0, 0);
            }
            uint4 b0 = *(const uint4*)(Wrow + k0 + sbk);
            uint4 b1 = *(const uint4*)(Wrow + k0 + sbk + 8);
            __syncthreads();
            *(uint4*)&As[sar][sak] = apk;
            *(uint4*)&Bs[sbn][sbk] = b0;
            *(uint4*)&Bs[sbn][sbk + 8] = b1;
            __syncthreads();
            bf16x8 af = *(const bf16x8*)&As[16 * wv + l16][q * 8];
#pragma unroll
            for (int t = 0; t < 8; t++) {
                bf16x8 bf = *(const bf16x8*)&Bs[t * 16 + l16][q * 8];
                acc[t] = __builtin_amdgcn_mfma_f32_16x16x32_bf16(af, bf, acc[t], 0, 0, 0);
            }
        }
    }
#pragma unroll
    for (int t = 0; t < 8; t++) {
        int col = t * 16 + l16;
        float bb = bias ? bias[col] : 0.f;
#pragma unroll
        for (int r = 0; r < 4; r++) {
            int row = m0 + 16 * wv + q * 4 + r;
            bool ok = row < M;
            float val = acc[t][r] + bb;
            if (flags & RELUF) val = fmaxf(val, 0.f);
            if (ok) C[(size_t)row * 128 + col] = val;
            if (Cb) {
                float other = __shfl_xor(val, 1);
                if (!(lane & 1) && ok) {
                    unsigned int pk = f2bu(val) | (f2bu(other) << 16);
                    *(unsigned int*)(Cb + (size_t)row * 128 + col) = pk;
                }
            }
        }
    }
}

// ---------- MFMA triple GEMM (QKV): Wt is [384][K]; C0 fp32 (q); kv bf16 shadow for k/v ----------
__global__ __launch_bounds__(256)
void gemm3_kernel(const float* __restrict__ A, int lda,
                  const ushort_t* __restrict__ Wt,
                  float* __restrict__ C0,
                  int M, int K,
                  const float* __restrict__ b0, const float* __restrict__ b1,
                  const float* __restrict__ b2,
                  ushort_t* __restrict__ kv)
{
    __shared__ ushort_t As[64][40];
    __shared__ ushort_t Bs[384][40];
    const int tid = threadIdx.x;
    const int m0 = blockIdx.x * 64;
    const int lane = tid & 63;
    const int wv = tid >> 6;
    const int q = lane >> 4;
    const int l16 = lane & 15;
    const int sar = tid >> 2;
    const int sak = (tid & 3) << 3;
    const bool arow_ok = (m0 + sar) < M;
    const float* Arow = A + (size_t)(m0 + sar) * lda;

    f32x4 acc[24];
#pragma unroll
    for (int t = 0; t < 24; t++) acc[t] = (f32x4){0.f, 0.f, 0.f, 0.f};

    for (int k0 = 0; k0 < K; k0 += 32) {
        uint4 apk;
        if (arow_ok) {
            float4 p0 = *(const float4*)(Arow + k0 + sak);
            float4 p1 = *(const float4*)(Arow + k0 + sak + 4);
            apk.x = f2bu(p0.x) | (f2bu(p0.y) << 16);
            apk.y = f2bu(p0.z) | (f2bu(p0.w) << 16);
            apk.z = f2bu(p1.x) | (f2bu(p1.y) << 16);
            apk.w = f2bu(p1.z) | (f2bu(p1.w) << 16);
        } else {
            apk = make_uint4(0, 0, 0, 0);
        }
        uint4 bv[3][2];
        int rows[3], kofs[3];
#pragma unroll
        for (int j = 0; j < 3; j++) {
            int slot = tid + j * 256;
            rows[j] = slot >> 1;
            kofs[j] = (slot & 1) << 4;
            const ushort_t* Wrow = Wt + (size_t)rows[j] * K + k0 + kofs[j];
            bv[j][0] = *(const uint4*)Wrow;
            bv[j][1] = *(const uint4*)(Wrow + 8);
        }
        __syncthreads();
        *(uint4*)&As[sar][sak] = apk;
#pragma unroll
        for (int j = 0; j < 3; j++) {
            *(uint4*)&Bs[rows[j]][kofs[j]] = bv[j][0];
            *(uint4*)&Bs[rows[j]][kofs[j] + 8] = bv[j][1];
        }
        __syncthreads();
        bf16x8 af = *(const bf16x8*)&As[16 * wv + l16][q * 8];
#pragma unroll
        for (int t = 0; t < 24; t++) {
            bf16x8 bf = *(const bf16x8*)&Bs[t * 16 + l16][q * 8];
            acc[t] = __builtin_amdgcn_mfma_f32_16x16x32_bf16(af, bf, acc[t], 0, 0, 0);
        }
    }
    const float* bs[3] = {b0, b1, b2};
#pragma unroll
    for (int s = 0; s < 3; s++) {
#pragma unroll
        for (int t8 = 0; t8 < 8; t8++) {
            int t = s * 8 + t8;
            int col = t8 * 16 + l16;
            float bb = bs[s] ? bs[s][col] : 0.f;
#pragma unroll
            for (int r = 0; r < 4; r++) {
                int row = m0 + 16 * wv + q * 4 + r;
                bool ok = row < M;
                float val = acc[t][r] + bb;
                if (s == 0) {
                    if (ok) C0[(size_t)row * 128 + col] = val;
                } else {
                    float other = __shfl_xor(val, 1);
                    if (!(lane & 1) && ok) {
                        unsigned int pk = f2bu(val) | (f2bu(other) << 16);
                        *(unsigned int*)(kv + (size_t)row * 256 + (s - 1) * 128 + col) = pk;
                    }
                }
            }
        }
    }
}

// ---------- LayerNorm(128) + ReLU in place (+ optional bf16 shadow) ----------
__global__ void ln_relu_kernel(float* __restrict__ X, int ld,
                               const float* __restrict__ g,
                               const float* __restrict__ b, int M,
                               ushort_t* __restrict__ Xb)
{
    int node = blockIdx.x * 4 + (threadIdx.x >> 6);
    int lane = threadIdx.x & 63;
    if (node >= M) return;
    float* row = X + (size_t)node * ld;
    float2 v = *(float2*)(row + lane * 2);
    float s = v.x + v.y, sq = v.x * v.x + v.y * v.y;
#pragma unroll
    for (int off = 32; off; off >>= 1) { s += __shfl_xor(s, off); sq += __shfl_xor(sq, off); }
    float mean = s * (1.f / 128.f);
    float var = sq * (1.f / 128.f) - mean * mean;
    float inv = rsqrtf(var + 1e-5f);
    float y0 = fmaxf((v.x - mean) * inv * g[lane * 2] + b[lane * 2], 0.f);
    float y1 = fmaxf((v.y - mean) * inv * g[lane * 2 + 1] + b[lane * 2 + 1], 0.f);
    *(float2*)(row + lane * 2) = make_float2(y0, y1);
    if (Xb) {
        unsigned int p = f2bu(y0) | (f2bu(y1) << 16);
        *(unsigned int*)(Xb + (size_t)node * 128 + lane * 2) = p;
    }
}

// ---------- router ----------
__global__ void router_kernel(const float* __restrict__ hr, const float* __restrict__ rW,
                              float* __restrict__ gates, int M)
{
    int node = blockIdx.x * 4 + (threadIdx.x >> 6);
    int lane = threadIdx.x & 63;
    if (node >= M) return;
    const float* row = hr + (size_t)node * 256;
    float a0 = 0, a1 = 0, a2 = 0, a3 = 0;
#pragma unroll
    for (int i = 0; i < 4; i++) {
        int k = lane + i * 64;
        float xv = row[k];
        float4 wv = *(const float4*)(rW + k * 4);
        a0 = fmaf(xv, wv.x, a0); a1 = fmaf(xv, wv.y, a1);
        a2 = fmaf(xv, wv.z, a2); a3 = fmaf(xv, wv.w, a3);
    }
#pragma unroll
    for (int off = 32; off; off >>= 1) {
        a0 += __shfl_xor(a0, off); a1 += __shfl_xor(a1, off);
        a2 += __shfl_xor(a2, off); a3 += __shfl_xor(a3, off);
    }
    if (lane == 0) {
        float l[4] = {a0 * (1.f / 1.5f), a1 * (1.f / 1.5f), a2 * (1.f / 1.5f), a3 * (1.f / 1.5f)};
        float mx = fmaxf(fmaxf(l[0], l[1]), fmaxf(l[2], l[3]));
        float e[4], ssum = 0.f;
#pragma unroll
        for (int i = 0; i < 4; i++) { e[i] = expf(l[i] - mx); ssum += e[i]; }
        float p[4];
#pragma unroll
        for (int i = 0; i < 4; i++) p[i] = e[i] / ssum;
        int i0 = 0;
        for (int i = 1; i < 4; i++) if (p[i] > p[i0]) i0 = i;
        int i1 = -1;
        for (int i = 0; i < 4; i++) {
            if (i == i0) continue;
            if (i1 < 0 || p[i] > p[i1]) i1 = i;
        }
        float wsum = fmaxf(p[i0] + p[i1], 1e-9f);
        float gg[4] = {0.f, 0.f, 0.f, 0.f};
        gg[i0] = p[i0] / wsum;
        gg[i1] = p[i1] / wsum;
        *(float4*)(gates + (size_t)node * 4) = make_float4(gg[0], gg[1], gg[2], gg[3]);
    }
}

// ---------- graph structure ----------
__global__ void edge_deg_kernel(const int* __restrict__ dst, int* __restrict__ degi, int E) {
    int e = blockIdx.x * blockDim.x + threadIdx.x;
    if (e < E) atomicAdd(&degi[dst[e]], 1);
}
__global__ void csr_fill_kernel(const int* __restrict__ src, const int* __restrict__ dst,
                                const int* __restrict__ rowptr, int* __restrict__ cursor,
                                int* __restrict__ csr, int E) {
    int e = blockIdx.x * blockDim.x + threadIdx.x;
    if (e >= E) return;
    int d = dst[e];
    int pos = atomicAdd(&cursor[d], 1);
    csr[rowptr[d] + pos] = src[e];
}
__global__ void dinv_kernel(const int* __restrict__ degi, float* __restrict__ dinv,
                            float* __restrict__ dinvl, int N) {
    int n = blockIdx.x * blockDim.x + threadIdx.x;
    if (n >= N) return;
    float deg = (float)degi[n];
    dinv[n] = (deg > 0.f) ? rsqrtf(fmaxf(deg, 1.f)) : 0.f;
    dinvl[n] = rsqrtf(deg + 1.f);
}

// ---------- single gather (bf16 in, fp32 out) ----------
__global__ void gather_kernel(const ushort_t* __restrict__ Xb, float* __restrict__ Out,
                              const int* __restrict__ rowptr, const int* __restrict__ csr,
                              const float* __restrict__ dv, int self_loop, float scale,
                              const float* __restrict__ bias, int relu, int M)
{
    int node = blockIdx.x * 4 + (threadIdx.x >> 6);
    int lane = threadIdx.x & 63;
    if (node >= M) return;
    int beg = rowptr[node], end = rowptr[node + 1];
    float dn = dv[node];
    float ax = 0.f, ay = 0.f;
    int e = beg;
    for (; e + 3 < end; e += 4) {
        int s0 = csr[e], s1 = csr[e + 1], s2 = csr[e + 2], s3 = csr[e + 3];
        float c0 = dn * dv[s0], c1 = dn * dv[s1], c2 = dn * dv[s2], c3 = dn * dv[s3];
        unsigned int u0 = *(const unsigned int*)(Xb + (size_t)s0 * 128 + lane * 2);
        unsigned int u1 = *(const unsigned int*)(Xb + (size_t)s1 * 128 + lane * 2);
        unsigned int u2 = *(const unsigned int*)(Xb + (size_t)s2 * 128 + lane * 2);
        unsigned int u3 = *(const unsigned int*)(Xb + (size_t)s3 * 128 + lane * 2);
        ax = fmaf(c0, bf2f(u0 & 0xffff), fmaf(c1, bf2f(u1 & 0xffff),
             fmaf(c2, bf2f(u2 & 0xffff), fmaf(c3, bf2f(u3 & 0xffff), ax))));
        ay = fmaf(c0, bf2f(u0 >> 16), fmaf(c1, bf2f(u1 >> 16),
             fmaf(c2, bf2f(u2 >> 16), fmaf(c3, bf2f(u3 >> 16), ay))));
    }
    for (; e < end; e++) {
        int s = csr[e];
        float c = dn * dv[s];
        unsigned int u = *(const unsigned int*)(Xb + (size_t)s * 128 + lane * 2);
        ax = fmaf(c, bf2f(u & 0xffff), ax);
        ay = fmaf(c, bf2f(u >> 16), ay);
    }
    if (self_loop) {
        float c = dn * dn;
        unsigned int u = *(const unsigned int*)(Xb + (size_t)node * 128 + lane * 2);
        ax = fmaf(c, bf2f(u & 0xffff), ax);
        ay = fmaf(c, bf2f(u >> 16), ay);
    }
    ax *= scale; ay *= scale;
    if (bias) { ax += bias[lane * 2]; ay += bias[lane * 2 + 1]; }
    if (relu) { ax = fmaxf(ax, 0.f); ay = fmaxf(ay, 0.f); }
    *(float2*)(Out + (size_t)node * 128 + lane * 2) = make_float2(ax, ay);
}

// ---------- fused dual gather ----------
__global__ void gather2_kernel(const ushort_t* __restrict__ Xb,
                               float* __restrict__ OutA, float* __restrict__ OutB,
                               const int* __restrict__ rowptr, const int* __restrict__ csr,
                               const float* __restrict__ dinv, const float* __restrict__ dinvl,
                               int M)
{
    int node = blockIdx.x * 4 + (threadIdx.x >> 6);
    int lane = threadIdx.x & 63;
    if (node >= M) return;
    int beg = rowptr[node], end = rowptr[node + 1];
    float dn = dinv[node], dnl = dinvl[node];
    float axA = 0.f, ayA = 0.f, axB = 0.f, ayB = 0.f;
    int e = beg;
    for (; e + 1 < end; e += 2) {
        int s0 = csr[e], s1 = csr[e + 1];
        float c0 = dn * dinv[s0], c1 = dn * dinv[s1];
        float l0 = dnl * dinvl[s0], l1 = dnl * dinvl[s1];
        unsigned int u0 = *(const unsigned int*)(Xb + (size_t)s0 * 128 + lane * 2);
        unsigned int u1 = *(const unsigned int*)(Xb + (size_t)s1 * 128 + lane * 2);
        float x00 = bf2f(u0 & 0xffff), x01 = bf2f(u0 >> 16);
        float x10 = bf2f(u1 & 0xffff), x11 = bf2f(u1 >> 16);
        axA = fmaf(c0, x00, fmaf(c1, x10, axA));
        ayA = fmaf(c0, x01, fmaf(c1, x11, ayA));
        axB = fmaf(l0, x00, fmaf(l1, x10, axB));
        ayB = fmaf(l0, x01, fmaf(l1, x11, ayB));
    }
    for (; e < end; e++) {
        int s = csr[e];
        float c = dn * dinv[s], l = dnl * dinvl[s];
        unsigned int u = *(const unsigned int*)(Xb + (size_t)s * 128 + lane * 2);
        float x0 = bf2f(u & 0xffff), x1 = bf2f(u >> 16);
        axA = fmaf(c, x0, axA); ayA = fmaf(c, x1, ayA);
        axB = fmaf(l, x0, axB); ayB = fmaf(l, x1, ayB);
    }
    {
        float c = dnl * dnl;
        unsigned int u = *(const unsigned int*)(Xb + (size_t)node * 128 + lane * 2);
        axB = fmaf(c, bf2f(u & 0xffff), axB);
        ayB = fmaf(c, bf2f(u >> 16), ayB);
    }
    size_t ofs = (size_t)node * 128 + lane * 2;
    *(float2*)(OutA + ofs) = make_float2(-axA, -ayA);
    *(float2*)(OutB + ofs) = make_float2(axB, ayB);
}

// ---------- attention: interleaved KV [N][256], no-max softmax, unroll 4 ----------
__global__ void gt_attn_kernel(const float* __restrict__ Q, const ushort_t* __restrict__ KV,
                               const int* __restrict__ rowptr, const int* __restrict__ csr,
                               float* __restrict__ Out, int M)
{
    const float SCL = 0.17677669529663689f * 1.4426950408889634f;
    int node = blockIdx.x * 4 + (threadIdx.x >> 6);
    int lane = threadIdx.x & 63;
    if (node >= M) return;
    int beg = rowptr[node], end = rowptr[node + 1];
    float2 q = *(const float2*)(Q + (size_t)node * 128 + lane * 2);
    q.x *= SCL; q.y *= SCL;
    float den = 0.f, ax = 0.f, ay = 0.f;
    int e = beg;
    for (; e + 3 < end; e += 4) {
        int s0 = csr[e], s1 = csr[e + 1], s2 = csr[e + 2], s3 = csr[e + 3];
        unsigned int k0 = *(const unsigned int*)(KV + (size_t)s0 * 256 + lane * 2);
        unsigned int k1 = *(const unsigned int*)(KV + (size_t)s1 * 256 + lane * 2);
        unsigned int k2 = *(const unsigned int*)(KV + (size_t)s2 * 256 + lane * 2);
        unsigned int k3 = *(const unsigned int*)(KV + (size_t)s3 * 256 + lane * 2);
        unsigned int v0 = *(const unsigned int*)(KV + (size_t)s0 * 256 + 128 + lane * 2);
        unsigned int v1 = *(const unsigned int*)(KV + (size_t)s1 * 256 + 128 + lane * 2);
        unsigned int v2 = *(const unsigned int*)(KV + (size_t)s2 * 256 + 128 + lane * 2);
        unsigned int v3 = *(const unsigned int*)(KV + (size_t)s3 * 256 + 128 + lane * 2);
        float p0 = q.x * bf2f(k0 & 0xffff) + q.y * bf2f(k0 >> 16);
        float p1 = q.x * bf2f(k1 & 0xffff) + q.y * bf2f(k1 >> 16);
        float p2 = q.x * bf2f(k2 & 0xffff) + q.y * bf2f(k2 >> 16);
        float p3 = q.x * bf2f(k3 & 0xffff) + q.y * bf2f(k3 >> 16);
#pragma unroll
        for (int off = 1; off <= 8; off <<= 1) {
            p0 += __shfl_xor(p0, off); p1 += __shfl_xor(p1, off);
            p2 += __shfl_xor(p2, off); p3 += __shfl_xor(p3, off);
        }
        float w0 = exp2f(fminf(p0, 80.f));
        float w1 = exp2f(fminf(p1, 80.f));
        float w2 = exp2f(fminf(p2, 80.f));
        float w3 = exp2f(fminf(p3, 80.f));
        den += (w0 + w1) + (w2 + w3);
        ax = fmaf(w0, bf2f(v0 & 0xffff), fmaf(w1, bf2f(v1 & 0xffff),
             fmaf(w2, bf2f(v2 & 0xffff), fmaf(w3, bf2f(v3 & 0xffff), ax))));
        ay = fmaf(w0, bf2f(v0 >> 16), fmaf(w1, bf2f(v1 >> 16),
             fmaf(w2, bf2f(v2 >> 16), fmaf(w3, bf2f(v3 >> 16), ay))));
    }
    for (; e < end; e++) {
        int s = csr[e];
        unsigned int ku = *(const unsigned int*)(KV + (size_t)s * 256 + lane * 2);
        unsigned int vu = *(const unsigned int*)(KV + (size_t)s * 256 + 128 + lane * 2);
        float p = q.x * bf2f(ku & 0xffff) + q.y * bf2f(ku >> 16);
#pragma unroll
        for (int off = 1; off <= 8; off <<= 1) p += __shfl_xor(p, off);
        float w = exp2f(fminf(p, 80.f));
        den += w;
        ax = fmaf(w, bf2f(vu & 0xffff), ax);
        ay = fmaf(w, bf2f(vu >> 16), ay);
    }
    float d = fmaxf(den, 1e-9f);
    *(float2*)(Out + (size_t)node * 128 + lane * 2) = make_float2(ax / d, ay / d);
}

// ---------- fused combine + pool phase 1: one wave per (graph, chunk) ----------
__global__ void pool_combine_kernel(const float* __restrict__ h,
                                    const float* __restrict__ e0, const float* __restrict__ e1,
                                    const float* __restrict__ e2, const float* __restrict__ e3,
                                    const float* __restrict__ gates,
                                    const float* __restrict__ png, const float* __restrict__ pnb,
                                    const float* __restrict__ esc,
                                    const int* __restrict__ bstart, const int* __restrict__ bend,
                                    float* __restrict__ partial)
{
    int b = blockIdx.x, c = blockIdx.y;
    int lane = threadIdx.x;   // 64
    int s0 = bstart[b], e0i = bend[b];
    float g0a = png[0 * 128 + lane * 2], g0b = png[0 * 128 + lane * 2 + 1];
    float g1a = png[1 * 128 + lane * 2], g1b = png[1 * 128 + lane * 2 + 1];
    float g2a = png[2 * 128 + lane * 2], g2b = png[2 * 128 + lane * 2 + 1];
    float g3a = png[3 * 128 + lane * 2], g3b = png[3 * 128 + lane * 2 + 1];
    float b0a = pnb[0 * 128 + lane * 2], b0b = pnb[0 * 128 + lane * 2 + 1];
    float b1a = pnb[1 * 128 + lane * 2], b1b = pnb[1 * 128 + lane * 2 + 1];
    float b2a = pnb[2 * 128 + lane * 2], b2b = pnb[2 * 128 + lane * 2 + 1];
    float b3a = pnb[3 * 128 + lane * 2], b3b = pnb[3 * 128 + lane * 2 + 1];
    float es0 = esc[0], es1 = esc[1], es2 = esc[2], es3 = esc[3];
    const float* eps[4] = {e0, e1, e2, e3};
    float ga[4] = {g0a, g1a, g2a, g3a}, gb[4] = {g0b, g1b, g2b, g3b};
    float ba[4] = {b0a, b1a, b2a, b3a}, bb[4] = {b0b, b1b, b2b, b3b};
    float es[4] = {es0, es1, es2, es3};
    float sx = 0.f, sy = 0.f;
    for (int n = s0 + c; n < e0i; n += PCH) {
        size_t ofs = (size_t)n * 128 + lane * 2;
        float4 gg = *(const float4*)(gates + (size_t)n * 4);
        float gv[4] = {gg.x, gg.y, gg.z, gg.w};
        float2 hv = *(const float2*)(h + ofs);
        float ox = hv.x, oy = hv.y;
#pragma unroll
        for (int ee = 0; ee < 4; ee++) {
            float2 v = *(const float2*)(eps[ee] + ofs);
            float su = v.x + v.y, sq = v.x * v.x + v.y * v.y;
#pragma unroll
            for (int off = 32; off; off >>= 1) { su += __shfl_xor(su, off); sq += __shfl_xor(sq, off); }
            float mean = su * (1.f / 128.f);
            float var = sq * (1.f / 128.f) - mean * mean;
            float inv = rsqrtf(var + 1e-5f);
            float cc = es[ee] * gv[ee];
            ox = fmaf(cc, (v.x - mean) * inv * ga[ee] + ba[ee], ox);
            oy = fmaf(cc, (v.y - mean) * inv * gb[ee] + bb[ee], oy);
        }
        sx += ox; sy += oy;
    }
    *(float2*)(partial + ((size_t)b * PCH + c) * 128 + lane * 2) = make_float2(sx, sy);
}
__global__ void pool_reduce_kernel(const float* __restrict__ partial,
                                   const int* __restrict__ bstart, const int* __restrict__ bend,
                                   float* __restrict__ pooled)
{
    int b = blockIdx.x, t = threadIdx.x;
    float sum = 0.f;
#pragma unroll
    for (int c = 0; c < PCH; c++) sum += partial[((size_t)b * PCH + c) * 128 + t];
    float cnt = fmaxf((float)(bend[b] - bstart[b]), 1.f);
    pooled[(size_t)b * 128 + t] = sum / cnt;
}

// ---------- classification head (fp32 out) ----------
__global__ void head_kernel(const float* __restrict__ pooled,
                            const float* __restrict__ h1W, const float* __restrict__ h1b,
                            const float* __restrict__ h1g, const float* __restrict__ h1be,
                            const float* __restrict__ h2W, const float* __restrict__ h2b,
                            const float* __restrict__ h2g, const float* __restrict__ h2be,
                            const float* __restrict__ h3W, const float* __restrict__ h3b,
                            const float* __restrict__ lbias,
                            float* __restrict__ out, int B)
{
    __shared__ float p[128], z[128];
    int b = blockIdx.x, t = threadIdx.x;
    p[t] = pooled[(size_t)b * 128 + t];
    __syncthreads();
    float a = h1b[t];
    for (int k = 0; k < 128; k++) a = fmaf(p[k], h1W[k * 128 + t], a);
    z[t] = a;
    __syncthreads();
    float s = 0.f, sq = 0.f;
    for (int k = 0; k < 128; k++) { float x = z[k]; s += x; sq += x * x; }
    float mean = s * (1.f / 128.f), var = sq * (1.f / 128.f) - mean * mean;
    float y = fmaxf((a - mean) * rsqrtf(var + 1e-5f) * h1g[t] + h1be[t], 0.f);
    __syncthreads();
    z[t] = y;
    __syncthreads();
    float a2 = 0.f;
    if (t < 64) {
        a2 = h2b[t];
        for (int k = 0; k < 128; k++) a2 = fmaf(z[k], h2W[k * 64 + t], a2);
    }
    __syncthreads();
    if (t < 64) p[t] = a2;
    __syncthreads();
    if (t < 2) {
        float s2 = 0.f, sq2 = 0.f;
        for (int k = 0; k < 64; k++) { float x = p[k]; s2 += x; sq2 += x * x; }
        float mean2 = s2 * (1.f / 64.f), var2 = sq2 * (1.f / 64.f) - mean2 * mean2;
        float inv2 = rsqrtf(var2 + 1e-5f);
        float o = h3b[t] + lbias[t];
        for (int k = 0; k < 64; k++) {
            float zc = fmaxf((p[k] - mean2) * inv2 * h2g[k] + h2be[k], 0.f);
            o = fmaf(zc, h3W[k * 2 + t], o);
        }
        out[b * 2 + t] = o;
    }
}

// ---------------- launch ----------------
extern "C" void kernel_launch(void* const* d_in, const int* in_sizes, int n_in,
                              void* d_out, int out_size, void* d_ws, size_t ws_size,
                              hipStream_t stream)
{
    (void)ws_size; (void)n_in;
    const int N = in_sizes[3];
    const int E = in_sizes[2] / 2;
    const int B = out_size / 2;

    const int* ei = (const int*)d_in[2];
    const int* src = ei;
    const int* dst = ei + E;
    const int* batch = (const int*)d_in[3];

    const float* W[47];
    for (int i = 0; i < 47; i++) W[i] = (const float*)d_in[i];

    size_t fN = (size_t)N;
    float* hr    = (float*)d_ws;
    float* h     = hr + 256 * fN;
    float* e0    = h + 128 * fN;
    float* e1    = e0 + 128 * fN;
    float* e2    = e1 + 128 * fN;
    float* e3    = e2 + 128 * fN;
    float* tmp0  = e3 + 128 * fN;
    float* tmp1  = tmp0 + 128 * fN;
    float* gates = tmp1 + 128 * fN;
    float* dinv  = gates + 4 * fN;
    float* dinvl = dinv + fN;
    float* pooled = dinvl + fN;
    float* partial = pooled + (size_t)128 * B;
    ushort_t* hb  = (ushort_t*)(partial + (size_t)128 * B * PCH);
    ushort_t* bf0 = hb + 128 * fN;     // also serves as KV[N][256] (spans bf0+bf1)
    ushort_t* bf1 = bf0 + 128 * fN;
    ushort_t* wt  = bf1 + 128 * fN;
    // weight table: QKV contiguous per layer
    WtPack wp;
    const float* wsrc[NWT] = {
        W[4], W[8], W[12], W[17], W[19],
        W[21], W[21] + 16384, W[21] + 32768, W[21] + 49152,
        W[23], W[25], W[27],                     // q0,k0,v0 contiguous
        W[23] + 16384, W[25] + 16384, W[27] + 16384,  // q1,k1,v1 contiguous
        W[29], W[29] + 16384,
        W[31], W[31] + 16384
    };
    const int wk[NWT] = {200, 128, 256, 128, 128,
                         128, 128, 128, 128,
                         128, 128, 128,
                         128, 128, 128,
                         128, 128,
                         128, 128};
    unsigned long long woff[NWT];
    unsigned long long acc_off = 0;
    for (int i = 0; i < NWT; i++) {
        wp.src[i] = wsrc[i];
        wp.K[i] = wk[i];
        wp.off[i] = acc_off;
        woff[i] = acc_off;
        acc_off += (unsigned long long)128 * wk[i];
    }
    int* degi   = (int*)(wt + acc_off + 8);
    int* cursor = degi + N;
    int* rowptr = cursor + N;
    int* csr    = rowptr + (N + 1);
    int* bstart = csr + E;
    int* bend   = bstart + B;
    int* bsum   = bend + B;
    float* bufA = hr;
    float* bufB = hr + 128 * fN;

    dim3 blk(256);
    int gN4 = (N + 3) / 4;
    dim3 gG((N + 63) / 64);
    int nsb = (N + SCH - 1) / SCH;
    ushort_t* NOB = (ushort_t*)0;

    // weights + graph structure
    wconv_kernel<<<dim3(32, NWT), blk, 0, stream>>>(wp, wt);
    zero_i32_kernel<<<(2 * N + 255) / 256, blk, 0, stream>>>(degi, 2 * N);
    zero_i32_kernel<<<1, blk, 0, stream>>>(bstart, 2 * B);
    seg_bounds_kernel<<<(N + 255) / 256, blk, 0, stream>>>(batch, bstart, bend, N);
    edge_deg_kernel<<<(E + 255) / 256, blk, 0, stream>>>(dst, degi, E);
    scan1_kernel<<<dim3(nsb), blk, 0, stream>>>(degi, rowptr, bsum, N);
    scan2_kernel<<<1, blk, 0, stream>>>(bsum, nsb);
    scan3_kernel<<<(N + 255) / 256, blk, 0, stream>>>(rowptr, bsum, N);
    csr_fill_kernel<<<(E + 255) / 256, blk, 0, stream>>>(src, dst, rowptr, cursor, csr, E);
    dinv_kernel<<<(N + 255) / 256, blk, 0, stream>>>(degi, dinv, dinvl, N);

    // encoders + fuse + router
    gemm_kernel<<<gG, blk, 0, stream>>>(W[0], 200, wt + woff[0], hr, 256, N, 200, W[5], 0, NOB);
    gemm_kernel<<<gG, blk, 0, stream>>>(W[1], 128, wt + woff[1], hr + 128, 256, N, 128, W[9], 0, NOB);
    ln_relu_kernel<<<gN4, blk, 0, stream>>>(hr, 256, W[6], W[7], N, NOB);
    ln_relu_kernel<<<gN4, blk, 0, stream>>>(hr + 128, 256, W[10], W[11], N, NOB);
    router_kernel<<<gN4, blk, 0, stream>>>(hr, W[16], gates, N);
    gemm_kernel<<<gG, blk, 0, stream>>>(hr, 256, wt + woff[2], h, 128, N, 256, W[13], 0, NOB);
    ln_relu_kernel<<<gN4, blk, 0, stream>>>(h, 128, W[14], W[15], N, hb);

    // expert 0: MLP
    gemm_kernel<<<gG, blk, 0, stream>>>(h, 128, wt + woff[3], bufA, 128, N, 128, W[18], RELUF, NOB);
    gemm_kernel<<<gG, blk, 0, stream>>>(bufA, 128, wt + woff[4], e0, 128, N, 128, W[20], 0, NOB);

    // fused layer-1 gather: bufA = -aprop_dinv(h) [Cheb]; tmp1 = gcn gather(h)
    gather2_kernel<<<gN4, blk, 0, stream>>>(hb, bufA, tmp1, rowptr, csr, dinv, dinvl, N);

    // expert 1: ChebNet K=2 (dual GEMMs)
    gemm_dual_kernel<<<gG, blk, 0, stream>>>(h, wt + woff[5], bufA, wt + woff[6],
                                             bufB, N, 128, W[22], RELUF, bf0);
    gather_kernel<<<gN4, blk, 0, stream>>>(bf0, bufA, rowptr, csr, dinv, 0, -1.f, (const float*)0, 0, N);
    gemm_dual_kernel<<<gG, blk, 0, stream>>>(bufB, wt + woff[7], bufA, wt + woff[8],
                                             e1, N, 128, W[22] + 128, 0, NOB);

    // expert 3: GCN (gather-then-GEMM)
    gemm_kernel<<<gG, blk, 0, stream>>>(tmp1, 128, wt + woff[17], bufA, 128, N, 128, W[32], RELUF, bf0);
    gather_kernel<<<gN4, blk, 0, stream>>>(bf0, tmp1, rowptr, csr, dinvl, 1, 1.f, (const float*)0, 0, N);
    gemm_kernel<<<gG, blk, 0, stream>>>(tmp1, 128, wt + woff[18], e3, 128, N, 128, W[32] + 128, 0, NOB);

    // expert 2: Graph Transformer (2 layers, fused QKV + interleaved KV)
    gemm3_kernel<<<gG, blk, 0, stream>>>(h, 128, wt + woff[9], bufA, N, 128,
                                         W[24], W[26], W[28], bf0);
    gt_attn_kernel<<<gN4, blk, 0, stream>>>(bufA, bf0, rowptr, csr, tmp1, N);
    gemm_kernel<<<gG, blk, 0, stream>>>(h, 128, wt + woff[15], tmp1, 128, N, 128, W[30], ACCF | RELUF, NOB);
    gemm3_kernel<<<gG, blk, 0, stream>>>(tmp1, 128, wt + woff[12], bufA, N, 128,
                                         W[24] + 128, W[26] + 128, W[28] + 128, bf0);
    gt_attn_kernel<<<gN4, blk, 0, stream>>>(bufA, bf0, rowptr, csr, e2, N);
    gemm_kernel<<<gG, blk, 0, stream>>>(tmp1, 128, wt + woff[16], e2, 128, N, 128, W[30] + 128, ACCF, NOB);

    // fused combine+pool + head
    pool_combine_kernel<<<dim3(B, PCH), dim3(64), 0, stream>>>(
        h, e0, e1, e2, e3, gates, W[33], W[34], W[35], bstart, bend, partial);
    pool_reduce_kernel<<<dim3(B), dim3(128), 0, stream>>>(partial, bstart, bend, pooled);
    head_kernel<<<dim3(B), dim3(128), 0, stream>>>(pooled,
        W[36], W[37], W[38], W[39],
        W[40], W[41], W[42], W[43],
        W[44], W[45], W[46],
        (float*)d_out, B);
}

// Round 11
// 660.183 us; speedup vs baseline: 2.3446x; 1.0588x over previous
//
#include <hip/hip_runtime.h>

#define RELUF 1
#define ACCF  2
#define PCH   16
#define NWT   19
#define SCH   2048

typedef unsigned short ushort_t;
typedef __attribute__((ext_vector_type(8))) short bf16x8;
typedef __attribute__((ext_vector_type(4))) float f32x4;

__device__ __forceinline__ float bf2f(unsigned int v) {
    return __uint_as_float(v << 16);
}
__device__ __forceinline__ unsigned int f2bu(float f) {
    unsigned int u = __float_as_uint(f);
    return (u + 0x7fffu + ((u >> 16) & 1u)) >> 16;
}

// ---------------- utility ----------------
__global__ void zero_i32_kernel(int* __restrict__ p, int n) {
    int i = blockIdx.x * blockDim.x + threadIdx.x;
    if (i < n) p[i] = 0;
}
__global__ void seg_bounds_kernel(const int* __restrict__ batch, int* __restrict__ bstart,
                                  int* __restrict__ bend, int N) {
    int n = blockIdx.x * blockDim.x + threadIdx.x;
    if (n >= N) return;
    int b = batch[n];
    if (n == 0) bstart[b] = 0;
    else {
        int pb = batch[n - 1];
        if (pb != b) { bstart[b] = n; bend[pb] = n; }
    }
    if (n == N - 1) bend[b] = N;
}

// ---------- parallel 3-phase scan ----------
__global__ void scan1_kernel(const int* __restrict__ degi, int* __restrict__ rowptr,
                             int* __restrict__ bsum, int n) {
    __shared__ int sh[256];
    int tid = threadIdx.x;
    int base = blockIdx.x * SCH + tid * 8;
    int loc[8]; int s = 0;
#pragma unroll
    for (int j = 0; j < 8; j++) {
        int idx = base + j;
        int v = (idx < n) ? degi[idx] : 0;
        s += v; loc[j] = s;
    }
    sh[tid] = s;
    __syncthreads();
    for (int off = 1; off < 256; off <<= 1) {
        int t = (tid >= off) ? sh[tid - off] : 0;
        __syncthreads();
        sh[tid] += t;
        __syncthreads();
    }
    int prev = (tid > 0) ? sh[tid - 1] : 0;
#pragma unroll
    for (int j = 0; j < 8; j++) {
        int idx = base + j;
        if (idx < n) rowptr[idx + 1] = prev + loc[j];
    }
    if (tid == 255) bsum[blockIdx.x] = sh[255];
}
__global__ void scan2_kernel(int* __restrict__ bsum, int nb) {
    __shared__ int sh[256];
    int tid = threadIdx.x;
    sh[tid] = (tid < nb) ? bsum[tid] : 0;
    __syncthreads();
    for (int off = 1; off < 256; off <<= 1) {
        int t = (tid >= off) ? sh[tid - off] : 0;
        __syncthreads();
        sh[tid] += t;
        __syncthreads();
    }
    if (tid < nb) bsum[tid] = (tid > 0) ? sh[tid - 1] : 0;
}
__global__ void scan3_kernel(int* __restrict__ rowptr, const int* __restrict__ bsum, int n) {
    int i = blockIdx.x * blockDim.x + threadIdx.x;
    if (i == 0) rowptr[0] = 0;
    if (i < n) rowptr[i + 1] += bsum[i / SCH];
}

// ---------- batched W transpose+convert ----------
struct WtPack {
    const float* src[NWT];
    unsigned long long off[NWT];
    int K[NWT];
};
__global__ void wconv_kernel(WtPack p, ushort_t* __restrict__ base) {
    int a = blockIdx.y;
    const float* s = p.src[a];
    ushort_t* d = base + p.off[a];
    int K = p.K[a];
    int total = K * 128;
    for (int i = blockIdx.x * blockDim.x + threadIdx.x; i < total; i += gridDim.x * blockDim.x) {
        int k = i >> 7, n = i & 127;
        d[n * K + k] = (ushort_t)f2bu(s[i]);
    }
}

// ---------- fp32-A MFMA GEMM (hr path): C fp32 ----------
__global__ __launch_bounds__(256)
void gemm_f32_kernel(const float* __restrict__ A, int lda,
                     const ushort_t* __restrict__ Wt,
                     float* __restrict__ C, int ldc,
                     int M, int K,
                     const float* __restrict__ bias)
{
    __shared__ ushort_t As[64][40];
    __shared__ ushort_t Bs[128][40];
    const int tid = threadIdx.x;
    const int m0 = blockIdx.x * 64;
    const int lane = tid & 63;
    const int wv = tid >> 6;
    const int q = lane >> 4;
    const int l16 = lane & 15;
    const int sar = tid >> 2;
    const int sak = (tid & 3) << 3;
    const int sbn = tid >> 1;
    const int sbk = (tid & 1) << 4;
    const bool arow_ok = (m0 + sar) < M;
    const float* Arow = A + (size_t)(m0 + sar) * lda;
    const ushort_t* Wrow = Wt + (size_t)sbn * K;

    f32x4 acc[8];
#pragma unroll
    for (int t = 0; t < 8; t++) acc[t] = (f32x4){0.f, 0.f, 0.f, 0.f};

    for (int k0 = 0; k0 < K; k0 += 32) {
        uint4 apk;
        if (arow_ok && k0 + sak + 8 <= K) {
            float4 p0 = *(const float4*)(Arow + k0 + sak);
            float4 p1 = *(const float4*)(Arow + k0 + sak + 4);
            apk.x = f2bu(p0.x) | (f2bu(p0.y) << 16);
            apk.y = f2bu(p0.z) | (f2bu(p0.w) << 16);
            apk.z = f2bu(p1.x) | (f2bu(p1.y) << 16);
            apk.w = f2bu(p1.z) | (f2bu(p1.w) << 16);
        } else {
            unsigned int t4[4] = {0, 0, 0, 0};
            for (int j = 0; j < 8; j++) {
                int k = k0 + sak + j;
                unsigned int bv = (arow_ok && k < K) ? f2bu(Arow[k]) : 0u;
                t4[j >> 1] |= bv << ((j & 1) * 16);
            }
            apk = make_uint4(t4[0], t4[1], t4[2], t4[3]);
        }
        uint4 b0, b1;
        if (k0 + sbk + 16 <= K) {
            b0 = *(const uint4*)(Wrow + k0 + sbk);
            b1 = *(const uint4*)(Wrow + k0 + sbk + 8);
        } else {
            unsigned int t8[8] = {0, 0, 0, 0, 0, 0, 0, 0};
            for (int j = 0; j < 16; j++) {
                int k = k0 + sbk + j;
                unsigned int bv = (k < K) ? (unsigned int)Wrow[k] : 0u;
                t8[j >> 1] |= bv << ((j & 1) * 16);
            }
            b0 = make_uint4(t8[0], t8[1], t8[2], t8[3]);
            b1 = make_uint4(t8[4], t8[5], t8[6], t8[7]);
        }
        __syncthreads();
        *(uint4*)&As[sar][sak] = apk;
        *(uint4*)&Bs[sbn][sbk] = b0;
        *(uint4*)&Bs[sbn][sbk + 8] = b1;
        __syncthreads();
        bf16x8 af = *(const bf16x8*)&As[16 * wv + l16][q * 8];
#pragma unroll
        for (int t = 0; t < 8; t++) {
            bf16x8 bf = *(const bf16x8*)&Bs[t * 16 + l16][q * 8];
            acc[t] = __builtin_amdgcn_mfma_f32_16x16x32_bf16(af, bf, acc[t], 0, 0, 0);
        }
    }
#pragma unroll
    for (int t = 0; t < 8; t++) {
        int col = t * 16 + l16;
        float bb = bias ? bias[col] : 0.f;
#pragma unroll
        for (int r = 0; r < 4; r++) {
            int row = m0 + 16 * wv + q * 4 + r;
            if (row < M) C[(size_t)row * ldc + col] = acc[t][r] + bb;
        }
    }
}

// ---------- bf16-A MFMA GEMM: Cb bf16 in/out, K=128 ----------
__global__ __launch_bounds__(256)
void gemm_bf_kernel(const ushort_t* __restrict__ A,
                    const ushort_t* __restrict__ Wt,
                    ushort_t* __restrict__ Cb,
                    int M, const float* __restrict__ bias, int flags)
{
    const int K = 128;
    __shared__ ushort_t As[64][40];
    __shared__ ushort_t Bs[128][40];
    const int tid = threadIdx.x;
    const int m0 = blockIdx.x * 64;
    const int lane = tid & 63;
    const int wv = tid >> 6;
    const int q = lane >> 4;
    const int l16 = lane & 15;
    const int sar = tid >> 2;
    const int sak = (tid & 3) << 3;
    const int sbn = tid >> 1;
    const int sbk = (tid & 1) << 4;
    const bool arow_ok = (m0 + sar) < M;
    const ushort_t* Arow = A + (size_t)(m0 + sar) * K;
    const ushort_t* Wrow = Wt + (size_t)sbn * K;

    f32x4 acc[8];
#pragma unroll
    for (int t = 0; t < 8; t++) acc[t] = (f32x4){0.f, 0.f, 0.f, 0.f};

    for (int k0 = 0; k0 < K; k0 += 32) {
        uint4 apk = arow_ok ? *(const uint4*)(Arow + k0 + sak) : make_uint4(0, 0, 0, 0);
        uint4 b0 = *(const uint4*)(Wrow + k0 + sbk);
        uint4 b1 = *(const uint4*)(Wrow + k0 + sbk + 8);
        __syncthreads();
        *(uint4*)&As[sar][sak] = apk;
        *(uint4*)&Bs[sbn][sbk] = b0;
        *(uint4*)&Bs[sbn][sbk + 8] = b1;
        __syncthreads();
        bf16x8 af = *(const bf16x8*)&As[16 * wv + l16][q * 8];
#pragma unroll
        for (int t = 0; t < 8; t++) {
            bf16x8 bf = *(const bf16x8*)&Bs[t * 16 + l16][q * 8];
            acc[t] = __builtin_amdgcn_mfma_f32_16x16x32_bf16(af, bf, acc[t], 0, 0, 0);
        }
    }
#pragma unroll
    for (int t = 0; t < 8; t++) {
        int col = t * 16 + l16;
        float bb = bias ? bias[col] : 0.f;
#pragma unroll
        for (int r = 0; r < 4; r++) {
            int row = m0 + 16 * wv + q * 4 + r;
            bool ok = row < M;
            float val = acc[t][r] + bb;
            if ((flags & ACCF) && ok) val += bf2f(Cb[(size_t)row * 128 + col]);
            if (flags & RELUF) val = fmaxf(val, 0.f);
            float other = __shfl_xor(val, 1);
            if (!(lane & 1) && ok) {
                unsigned int pk = f2bu(val) | (f2bu(other) << 16);
                *(unsigned int*)(Cb + (size_t)row * 128 + col) = pk;
            }
        }
    }
}

// ---------- bf16 dual GEMM: Cb = A1@W1 + A2@W2 (+bias)(+relu) ----------
__global__ __launch_bounds__(256)
void gemm_dual_kernel(const ushort_t* __restrict__ A1, const ushort_t* __restrict__ Wt1,
                      const ushort_t* __restrict__ A2, const ushort_t* __restrict__ Wt2,
                      ushort_t* __restrict__ Cb, int M,
                      const float* __restrict__ bias, int flags)
{
    const int K = 128;
    __shared__ ushort_t As[64][40];
    __shared__ ushort_t Bs[128][40];
    const int tid = threadIdx.x;
    const int m0 = blockIdx.x * 64;
    const int lane = tid & 63;
    const int wv = tid >> 6;
    const int q = lane >> 4;
    const int l16 = lane & 15;
    const int sar = tid >> 2;
    const int sak = (tid & 3) << 3;
    const int sbn = tid >> 1;
    const int sbk = (tid & 1) << 4;
    const bool arow_ok = (m0 + sar) < M;

    f32x4 acc[8];
#pragma unroll
    for (int t = 0; t < 8; t++) acc[t] = (f32x4){0.f, 0.f, 0.f, 0.f};

    for (int ph = 0; ph < 2; ph++) {
        const ushort_t* Arow = (ph ? A2 : A1) + (size_t)(m0 + sar) * K;
        const ushort_t* Wrow = (ph ? Wt2 : Wt1) + (size_t)sbn * K;
        for (int k0 = 0; k0 < K; k0 += 32) {
            uint4 apk = arow_ok ? *(const uint4*)(Arow + k0 + sak) : make_uint4(0, 0, 0, 0);
            uint4 b0 = *(const uint4*)(Wrow + k0 + sbk);
            uint4 b1 = *(const uint4*)(Wrow + k0 + sbk + 8);
            __syncthreads();
            *(uint4*)&As[sar][sak] = apk;
            *(uint4*)&Bs[sbn][sbk] = b0;
            *(uint4*)&Bs[sbn][sbk + 8] = b1;
            __syncthreads();
            bf16x8 af = *(const bf16x8*)&As[16 * wv + l16][q * 8];
#pragma unroll
            for (int t = 0; t < 8; t++) {
                bf16x8 bf = *(const bf16x8*)&Bs[t * 16 + l16][q * 8];
                acc[t] = __builtin_amdgcn_mfma_f32_16x16x32_bf16(af, bf, acc[t], 0, 0, 0);
            }
        }
    }
#pragma unroll
    for (int t = 0; t < 8; t++) {
        int col = t * 16 + l16;
        float bb = bias ? bias[col] : 0.f;
#pragma unroll
        for (int r = 0; r < 4; r++) {
            int row = m0 + 16 * wv + q * 4 + r;
            bool ok = row < M;
            float val = acc[t][r] + bb;
            if (flags & RELUF) val = fmaxf(val, 0.f);
            float other = __shfl_xor(val, 1);
            if (!(lane & 1) && ok) {
                unsigned int pk = f2bu(val) | (f2bu(other) << 16);
                *(unsigned int*)(Cb + (size_t)row * 128 + col) = pk;
            }
        }
    }
}

// ---------- bf16 triple GEMM (QKV): q -> qb bf16; k/v -> interleaved kv bf16 ----------
__global__ __launch_bounds__(256)
void gemm3_kernel(const ushort_t* __restrict__ A,
                  const ushort_t* __restrict__ Wt,
                  ushort_t* __restrict__ qb,
                  int M,
                  const float* __restrict__ b0, const float* __restrict__ b1,
                  const float* __restrict__ b2,
                  ushort_t* __restrict__ kv)
{
    const int K = 128;
    __shared__ ushort_t As[64][40];
    __shared__ ushort_t Bs[384][40];
    const int tid = threadIdx.x;
    const int m0 = blockIdx.x * 64;
    const int lane = tid & 63;
    const int wv = tid >> 6;
    const int q = lane >> 4;
    const int l16 = lane & 15;
    const int sar = tid >> 2;
    const int sak = (tid & 3) << 3;
    const bool arow_ok = (m0 + sar) < M;
    const ushort_t* Arow = A + (size_t)(m0 + sar) * K;

    f32x4 acc[24];
#pragma unroll
    for (int t = 0; t < 24; t++) acc[t] = (f32x4){0.f, 0.f, 0.f, 0.f};

    for (int k0 = 0; k0 < K; k0 += 32) {
        uint4 apk = arow_ok ? *(const uint4*)(Arow + k0 + sak) : make_uint4(0, 0, 0, 0);
        uint4 bv[3][2];
        int rows[3], kofs[3];
#pragma unroll
        for (int j = 0; j < 3; j++) {
            int slot = tid + j * 256;
            rows[j] = slot >> 1;
            kofs[j] = (slot & 1) << 4;
            const ushort_t* Wrow = Wt + (size_t)rows[j] * K + k0 + kofs[j];
            bv[j][0] = *(const uint4*)Wrow;
            bv[j][1] = *(const uint4*)(Wrow + 8);
        }
        __syncthreads();
        *(uint4*)&As[sar][sak] = apk;
#pragma unroll
        for (int j = 0; j < 3; j++) {
            *(uint4*)&Bs[rows[j]][kofs[j]] = bv[j][0];
            *(uint4*)&Bs[rows[j]][kofs[j] + 8] = bv[j][1];
        }
        __syncthreads();
        bf16x8 af = *(const bf16x8*)&As[16 * wv + l16][q * 8];
#pragma unroll
        for (int t = 0; t < 24; t++) {
            bf16x8 bf = *(const bf16x8*)&Bs[t * 16 + l16][q * 8];
            acc[t] = __builtin_amdgcn_mfma_f32_16x16x32_bf16(af, bf, acc[t], 0, 0, 0);
        }
    }
    const float* bs[3] = {b0, b1, b2};
#pragma unroll
    for (int s = 0; s < 3; s++) {
#pragma unroll
        for (int t8 = 0; t8 < 8; t8++) {
            int t = s * 8 + t8;
            int col = t8 * 16 + l16;
            float bb = bs[s] ? bs[s][col] : 0.f;
#pragma unroll
            for (int r = 0; r < 4; r++) {
                int row = m0 + 16 * wv + q * 4 + r;
                bool ok = row < M;
                float val = acc[t][r] + bb;
                float other = __shfl_xor(val, 1);
                if (!(lane & 1) && ok) {
                    unsigned int pk = f2bu(val) | (f2bu(other) << 16);
                    if (s == 0)
                        *(unsigned int*)(qb + (size_t)row * 128 + col) = pk;
                    else
                        *(unsigned int*)(kv + (size_t)row * 256 + (s - 1) * 128 + col) = pk;
                }
            }
        }
    }
}

// ---------- LayerNorm(128)+ReLU: fp32 in; optional fp32 in-place + optional bf16 out ----------
__global__ void ln_relu_kernel(float* __restrict__ X, int ld,
                               const float* __restrict__ g,
                               const float* __restrict__ b, int M,
                               int wfp32, ushort_t* __restrict__ Xb)
{
    int node = blockIdx.x * 4 + (threadIdx.x >> 6);
    int lane = threadIdx.x & 63;
    if (node >= M) return;
    float* row = X + (size_t)node * ld;
    float2 v = *(float2*)(row + lane * 2);
    float s = v.x + v.y, sq = v.x * v.x + v.y * v.y;
#pragma unroll
    for (int off = 32; off; off >>= 1) { s += __shfl_xor(s, off); sq += __shfl_xor(sq, off); }
    float mean = s * (1.f / 128.f);
    float var = sq * (1.f / 128.f) - mean * mean;
    float inv = rsqrtf(var + 1e-5f);
    float y0 = fmaxf((v.x - mean) * inv * g[lane * 2] + b[lane * 2], 0.f);
    float y1 = fmaxf((v.y - mean) * inv * g[lane * 2 + 1] + b[lane * 2 + 1], 0.f);
    if (wfp32) *(float2*)(row + lane * 2) = make_float2(y0, y1);
    if (Xb) {
        unsigned int p = f2bu(y0) | (f2bu(y1) << 16);
        *(unsigned int*)(Xb + (size_t)node * 128 + lane * 2) = p;
    }
}

// ---------- router (fp32 exact) ----------
__global__ void router_kernel(const float* __restrict__ hr, const float* __restrict__ rW,
                              float* __restrict__ gates, int M)
{
    int node = blockIdx.x * 4 + (threadIdx.x >> 6);
    int lane = threadIdx.x & 63;
    if (node >= M) return;
    const float* row = hr + (size_t)node * 256;
    float a0 = 0, a1 = 0, a2 = 0, a3 = 0;
#pragma unroll
    for (int i = 0; i < 4; i++) {
        int k = lane + i * 64;
        float xv = row[k];
        float4 wv = *(const float4*)(rW + k * 4);
        a0 = fmaf(xv, wv.x, a0); a1 = fmaf(xv, wv.y, a1);
        a2 = fmaf(xv, wv.z, a2); a3 = fmaf(xv, wv.w, a3);
    }
#pragma unroll
    for (int off = 32; off; off >>= 1) {
        a0 += __shfl_xor(a0, off); a1 += __shfl_xor(a1, off);
        a2 += __shfl_xor(a2, off); a3 += __shfl_xor(a3, off);
    }
    if (lane == 0) {
        float l[4] = {a0 * (1.f / 1.5f), a1 * (1.f / 1.5f), a2 * (1.f / 1.5f), a3 * (1.f / 1.5f)};
        float mx = fmaxf(fmaxf(l[0], l[1]), fmaxf(l[2], l[3]));
        float e[4], ssum = 0.f;
#pragma unroll
        for (int i = 0; i < 4; i++) { e[i] = expf(l[i] - mx); ssum += e[i]; }
        float p[4];
#pragma unroll
        for (int i = 0; i < 4; i++) p[i] = e[i] / ssum;
        int i0 = 0;
        for (int i = 1; i < 4; i++) if (p[i] > p[i0]) i0 = i;
        int i1 = -1;
        for (int i = 0; i < 4; i++) {
            if (i == i0) continue;
            if (i1 < 0 || p[i] > p[i1]) i1 = i;
        }
        float wsum = fmaxf(p[i0] + p[i1], 1e-9f);
        float gg[4] = {0.f, 0.f, 0.f, 0.f};
        gg[i0] = p[i0] / wsum;
        gg[i1] = p[i1] / wsum;
        *(float4*)(gates + (size_t)node * 4) = make_float4(gg[0], gg[1], gg[2], gg[3]);
    }
}

// ---------- graph structure ----------
__global__ void edge_deg_kernel(const int* __restrict__ dst, int* __restrict__ degi, int E) {
    int e = blockIdx.x * blockDim.x + threadIdx.x;
    if (e < E) atomicAdd(&degi[dst[e]], 1);
}
__global__ void csr_fill_kernel(const int* __restrict__ src, const int* __restrict__ dst,
                                const int* __restrict__ rowptr, int* __restrict__ cursor,
                                int* __restrict__ csr, int E) {
    int e = blockIdx.x * blockDim.x + threadIdx.x;
    if (e >= E) return;
    int d = dst[e];
    int pos = atomicAdd(&cursor[d], 1);
    csr[rowptr[d] + pos] = src[e];
}
__global__ void dinv_kernel(const int* __restrict__ degi, float* __restrict__ dinv,
                            float* __restrict__ dinvl, int N) {
    int n = blockIdx.x * blockDim.x + threadIdx.x;
    if (n >= N) return;
    float deg = (float)degi[n];
    dinv[n] = (deg > 0.f) ? rsqrtf(fmaxf(deg, 1.f)) : 0.f;
    dinvl[n] = rsqrtf(deg + 1.f);
}

// ---------- gather: bf16 in -> bf16 out ----------
__global__ void gather_kernel(const ushort_t* __restrict__ Xb, ushort_t* __restrict__ Outb,
                              const int* __restrict__ rowptr, const int* __restrict__ csr,
                              const float* __restrict__ dv, int self_loop, float scale,
                              const float* __restrict__ bias, int relu, int M)
{
    int node = blockIdx.x * 4 + (threadIdx.x >> 6);
    int lane = threadIdx.x & 63;
    if (node >= M) return;
    int beg = rowptr[node], end = rowptr[node + 1];
    float dn = dv[node];
    float ax = 0.f, ay = 0.f;
    int e = beg;
    for (; e + 3 < end; e += 4) {
        int s0 = csr[e], s1 = csr[e + 1], s2 = csr[e + 2], s3 = csr[e + 3];
        float c0 = dn * dv[s0], c1 = dn * dv[s1], c2 = dn * dv[s2], c3 = dn * dv[s3];
        unsigned int u0 = *(const unsigned int*)(Xb + (size_t)s0 * 128 + lane * 2);
        unsigned int u1 = *(const unsigned int*)(Xb + (size_t)s1 * 128 + lane * 2);
        unsigned int u2 = *(const unsigned int*)(Xb + (size_t)s2 * 128 + lane * 2);
        unsigned int u3 = *(const unsigned int*)(Xb + (size_t)s3 * 128 + lane * 2);
        ax = fmaf(c0, bf2f(u0 & 0xffff), fmaf(c1, bf2f(u1 & 0xffff),
             fmaf(c2, bf2f(u2 & 0xffff), fmaf(c3, bf2f(u3 & 0xffff), ax))));
        ay = fmaf(c0, bf2f(u0 >> 16), fmaf(c1, bf2f(u1 >> 16),
             fmaf(c2, bf2f(u2 >> 16), fmaf(c3, bf2f(u3 >> 16), ay))));
    }
    for (; e < end; e++) {
        int s = csr[e];
        float c = dn * dv[s];
        unsigned int u = *(const unsigned int*)(Xb + (size_t)s * 128 + lane * 2);
        ax = fmaf(c, bf2f(u & 0xffff), ax);
        ay = fmaf(c, bf2f(u >> 16), ay);
    }
    if (self_loop) {
        float c = dn * dn;
        unsigned int u = *(const unsigned int*)(Xb + (size_t)node * 128 + lane * 2);
        ax = fmaf(c, bf2f(u & 0xffff), ax);
        ay = fmaf(c, bf2f(u >> 16), ay);
    }
    ax *= scale; ay *= scale;
    if (bias) { ax += bias[lane * 2]; ay += bias[lane * 2 + 1]; }
    if (relu) { ax = fmaxf(ax, 0.f); ay = fmaxf(ay, 0.f); }
    unsigned int pk = f2bu(ax) | (f2bu(ay) << 16);
    *(unsigned int*)(Outb + (size_t)node * 128 + lane * 2) = pk;
}

// ---------- dual gather: OutA = -aprop_dinv(X); OutB = aprop_dinvl(X)+X*dinvl^2 ----------
__global__ void gather2_kernel(const ushort_t* __restrict__ Xb,
                               ushort_t* __restrict__ OutA, ushort_t* __restrict__ OutB,
                               const int* __restrict__ rowptr, const int* __restrict__ csr,
                               const float* __restrict__ dinv, const float* __restrict__ dinvl,
                               int M)
{
    int node = blockIdx.x * 4 + (threadIdx.x >> 6);
    int lane = threadIdx.x & 63;
    if (node >= M) return;
    int beg = rowptr[node], end = rowptr[node + 1];
    float dn = dinv[node], dnl = dinvl[node];
    float axA = 0.f, ayA = 0.f, axB = 0.f, ayB = 0.f;
    int e = beg;
    for (; e + 1 < end; e += 2) {
        int s0 = csr[e], s1 = csr[e + 1];
        float c0 = dn * dinv[s0], c1 = dn * dinv[s1];
        float l0 = dnl * dinvl[s0], l1 = dnl * dinvl[s1];
        unsigned int u0 = *(const unsigned int*)(Xb + (size_t)s0 * 128 + lane * 2);
        unsigned int u1 = *(const unsigned int*)(Xb + (size_t)s1 * 128 + lane * 2);
        float x00 = bf2f(u0 & 0xffff), x01 = bf2f(u0 >> 16);
        float x10 = bf2f(u1 & 0xffff), x11 = bf2f(u1 >> 16);
        axA = fmaf(c0, x00, fmaf(c1, x10, axA));
        ayA = fmaf(c0, x01, fmaf(c1, x11, ayA));
        axB = fmaf(l0, x00, fmaf(l1, x10, axB));
        ayB = fmaf(l0, x01, fmaf(l1, x11, ayB));
    }
    for (; e < end; e++) {
        int s = csr[e];
        float c = dn * dinv[s], l = dnl * dinvl[s];
        unsigned int u = *(const unsigned int*)(Xb + (size_t)s * 128 + lane * 2);
        float x0 = bf2f(u & 0xffff), x1 = bf2f(u >> 16);
        axA = fmaf(c, x0, axA); ayA = fmaf(c, x1, ayA);
        axB = fmaf(l, x0, axB); ayB = fmaf(l, x1, ayB);
    }
    {
        float c = dnl * dnl;
        unsigned int u = *(const unsigned int*)(Xb + (size_t)node * 128 + lane * 2);
        axB = fmaf(c, bf2f(u & 0xffff), axB);
        ayB = fmaf(c, bf2f(u >> 16), ayB);
    }
    size_t ofs = (size_t)node * 128 + lane * 2;
    *(unsigned int*)(OutA + ofs) = f2bu(-axA) | (f2bu(-ayA) << 16);
    *(unsigned int*)(OutB + ofs) = f2bu(axB) | (f2bu(ayB) << 16);
}

// ---------- attention: bf16 q, interleaved bf16 KV, bf16 out ----------
__global__ void gt_attn_kernel(const ushort_t* __restrict__ Qb, const ushort_t* __restrict__ KV,
                               const int* __restrict__ rowptr, const int* __restrict__ csr,
                               ushort_t* __restrict__ Outb, int M)
{
    const float SCL = 0.17677669529663689f * 1.4426950408889634f;
    int node = blockIdx.x * 4 + (threadIdx.x >> 6);
    int lane = threadIdx.x & 63;
    if (node >= M) return;
    int beg = rowptr[node], end = rowptr[node + 1];
    unsigned int qu = *(const unsigned int*)(Qb + (size_t)node * 128 + lane * 2);
    float qx = bf2f(qu & 0xffff) * SCL, qy = bf2f(qu >> 16) * SCL;
    float den = 0.f, ax = 0.f, ay = 0.f;
    int e = beg;
    for (; e + 3 < end; e += 4) {
        int s0 = csr[e], s1 = csr[e + 1], s2 = csr[e + 2], s3 = csr[e + 3];
        unsigned int k0 = *(const unsigned int*)(KV + (size_t)s0 * 256 + lane * 2);
        unsigned int k1 = *(const unsigned int*)(KV + (size_t)s1 * 256 + lane * 2);
        unsigned int k2 = *(const unsigned int*)(KV + (size_t)s2 * 256 + lane * 2);
        unsigned int k3 = *(const unsigned int*)(KV + (size_t)s3 * 256 + lane * 2);
        unsigned int v0 = *(const unsigned int*)(KV + (size_t)s0 * 256 + 128 + lane * 2);
        unsigned int v1 = *(const unsigned int*)(KV + (size_t)s1 * 256 + 128 + lane * 2);
        unsigned int v2 = *(const unsigned int*)(KV + (size_t)s2 * 256 + 128 + lane * 2);
        unsigned int v3 = *(const unsigned int*)(KV + (size_t)s3 * 256 + 128 + lane * 2);
        float p0 = qx * bf2f(k0 & 0xffff) + qy * bf2f(k0 >> 16);
        float p1 = qx * bf2f(k1 & 0xffff) + qy * bf2f(k1 >> 16);
        float p2 = qx * bf2f(k2 & 0xffff) + qy * bf2f(k2 >> 16);
        float p3 = qx * bf2f(k3 & 0xffff) + qy * bf2f(k3 >> 16);
#pragma unroll
        for (int off = 1; off <= 8; off <<= 1) {
            p0 += __shfl_xor(p0, off); p1 += __shfl_xor(p1, off);
            p2 += __shfl_xor(p2, off); p3 += __shfl_xor(p3, off);
        }
        float w0 = exp2f(fminf(p0, 80.f));
        float w1 = exp2f(fminf(p1, 80.f));
        float w2 = exp2f(fminf(p2, 80.f));
        float w3 = exp2f(fminf(p3, 80.f));
        den += (w0 + w1) + (w2 + w3);
        ax = fmaf(w0, bf2f(v0 & 0xffff), fmaf(w1, bf2f(v1 & 0xffff),
             fmaf(w2, bf2f(v2 & 0xffff), fmaf(w3, bf2f(v3 & 0xffff), ax))));
        ay = fmaf(w0, bf2f(v0 >> 16), fmaf(w1, bf2f(v1 >> 16),
             fmaf(w2, bf2f(v2 >> 16), fmaf(w3, bf2f(v3 >> 16), ay))));
    }
    for (; e < end; e++) {
        int s = csr[e];
        unsigned int ku = *(const unsigned int*)(KV + (size_t)s * 256 + lane * 2);
        unsigned int vu = *(const unsigned int*)(KV + (size_t)s * 256 + 128 + lane * 2);
        float p = qx * bf2f(ku & 0xffff) + qy * bf2f(ku >> 16);
#pragma unroll
        for (int off = 1; off <= 8; off <<= 1) p += __shfl_xor(p, off);
        float w = exp2f(fminf(p, 80.f));
        den += w;
        ax = fmaf(w, bf2f(vu & 0xffff), ax);
        ay = fmaf(w, bf2f(vu >> 16), ay);
    }
    float d = fmaxf(den, 1e-9f);
    unsigned int pk = f2bu(ax / d) | (f2bu(ay / d) << 16);
    *(unsigned int*)(Outb + (size_t)node * 128 + lane * 2) = pk;
}

// ---------- fused combine + pool phase 1 (bf16 features) ----------
__global__ void pool_combine_kernel(const ushort_t* __restrict__ hb,
                                    const ushort_t* __restrict__ e0, const ushort_t* __restrict__ e1,
                                    const ushort_t* __restrict__ e2, const ushort_t* __restrict__ e3,
                                    const float* __restrict__ gates,
                                    const float* __restrict__ png, const float* __restrict__ pnb,
                                    const float* __restrict__ esc,
                                    const int* __restrict__ bstart, const int* __restrict__ bend,
                                    float* __restrict__ partial)
{
    int b = blockIdx.x, c = blockIdx.y;
    int lane = threadIdx.x;   // 64
    int s0 = bstart[b], e0i = bend[b];
    const ushort_t* eps[4] = {e0, e1, e2, e3};
    float ga[4], gb[4], ba[4], bb[4], es[4];
#pragma unroll
    for (int ee = 0; ee < 4; ee++) {
        ga[ee] = png[ee * 128 + lane * 2];
        gb[ee] = png[ee * 128 + lane * 2 + 1];
        ba[ee] = pnb[ee * 128 + lane * 2];
        bb[ee] = pnb[ee * 128 + lane * 2 + 1];
        es[ee] = esc[ee];
    }
    float sx = 0.f, sy = 0.f;
    for (int n = s0 + c; n < e0i; n += PCH) {
        size_t ofs = (size_t)n * 128 + lane * 2;
        float4 gg = *(const float4*)(gates + (size_t)n * 4);
        float gv[4] = {gg.x, gg.y, gg.z, gg.w};
        unsigned int hu = *(const unsigned int*)(hb + ofs);
        float ox = bf2f(hu & 0xffff), oy = bf2f(hu >> 16);
#pragma unroll
        for (int ee = 0; ee < 4; ee++) {
            unsigned int u = *(const unsigned int*)(eps[ee] + ofs);
            float vx = bf2f(u & 0xffff), vy = bf2f(u >> 16);
            float su = vx + vy, sq = vx * vx + vy * vy;
#pragma unroll
            for (int off = 32; off; off >>= 1) { su += __shfl_xor(su, off); sq += __shfl_xor(sq, off); }
            float mean = su * (1.f / 128.f);
            float var = sq * (1.f / 128.f) - mean * mean;
            float inv = rsqrtf(var + 1e-5f);
            float cc = es[ee] * gv[ee];
            ox = fmaf(cc, (vx - mean) * inv * ga[ee] + ba[ee], ox);
            oy = fmaf(cc, (vy - mean) * inv * gb[ee] + bb[ee], oy);
        }
        sx += ox; sy += oy;
    }
    *(float2*)(partial + ((size_t)b * PCH + c) * 128 + lane * 2) = make_float2(sx, sy);
}
__global__ void pool_reduce_kernel(const float* __restrict__ partial,
                                   const int* __restrict__ bstart, const int* __restrict__ bend,
                                   float* __restrict__ pooled)
{
    int b = blockIdx.x, t = threadIdx.x;
    float sum = 0.f;
#pragma unroll
    for (int c = 0; c < PCH; c++) sum += partial[((size_t)b * PCH + c) * 128 + t];
    float cnt = fmaxf((float)(bend[b] - bstart[b]), 1.f);
    pooled[(size_t)b * 128 + t] = sum / cnt;
}

// ---------- classification head ----------
__global__ void head_kernel(const float* __restrict__ pooled,
                            const float* __restrict__ h1W, const float* __restrict__ h1b,
                            const float* __restrict__ h1g, const float* __restrict__ h1be,
                            const float* __restrict__ h2W, const float* __restrict__ h2b,
                            const float* __restrict__ h2g, const float* __restrict__ h2be,
                            const float* __restrict__ h3W, const float* __restrict__ h3b,
                            const float* __restrict__ lbias,
                            float* __restrict__ out, int B)
{
    __shared__ float p[128], z[128];
    int b = blockIdx.x, t = threadIdx.x;
    p[t] = pooled[(size_t)b * 128 + t];
    __syncthreads();
    float a = h1b[t];
    for (int k = 0; k < 128; k++) a = fmaf(p[k], h1W[k * 128 + t], a);
    z[t] = a;
    __syncthreads();
    float s = 0.f, sq = 0.f;
    for (int k = 0; k < 128; k++) { float x = z[k]; s += x; sq += x * x; }
    float mean = s * (1.f / 128.f), var = sq * (1.f / 128.f) - mean * mean;
    float y = fmaxf((a - mean) * rsqrtf(var + 1e-5f) * h1g[t] + h1be[t], 0.f);
    __syncthreads();
    z[t] = y;
    __syncthreads();
    float a2 = 0.f;
    if (t < 64) {
        a2 = h2b[t];
        for (int k = 0; k < 128; k++) a2 = fmaf(z[k], h2W[k * 64 + t], a2);
    }
    __syncthreads();
    if (t < 64) p[t] = a2;
    __syncthreads();
    if (t < 2) {
        float s2 = 0.f, sq2 = 0.f;
        for (int k = 0; k < 64; k++) { float x = p[k]; s2 += x; sq2 += x * x; }
        float mean2 = s2 * (1.f / 64.f), var2 = sq2 * (1.f / 64.f) - mean2 * mean2;
        float inv2 = rsqrtf(var2 + 1e-5f);
        float o = h3b[t] + lbias[t];
        for (int k = 0; k < 64; k++) {
            float zc = fmaxf((p[k] - mean2) * inv2 * h2g[k] + h2be[k], 0.f);
            o = fmaf(zc, h3W[k * 2 + t], o);
        }
        out[b * 2 + t] = o;
    }
}

// ---------------- launch ----------------
extern "C" void kernel_launch(void* const* d_in, const int* in_sizes, int n_in,
                              void* d_out, int out_size, void* d_ws, size_t ws_size,
                              hipStream_t stream)
{
    (void)ws_size; (void)n_in;
    const int N = in_sizes[3];
    const int E = in_sizes[2] / 2;
    const int B = out_size / 2;

    const int* ei = (const int*)d_in[2];
    const int* src = ei;
    const int* dst = ei + E;
    const int* batch = (const int*)d_in[3];

    const float* W[47];
    for (int i = 0; i < 47; i++) W[i] = (const float*)d_in[i];

    size_t fN = (size_t)N;
    // fp32 region
    float* hr     = (float*)d_ws;            // 256N
    float* htmp   = hr + 256 * fN;           // 128N (fuse out, LN reads)
    float* gates  = htmp + 128 * fN;         // 4N
    float* dinv   = gates + 4 * fN;          // N
    float* dinvl  = dinv + fN;               // N
    float* pooled = dinvl + fN;              // 128*B
    float* partial = pooled + (size_t)128 * B;  // 128*B*PCH
    // bf16 region
    ushort_t* hb  = (ushort_t*)(partial + (size_t)128 * B * PCH);
    ushort_t* e0b = hb + 128 * fN;
    ushort_t* e1b = e0b + 128 * fN;
    ushort_t* e2b = e1b + 128 * fN;
    ushort_t* e3b = e2b + 128 * fN;
    ushort_t* x0  = e3b + 128 * fN;
    ushort_t* x1  = x0 + 128 * fN;
    ushort_t* x2  = x1 + 128 * fN;
    ushort_t* x3  = x2 + 128 * fN;
    ushort_t* qb  = x3 + 128 * fN;
    ushort_t* kvb = qb + 128 * fN;           // 256N
    ushort_t* wt  = kvb + 256 * fN;
    // weight table: QKV contiguous per layer
    WtPack wp;
    const float* wsrc[NWT] = {
        W[4], W[8], W[12], W[17], W[19],
        W[21], W[21] + 16384, W[21] + 32768, W[21] + 49152,
        W[23], W[25], W[27],
        W[23] + 16384, W[25] + 16384, W[27] + 16384,
        W[29], W[29] + 16384,
        W[31], W[31] + 16384
    };
    const int wk[NWT] = {200, 128, 256, 128, 128,
                         128, 128, 128, 128,
                         128, 128, 128,
                         128, 128, 128,
                         128, 128,
                         128, 128};
    unsigned long long woff[NWT];
    unsigned long long acc_off = 0;
    for (int i = 0; i < NWT; i++) {
        wp.src[i] = wsrc[i];
        wp.K[i] = wk[i];
        wp.off[i] = acc_off;
        woff[i] = acc_off;
        acc_off += (unsigned long long)128 * wk[i];
    }
    int* degi   = (int*)(wt + acc_off + 8);
    int* cursor = degi + N;
    int* rowptr = cursor + N;
    int* csr    = rowptr + (N + 1);
    int* bstart = csr + E;
    int* bend   = bstart + B;
    int* bsum   = bend + B;

    dim3 blk(256);
    int gN4 = (N + 3) / 4;
    dim3 gG((N + 63) / 64);
    int nsb = (N + SCH - 1) / SCH;

    // weights + graph structure
    wconv_kernel<<<dim3(32, NWT), blk, 0, stream>>>(wp, wt);
    zero_i32_kernel<<<(2 * N + 255) / 256, blk, 0, stream>>>(degi, 2 * N);
    zero_i32_kernel<<<1, blk, 0, stream>>>(bstart, 2 * B);
    seg_bounds_kernel<<<(N + 255) / 256, blk, 0, stream>>>(batch, bstart, bend, N);
    edge_deg_kernel<<<(E + 255) / 256, blk, 0, stream>>>(dst, degi, E);
    scan1_kernel<<<dim3(nsb), blk, 0, stream>>>(degi, rowptr, bsum, N);
    scan2_kernel<<<1, blk, 0, stream>>>(bsum, nsb);
    scan3_kernel<<<(N + 255) / 256, blk, 0, stream>>>(rowptr, bsum, N);
    csr_fill_kernel<<<(E + 255) / 256, blk, 0, stream>>>(src, dst, rowptr, cursor, csr, E);
    dinv_kernel<<<(N + 255) / 256, blk, 0, stream>>>(degi, dinv, dinvl, N);

    // encoders + fuse + router (fp32 hr path, exact gating)
    gemm_f32_kernel<<<gG, blk, 0, stream>>>(W[0], 200, wt + woff[0], hr, 256, N, 200, W[5]);
    gemm_f32_kernel<<<gG, blk, 0, stream>>>(W[1], 128, wt + woff[1], hr + 128, 256, N, 128, W[9]);
    ln_relu_kernel<<<gN4, blk, 0, stream>>>(hr, 256, W[6], W[7], N, 1, (ushort_t*)0);
    ln_relu_kernel<<<gN4, blk, 0, stream>>>(hr + 128, 256, W[10], W[11], N, 1, (ushort_t*)0);
    router_kernel<<<gN4, blk, 0, stream>>>(hr, W[16], gates, N);
    gemm_f32_kernel<<<gG, blk, 0, stream>>>(hr, 256, wt + woff[2], htmp, 128, N, 256, W[13]);
    ln_relu_kernel<<<gN4, blk, 0, stream>>>(htmp, 128, W[14], W[15], N, 0, hb);

    // expert 0: MLP (bf16)
    gemm_bf_kernel<<<gG, blk, 0, stream>>>(hb, wt + woff[3], x0, N, W[18], RELUF);
    gemm_bf_kernel<<<gG, blk, 0, stream>>>(x0, wt + woff[4], e0b, N, W[20], 0);

    // fused layer-1 gather: x1 = -aprop_dinv(h) [Cheb], x2 = gcn-gather(h)
    gather2_kernel<<<gN4, blk, 0, stream>>>(hb, x1, x2, rowptr, csr, dinv, dinvl, N);

    // expert 1: ChebNet K=2
    gemm_dual_kernel<<<gG, blk, 0, stream>>>(hb, wt + woff[5], x1, wt + woff[6],
                                             x0, N, W[22], RELUF);
    gather_kernel<<<gN4, blk, 0, stream>>>(x0, x3, rowptr, csr, dinv, 0, -1.f, (const float*)0, 0, N);
    gemm_dual_kernel<<<gG, blk, 0, stream>>>(x0, wt + woff[7], x3, wt + woff[8],
                                             e1b, N, W[22] + 128, 0);

    // expert 3: GCN (gather-then-GEMM)
    gemm_bf_kernel<<<gG, blk, 0, stream>>>(x2, wt + woff[17], x1, N, W[32], RELUF);
    gather_kernel<<<gN4, blk, 0, stream>>>(x1, x2, rowptr, csr, dinvl, 1, 1.f, (const float*)0, 0, N);
    gemm_bf_kernel<<<gG, blk, 0, stream>>>(x2, wt + woff[18], e3b, N, W[32] + 128, 0);

    // expert 2: Graph Transformer (2 layers)
    gemm3_kernel<<<gG, blk, 0, stream>>>(hb, wt + woff[9], qb, N, W[24], W[26], W[28], kvb);
    gt_attn_kernel<<<gN4, blk, 0, stream>>>(qb, kvb, rowptr, csr, x1, N);
    gemm_bf_kernel<<<gG, blk, 0, stream>>>(hb, wt + woff[15], x1, N, W[30], ACCF | RELUF); // z1 in x1
    gemm3_kernel<<<gG, blk, 0, stream>>>(x1, wt + woff[12], qb, N,
                                         W[24] + 128, W[26] + 128, W[28] + 128, kvb);
    gt_attn_kernel<<<gN4, blk, 0, stream>>>(qb, kvb, rowptr, csr, e2b, N);
    gemm_bf_kernel<<<gG, blk, 0, stream>>>(x1, wt + woff[16], e2b, N, W[30] + 128, ACCF);

    // fused combine+pool + head
    pool_combine_kernel<<<dim3(B, PCH), dim3(64), 0, stream>>>(
        hb, e0b, e1b, e2b, e3b, gates, W[33], W[34], W[35], bstart, bend, partial);
    pool_reduce_kernel<<<dim3(B), dim3(128), 0, stream>>>(partial, bstart, bend, pooled);
    head_kernel<<<dim3(B), dim3(128), 0, stream>>>(pooled,
        W[36], W[37], W[38], W[39],
        W[40], W[41], W[42], W[43],
        W[44], W[45], W[46],
        (float*)d_out, B);
}